// Round 8
// baseline (1666.421 us; speedup 1.0000x reference)
//
#include <hip/hip_runtime.h>
#include <hip/hip_bf16.h>
#include <math.h>

// ---------------------------------------------------------------------------
// R8: fused persistent bi-LSTM (k_lstm_all): one launch, 256 co-resident
//     blocks, per-group (dir x batch-slab) spin barriers via device-scope
//     atomics; c-state + biases in registers; h parity-double-buffered.
//     Image branch unchanged from R7.
// ---------------------------------------------------------------------------

namespace {

constexpr int S_ = 32, B_ = 128, H_ = 1024, P_ = 196, OC_ = 128;
constexpr int NE = B_ * OC_ * P_;        // elems of a [B][128][196] slab
constexpr int KX = 384;                  // padded x-K (300 -> 384)

typedef __attribute__((ext_vector_type(8))) short short8v;
typedef __attribute__((ext_vector_type(4))) float f32x4;
#define MFMA16(a, b, c) __builtin_amdgcn_mfma_f32_16x16x32_bf16((a), (b), (c), 0, 0, 0)

__device__ __forceinline__ float sigm(float x){ return 1.0f/(1.0f + expf(-x)); }
__device__ __forceinline__ float c0f(int p){ return ((float)p/14.0f - 7.0f)/7.0f; }
__device__ __forceinline__ float c1f(int p){ return ((float)(p%14) - 7.0f)/7.0f; }
__device__ __forceinline__ unsigned short f2bf(float x){
  __hip_bfloat16 h = __float2bfloat16(x);
  return *reinterpret_cast<unsigned short*>(&h);
}

// ---------------- weight convert f32 -> bf16, K-padded -----------------------
__global__ void k_cvtpad(const float* __restrict__ src, unsigned short* __restrict__ dst,
                         int rows, int ks, int kd){
  int i = blockIdx.x*256 + threadIdx.x;
  if (i >= rows*kd) return;
  int k = i % kd, r = i / kd;
  dst[i] = (k < ks) ? f2bf(src[r*ks + k]) : (unsigned short)0;
}

// conv weights [oc][cin][3][3] f32 -> wT [s][oc][cpad] bf16
__global__ void k_cvt_wT(const float* __restrict__ w, unsigned short* __restrict__ wT,
                         int cin, int cpad){
  int i = blockIdx.x*256 + threadIdx.x;
  if (i >= 9*128*cpad) return;
  int c = i % cpad; int t = i / cpad; int oc = t % 128; int s = t / 128;
  wT[i] = (c < cin) ? f2bf(w[((size_t)oc*cin + c)*9 + s]) : (unsigned short)0;
}

__global__ void k_bias2(const float* __restrict__ bif, const float* __restrict__ bhf,
                        const float* __restrict__ bib, const float* __restrict__ bhb,
                        float* __restrict__ out){
  int i = blockIdx.x*256 + threadIdx.x;
  if (i >= 8192) return;
  out[i] = (i < 4096) ? (bif[i] + bhf[i]) : (bib[i-4096] + bhb[i-4096]);
}

// ---------------- embedding -> bf16 x[s][b][384] ------------------------------
__global__ void k_embed_bf(const int* __restrict__ que, const float* __restrict__ emb,
                           unsigned short* __restrict__ x){
  int idx = blockIdx.x*256 + threadIdx.x;
  if (idx >= S_*B_*KX) return;
  int e = idx % KX; int sb = idx / KX; int b = sb % B_; int s = sb / B_;
  float v = 0.0f;
  if (e < 300){
    int t = que[b*S_ + s];
    if (t != 0) v = emb[t*300 + e];
  }
  x[idx] = f2bf(v);
}

// ---------------- fused persistent bi-LSTM ------------------------------------
// grid (64, 4): x = dir*32 + colslab, y = batch-slab. 256 blocks = 1/CU
// (forced by 107KB LDS) -> all co-resident. Group = (dir, y): 32 blocks that
// exchange h; per-group per-step release/acquire counters in cnt[8][32].
// Block tile: M = 32 batch rows x N = 128 cols (4 gates x 32 units, wave =
// gate). h parity-dbuf in global; c + biases in registers.
__launch_bounds__(256, 1)
__global__ void k_lstm_all(const unsigned short* __restrict__ xbf,
                           const unsigned short* __restrict__ wihc,
                           const unsigned short* __restrict__ whhc,
                           const float* __restrict__ bias2,
                           unsigned short* __restrict__ hstate,
                           int* __restrict__ cnt,
                           float* __restrict__ Q){
  const int dir = blockIdx.x >> 5;
  const int u0  = (blockIdx.x & 31) * 32;
  const int m0g = blockIdx.y * 32;
  const int g   = dir*4 + blockIdx.y;
  const int tid = threadIdx.x, wave = tid >> 6, lane = tid & 63;
  const int lr = lane & 15, lk = lane >> 4;

  __shared__ unsigned short tA[32][1416];   // [m][k], pad 8
  __shared__ float sG[32][132];

  // weight rows for this wave's gate (invariant across steps)
  const int wr0 = wave*1024 + u0 + lr;
  const unsigned short* bx0 = wihc + (size_t)dir*4096*KX + (size_t)wr0*KX;
  const unsigned short* bx1 = bx0 + (size_t)16*KX;
  const unsigned short* bh0 = whhc + (size_t)dir*4096*H_ + (size_t)wr0*H_;
  const unsigned short* bh1 = bh0 + (size_t)16*H_;

  const int rA = tid >> 3, sgA = tid & 7;   // A-staging assignment

  // biases + c in registers (thread owns same (m,u) tasks every step)
  const float* bb = bias2 + (size_t)dir*4096;
  float bgi[4], bgf[4], bgg[4], bgo[4], creg[4];
  #pragma unroll
  for (int t = 0; t < 4; ++t){
    const int ug = u0 + ((tid + t*256) & 31);
    bgi[t] = bb[ug];        bgf[t] = bb[1024+ug];
    bgg[t] = bb[2048+ug];   bgo[t] = bb[3072+ug];
    creg[t] = 0.f;
  }

  #pragma unroll 1
  for (int s = 0; s < 32; ++s){
    const int xs = dir ? (S_-1-s) : s;
    const unsigned short* hin  = hstate + (size_t)(s & 1)*262144      + (size_t)dir*131072;
    unsigned short*       hout = hstate + (size_t)((s & 1)^1)*262144  + (size_t)dir*131072;

    // ---- wait for group's h of step s-1 ----
    if (s > 0){
      if (tid == 0){
        while (__hip_atomic_load(&cnt[g*32 + (s-1)], __ATOMIC_ACQUIRE,
                                 __HIP_MEMORY_SCOPE_AGENT) < 32)
          __builtin_amdgcn_s_sleep(2);
      }
      __syncthreads();
    }

    // ---- stage A: x row (384) + h row (1024), 22 indep loads/thread ----
    {
      const unsigned short* xr = xbf + ((size_t)xs*B_ + m0g + rA)*KX + sgA*48;
      #pragma unroll
      for (int q = 0; q < 6; ++q)
        *(short8v*)&tA[rA][sgA*48 + q*8] = *(const short8v*)(xr + q*8);
      const unsigned short* hr = hin + (size_t)(m0g + rA)*H_ + sgA*128;
      #pragma unroll
      for (int q = 0; q < 16; ++q)
        *(short8v*)&tA[rA][384 + sgA*128 + q*8] = *(const short8v*)(hr + q*8);
    }
    __syncthreads();

    // ---- K-loop: 12 x-chunks + 32 h-chunks of 32, barrier-free ----
    f32x4 acc00{0,0,0,0}, acc01{0,0,0,0}, acc10{0,0,0,0}, acc11{0,0,0,0};
    #pragma unroll
    for (int ch = 0; ch < 12; ++ch){
      const int ko = ch*32 + lk*8;
      short8v a0 = *(short8v*)&tA[lr][ko];
      short8v a1 = *(short8v*)&tA[16 + lr][ko];
      short8v b0 = *(const short8v*)(bx0 + ko);
      short8v b1 = *(const short8v*)(bx1 + ko);
      acc00 = MFMA16(a0, b0, acc00); acc01 = MFMA16(a0, b1, acc01);
      acc10 = MFMA16(a1, b0, acc10); acc11 = MFMA16(a1, b1, acc11);
    }
    #pragma unroll
    for (int ch = 0; ch < 32; ++ch){
      const int kb = ch*32 + lk*8;
      const int ka = 384 + kb;
      short8v a0 = *(short8v*)&tA[lr][ka];
      short8v a1 = *(short8v*)&tA[16 + lr][ka];
      short8v b0 = *(const short8v*)(bh0 + kb);
      short8v b1 = *(const short8v*)(bh1 + kb);
      acc00 = MFMA16(a0, b0, acc00); acc01 = MFMA16(a0, b1, acc01);
      acc10 = MFMA16(a1, b0, acc10); acc11 = MFMA16(a1, b1, acc11);
    }

    // ---- recombine through LDS ----
    #pragma unroll
    for (int j = 0; j < 4; ++j){
      const int rr = lk*4 + j;
      sG[rr][wave*32 + lr]            = acc00[j];
      sG[rr][wave*32 + 16 + lr]       = acc01[j];
      sG[16 + rr][wave*32 + lr]       = acc10[j];
      sG[16 + rr][wave*32 + 16 + lr]  = acc11[j];
    }
    __syncthreads();

    // ---- gate math (c in regs), write h + Q ----
    #pragma unroll
    for (int t = 0; t < 4; ++t){
      const int idx = tid + t*256;
      const int m = idx >> 5, u = idx & 31;
      const int ug = u0 + u, mg = m0g + m;
      float gi = sG[m][u]      + bgi[t];
      float gf = sG[m][32+u]   + bgf[t];
      float gg = sG[m][64+u]   + bgg[t];
      float go = sG[m][96+u]   + bgo[t];
      float cn = sigm(gf)*creg[t] + sigm(gi)*tanhf(gg);
      float hn = sigm(go)*tanhf(cn);
      creg[t] = cn;
      hout[(size_t)mg*H_ + ug] = f2bf(hn);
      Q[((size_t)xs*B_ + mg)*2048 + dir*1024 + ug] = hn;
    }

    // ---- release h to the group ----
    __threadfence();
    __syncthreads();
    if (tid == 0)
      __hip_atomic_fetch_add(&cnt[g*32 + s], 1, __ATOMIC_RELEASE,
                             __HIP_MEMORY_SCOPE_AGENT);
  }
}

// ---------------- qenc L2-normalize (in-place) + enc --------------------------
__global__ void k_qnorm(float* __restrict__ Q, float* __restrict__ enc){
  int sb = blockIdx.x;
  int s = sb >> 7, b = sb & 127;
  float* row = Q + (size_t)sb*2048;
  int tid = threadIdx.x;
  float v[8]; float ss = 0.f;
  #pragma unroll
  for (int i = 0; i < 8; ++i){ v[i] = row[tid*8+i]; ss += v[i]*v[i]; }
  __shared__ float red[256];
  red[tid] = ss; __syncthreads();
  for (int st = 128; st; st >>= 1){
    if (tid < st) red[tid] += red[tid+st];
    __syncthreads();
  }
  float inv = 1.0f / fmaxf(sqrtf(red[0]), 1e-12f);
  #pragma unroll
  for (int i = 0; i < 8; ++i){
    float q = v[i]*inv;
    row[tid*8+i] = q;
    if (s == S_-1) enc[(size_t)b*2048 + tid*8 + i] = q;
  }
}

// ---------------- per-pixel channel sumsq of img ------------------------------
__global__ void k_sqpart(const float* __restrict__ img, float* __restrict__ part){
  int b = blockIdx.x, cq = blockIdx.y;
  int t = threadIdx.x;
  if (t >= P_) return;
  const float* base = img + ((size_t)b*1024 + cq*256)*P_ + t;
  float s = 0.f;
  #pragma unroll 4
  for (int c = 0; c < 256; ++c){ float v = base[c*P_]; s += v*v; }
  part[((size_t)b*4 + cq)*P_ + t] = s;
}

__global__ void k_invnorm(const float* __restrict__ part, float* __restrict__ inv){
  int i = blockIdx.x*256 + threadIdx.x;
  if (i >= B_*P_) return;
  int b = i / P_, p = i % P_;
  float s = part[(b*4+0)*P_+p] + part[(b*4+1)*P_+p]
          + part[(b*4+2)*P_+p] + part[(b*4+3)*P_+p];
  inv[i] = 1.0f / fmaxf(sqrtf(s), 1e-12f);
}

// ---------------- img -> imgT[b][196][1056] bf16 (invnorm+coords+pad) ---------
__global__ void k_mkimgT(const float* __restrict__ img, const float* __restrict__ invn,
                         unsigned short* __restrict__ imgT){
  const int b = blockIdx.x, cg = blockIdx.y;
  const int tid = threadIdx.x;
  unsigned short* dstB = imgT + (size_t)b*196*1056;
  if (cg == 8){           // coord channels 1024,1025 + zero pad to 1055
    for (int i = tid; i < 196*32; i += 256){
      int p = i >> 5, cc = i & 31;
      float v = (cc == 0) ? c0f(p) : (cc == 1) ? c1f(p) : 0.f;
      dstB[(size_t)p*1056 + 1024 + cc] = f2bf(v);
    }
    return;
  }
  __shared__ unsigned short tt[196][136];
  __shared__ float sInv[200];
  for (int i = tid; i < 196; i += 256) sInv[i] = invn[b*196 + i];
  __syncthreads();
  const int c0 = cg*128;
  const float* srcB = img + ((size_t)b*1024 + c0)*196;
  for (int i = tid; i < 128*49; i += 256){
    int c = i / 49, p4 = i - (i/49)*49;
    float4 v = *(const float4*)(srcB + (size_t)c*196 + p4*4);
    int p = p4*4;
    tt[p+0][c] = f2bf(v.x * sInv[p+0]);
    tt[p+1][c] = f2bf(v.y * sInv[p+1]);
    tt[p+2][c] = f2bf(v.z * sInv[p+2]);
    tt[p+3][c] = f2bf(v.w * sInv[p+3]);
  }
  __syncthreads();
  for (int i = tid; i < 196*16; i += 256){
    int p = i >> 4, g = i & 15;
    *(short8v*)(dstB + (size_t)p*1056 + c0 + g*8) = *(short8v*)&tt[p][g*8];
  }
}

// ---------------- 3x3 conv via MFMA (T-layout input, N-split rows) ------------
template<int CPAD>
__device__ __forceinline__ void stage3t(unsigned short (*__restrict__ tile)[40],
                                        const unsigned short* __restrict__ src,
                                        int c0, int r0, int tid){
  for (int i = tid; i < 10*14*4; i += 256){
    int t = i / 56, rem = i - t*56, gx = rem >> 2, seg = rem & 3;
    int gy = r0 - 1 + t;
    if ((unsigned)gy < 14u){
      short8v v = *(const short8v*)(src + (size_t)(gy*14+gx)*CPAD + c0 + seg*8);
      *(short8v*)&tile[t*16 + gx + 1][seg*8] = v;
    }
  }
}

template<int CPAD>
__launch_bounds__(256, 2)
__global__ void k_conv3t(const unsigned short* __restrict__ srcT,
                         const unsigned short* __restrict__ wT,
                         const float* __restrict__ bias,
                         float* __restrict__ out){
  constexpr int T = CPAD / 32;
  const int b = blockIdx.x, n = blockIdx.y, z = blockIdx.z;
  const int r0 = n ? 6 : 0;
  const int chBeg = z ? T/2 : 0, chEnd = z ? T : T/2;
  const int tid = threadIdx.x, wave = tid >> 6, lane = tid & 63;
  const int lr = lane & 15, lk = lane >> 4;
  const int wfM = wave >> 1, wfN = wave & 1;
  const unsigned short* src = srcT + (size_t)b*196*CPAD;

  __shared__ unsigned short tile[2][164][40];

  for (int i = tid; i < 1640; i += 256)
    ((short8v*)&tile[0][0][0])[i] = short8v{0,0,0,0,0,0,0,0};
  __syncthreads();
  stage3t<CPAD>(tile[0], src, chBeg*32, r0, tid);
  __syncthreads();

  f32x4 acc[4][4];
  #pragma unroll
  for (int i = 0; i < 4; ++i)
    #pragma unroll
    for (int j = 0; j < 4; ++j) acc[i][j] = f32x4{0,0,0,0};

  for (int ch = chBeg; ch < chEnd; ++ch){
    const int cur = (ch - chBeg) & 1;
    #pragma unroll
    for (int dy = 0; dy < 3; ++dy){
      #pragma unroll
      for (int dx = 0; dx < 3; ++dx){
        const int dlt = dy*16 + dx;
        short8v a[4];
        #pragma unroll
        for (int rf = 0; rf < 4; ++rf)
          a[rf] = *(const short8v*)(wT + ((size_t)((dy*3+dx)*128) + wfM*64 + rf*16 + lr)*CPAD
                                       + ch*32 + lk*8);
        #pragma unroll
        for (int cf = 0; cf < 4; ++cf){
          short8v bf = *(short8v*)&tile[cur][wfN*64 + cf*16 + lr + dlt][lk*8];
          #pragma unroll
          for (int rf = 0; rf < 4; ++rf)
            acc[rf][cf] = MFMA16(a[rf], bf, acc[rf][cf]);
        }
      }
      if (dy == 0 && ch + 1 < chEnd)
        stage3t<CPAD>(tile[cur^1], src, (ch+1)*32, r0, tid);
    }
    __syncthreads();
  }

  #pragma unroll
  for (int rf = 0; rf < 4; ++rf){
    #pragma unroll
    for (int j = 0; j < 4; ++j){
      const int oc = wfM*64 + rf*16 + lk*4 + j;
      const float bz = z ? 0.f : bias[oc];
      #pragma unroll
      for (int cf = 0; cf < 4; ++cf){
        const int pos = wfN*64 + cf*16 + lr;
        const int py = r0 + (pos >> 4), px = pos & 15;
        const bool rowok = n ? (py >= 8) : true;
        if (rowok && px < 14)
          out[(size_t)z*NE + ((size_t)b*OC_ + oc)*P_ + py*14 + px] = acc[rf][cf][j] + bz;
      }
    }
  }
}

// ---------------- BN stats over 2 partial slabs -------------------------------
__global__ void k_bnstats(const float* __restrict__ t, float* __restrict__ stats){
  int o = blockIdx.x;
  int tid = threadIdx.x;
  float s = 0.f, s2 = 0.f;
  #pragma unroll 4
  for (int i = tid; i < B_*P_; i += 256){
    int b = i / P_, p = i - (i/P_)*P_;
    size_t off = ((size_t)b*OC_ + o)*P_ + p;
    float v = t[off] + t[off + NE];
    s += v; s2 += v*v;
  }
  __shared__ float r1[256], r2[256];
  r1[tid] = s; r2[tid] = s2; __syncthreads();
  for (int st = 128; st; st >>= 1){
    if (tid < st){ r1[tid] += r1[tid+st]; r2[tid] += r2[tid+st]; }
    __syncthreads();
  }
  if (tid == 0){
    float n = (float)(B_*P_);
    float m = r1[0] / n;
    float var = r2[0] / n - m*m;
    stats[o*2]   = m;
    stats[o*2+1] = rsqrtf(var + 1e-5f);
  }
}

// ---------------- BN apply + relu (+ optional residual add) -------------------
template<bool ADD>
__global__ void k_bnapply(const float* __restrict__ t, const float* __restrict__ stats,
                          const float* __restrict__ g, const float* __restrict__ bb,
                          const float* __restrict__ addsrc, float* __restrict__ out){
  int idx = blockIdx.x*256 + threadIdx.x;
  if (idx >= NE) return;
  int o = (idx / P_) % OC_;
  float m = stats[o*2], is = stats[o*2+1];
  float x = t[idx] + t[idx + NE];
  float v = g[o]*(x-m)*is + bb[o];
  v = fmaxf(v, 0.f);
  if (ADD) v += addsrc[idx];
  out[idx] = v;
}

// ---------------- 1x1 conv + relu; writes f32 [b][c][p] AND bf16 [b][p][c] ----
__launch_bounds__(256)
__global__ void k_conv1x1(const float* __restrict__ vin, const float* __restrict__ w,
                          const float* __restrict__ bias, float* __restrict__ out,
                          unsigned short* __restrict__ outT){
  const int b  = blockIdx.x;
  const int o0 = blockIdx.y * 64;
  const int tid = threadIdx.x;
  const int olane = tid & 63, pg = tid >> 6;
  const int o = o0 + olane;

  __shared__ float sV[32][196];
  __shared__ float sW[64][33];

  float acc[49];
  #pragma unroll
  for (int p = 0; p < 49; ++p) acc[p] = 0.f;

  for (int ch = 0; ch < 128; ch += 32){
    __syncthreads();
    for (int i = tid; i < 32*196; i += 256){
      int c = i / 196, p = i - c*196;
      sV[c][p] = vin[((size_t)b*128 + ch + c)*P_ + p];
    }
    for (int i = tid; i < 64*32; i += 256){
      int ol = i >> 5, c = i & 31;
      sW[ol][c] = w[(size_t)(o0+ol)*130 + ch + c];
    }
    __syncthreads();
    for (int c = 0; c < 32; ++c){
      float wv = sW[olane][c];
      #pragma unroll
      for (int p = 0; p < 49; ++p) acc[p] += sV[c][pg*49 + p] * wv;
    }
  }
  float w0 = w[(size_t)o*130 + 128], w1 = w[(size_t)o*130 + 129], bz = bias[o];
  #pragma unroll
  for (int p = 0; p < 49; ++p){
    int pp = pg*49 + p;
    float v = acc[p] + w0*c0f(pp) + w1*c1f(pp) + bz;
    v = fmaxf(v, 0.f);
    out[((size_t)b*128 + o)*P_ + pp] = v;
    outT[((size_t)b*P_ + pp)*128 + o] = f2bf(v);
  }
}

} // namespace

// ---------------------------------------------------------------------------
extern "C" void kernel_launch(void* const* d_in, const int* in_sizes, int n_in,
                              void* d_out, int out_size, void* d_ws, size_t ws_size,
                              hipStream_t stream){
  (void)in_sizes; (void)n_in; (void)out_size; (void)ws_size;
  const int*   que  = (const int*)  d_in[0];
  const float* img  = (const float*)d_in[1];
  const float* emb  = (const float*)d_in[2];
  const float* wihf = (const float*)d_in[3];
  const float* whhf = (const float*)d_in[4];
  const float* bihf = (const float*)d_in[5];
  const float* bhhf = (const float*)d_in[6];
  const float* wihb = (const float*)d_in[7];
  const float* whhb = (const float*)d_in[8];
  const float* bihb = (const float*)d_in[9];
  const float* bhhb = (const float*)d_in[10];
  const float* convw = (const float*)d_in[11];
  const float* convb = (const float*)d_in[12];
  const float* bng  = (const float*)d_in[13];
  const float* bnb  = (const float*)d_in[14];
  const float* r1c1w = (const float*)d_in[15];
  const float* r1c1b = (const float*)d_in[16];
  const float* r1c2w = (const float*)d_in[17];
  const float* r1c2b = (const float*)d_in[18];
  const float* r1bng = (const float*)d_in[19];
  const float* r1bnb = (const float*)d_in[20];
  const float* r2c1w = (const float*)d_in[21];
  const float* r2c1b = (const float*)d_in[22];
  const float* r2c2w = (const float*)d_in[23];
  const float* r2c2b = (const float*)d_in[24];
  const float* r2bng = (const float*)d_in[25];
  const float* r2bnb = (const float*)d_in[26];

  float* out  = (float*)d_out;
  float* enc  = out;                        // 128*2048
  float* Q    = out + 262144;               // 32*128*2048
  float* vout = out + 262144 + 8388608;     // 128*128*196

  // ------ workspace layout (f32 units) ----------------------------------------
  float* ws = (float*)d_ws;
  unsigned short* xbf  = (unsigned short*)ws;            // 32*128*384 bf16
  float* p1 = ws + 786432;
  unsigned short* wihc = (unsigned short*)p1;            // 2*4096*384 bf16
  float* p2 = p1 + 1572864;
  unsigned short* whhc = (unsigned short*)p2;            // 2*4096*1024 bf16
  float* p3 = p2 + 4194304;
  float* bias2 = p3;                                     // 2*4096
  float* p4 = p3 + 8192;
  unsigned short* hstate = (unsigned short*)p4;          // 2par*2dir*128*1024 bf16
  float* p5 = p4 + 262144;
  int*   cnt = (int*)p5;                                 // 8 groups x 32 steps
  float* p6 = p5 + 262144;                               // (rest of old cstate)
  float* part = p6;                                      // 128*4*196
  float* invn = p6 + 100352;                             // 128*196
  float* bufA = invn + 25088;                            // NE
  float* bufB = bufA + NE;                               // NE
  float* convOut = bufB + NE;                            // 2*NE partial slabs
  float* p7 = convOut + 2*(size_t)NE;
  float* stats = p7;                                     // 256
  float* p8 = p7 + 256;
  unsigned short* wTc  = (unsigned short*)p8;            // 9*128*1056 bf16
  float* p9 = p8 + 608256;
  unsigned short* wTr1 = (unsigned short*)p9;            // 9*128*128 bf16
  float* p10 = p9 + 73728;
  unsigned short* wTr2 = (unsigned short*)p10;           // 9*128*128 bf16
  float* p11 = p10 + 73728;
  unsigned short* imgT = (unsigned short*)p11;           // 128*196*1056 bf16
  float* p12 = p11 + 13246464;
  unsigned short* v1T  = (unsigned short*)p12;           // 128*196*128 bf16

  // zero h parity 0 (read at s=0) + step counters
  hipMemsetAsync(hstate, 0, (size_t)262144*sizeof(unsigned short), stream);
  hipMemsetAsync(cnt, 0, 8*32*sizeof(int), stream);

  // ------ conversions ---------------------------------------------------------
  k_cvtpad<<<6144, 256, 0, stream>>>(wihf, wihc,                     4096, 300, KX);
  k_cvtpad<<<6144, 256, 0, stream>>>(wihb, wihc + (size_t)4096*KX,   4096, 300, KX);
  k_cvtpad<<<16384,256, 0, stream>>>(whhf, whhc,                     4096, 1024, 1024);
  k_cvtpad<<<16384,256, 0, stream>>>(whhb, whhc + (size_t)4096*1024, 4096, 1024, 1024);
  k_bias2<<<32, 256, 0, stream>>>(bihf, bhhf, bihb, bhhb, bias2);
  k_embed_bf<<<6144, 256, 0, stream>>>(que, emb, xbf);
  k_cvt_wT<<<(9*128*1056 + 255)/256, 256, 0, stream>>>(convw, wTc, 1026, 1056);
  k_cvt_wT<<<(9*128*128 + 255)/256, 256, 0, stream>>>(r1c2w, wTr1, 128, 128);
  k_cvt_wT<<<(9*128*128 + 255)/256, 256, 0, stream>>>(r2c2w, wTr2, 128, 128);

  // ------ fused bi-LSTM (one launch) -------------------------------------------
  k_lstm_all<<<dim3(64,4), 256, 0, stream>>>(xbf, wihc, whhc, bias2, hstate, cnt, Q);
  k_qnorm<<<4096, 256, 0, stream>>>(Q, enc);

  // ------ image branch --------------------------------------------------------
  k_sqpart<<<dim3(128,4), 256, 0, stream>>>(img, part);
  k_invnorm<<<(25088+255)/256, 256, 0, stream>>>(part, invn);
  k_mkimgT<<<dim3(128,9), 256, 0, stream>>>(img, invn, imgT);

  k_conv3t<1056><<<dim3(128,2,2), 256, 0, stream>>>(imgT, wTc, convb, convOut);
  k_bnstats<<<128, 256, 0, stream>>>(convOut, stats);
  k_bnapply<false><<<(NE+255)/256, 256, 0, stream>>>(convOut, stats, bng, bnb, bufA, bufA);

  // res block 1: bufA(v) -> bufB/v1T(v1) -> convOut -> bufA(v2+v1)
  k_conv1x1<<<dim3(128,2), 256, 0, stream>>>(bufA, r1c1w, r1c1b, bufB, v1T);
  k_conv3t<128><<<dim3(128,2,2), 256, 0, stream>>>(v1T, wTr1, r1c2b, convOut);
  k_bnstats<<<128, 256, 0, stream>>>(convOut, stats);
  k_bnapply<true><<<(NE+255)/256, 256, 0, stream>>>(convOut, stats, r1bng, r1bnb, bufB, bufA);

  // res block 2: bufA -> bufB/v1T(v1) -> convOut -> vout
  k_conv1x1<<<dim3(128,2), 256, 0, stream>>>(bufA, r2c1w, r2c1b, bufB, v1T);
  k_conv3t<128><<<dim3(128,2,2), 256, 0, stream>>>(v1T, wTr2, r2c2b, convOut);
  k_bnstats<<<128, 256, 0, stream>>>(convOut, stats);
  k_bnapply<true><<<(NE+255)/256, 256, 0, stream>>>(convOut, stats, r2bng, r2bnb, bufB, vout);
}

// Round 9
// 1349.775 us; speedup vs baseline: 1.2346x; 1.2346x over previous
//
#include <hip/hip_runtime.h>
#include <hip/hip_bf16.h>
#include <math.h>

// ---------------------------------------------------------------------------
// R9: revert R8 fusion. LSTM = 32 launches of k_step6: NO LDS staging —
//     A (x|h rows) and B (weights) read straight from L2 in a barrier-free
//     K-loop; only sG (17KB) in LDS -> 2+ blocks/CU TLP.
//     Image branch identical to R7.
// ---------------------------------------------------------------------------

namespace {

constexpr int S_ = 32, B_ = 128, H_ = 1024, P_ = 196, OC_ = 128;
constexpr int NE = B_ * OC_ * P_;        // elems of a [B][128][196] slab
constexpr int KX = 384;                  // padded x-K (300 -> 384)

typedef __attribute__((ext_vector_type(8))) short short8v;
typedef __attribute__((ext_vector_type(4))) float f32x4;
#define MFMA16(a, b, c) __builtin_amdgcn_mfma_f32_16x16x32_bf16((a), (b), (c), 0, 0, 0)

__device__ __forceinline__ float sigm(float x){ return 1.0f/(1.0f + expf(-x)); }
__device__ __forceinline__ float c0f(int p){ return ((float)p/14.0f - 7.0f)/7.0f; }
__device__ __forceinline__ float c1f(int p){ return ((float)(p%14) - 7.0f)/7.0f; }
__device__ __forceinline__ unsigned short f2bf(float x){
  __hip_bfloat16 h = __float2bfloat16(x);
  return *reinterpret_cast<unsigned short*>(&h);
}

// ---------------- weight convert f32 -> bf16, K-padded -----------------------
__global__ void k_cvtpad(const float* __restrict__ src, unsigned short* __restrict__ dst,
                         int rows, int ks, int kd){
  int i = blockIdx.x*256 + threadIdx.x;
  if (i >= rows*kd) return;
  int k = i % kd, r = i / kd;
  dst[i] = (k < ks) ? f2bf(src[r*ks + k]) : (unsigned short)0;
}

// conv weights [oc][cin][3][3] f32 -> wT [s][oc][cpad] bf16
__global__ void k_cvt_wT(const float* __restrict__ w, unsigned short* __restrict__ wT,
                         int cin, int cpad){
  int i = blockIdx.x*256 + threadIdx.x;
  if (i >= 9*128*cpad) return;
  int c = i % cpad; int t = i / cpad; int oc = t % 128; int s = t / 128;
  wT[i] = (c < cin) ? f2bf(w[((size_t)oc*cin + c)*9 + s]) : (unsigned short)0;
}

__global__ void k_bias2(const float* __restrict__ bif, const float* __restrict__ bhf,
                        const float* __restrict__ bib, const float* __restrict__ bhb,
                        float* __restrict__ out){
  int i = blockIdx.x*256 + threadIdx.x;
  if (i >= 8192) return;
  out[i] = (i < 4096) ? (bif[i] + bhf[i]) : (bib[i-4096] + bhb[i-4096]);
}

// ---------------- embedding -> bf16 x[s][b][384] ------------------------------
__global__ void k_embed_bf(const int* __restrict__ que, const float* __restrict__ emb,
                           unsigned short* __restrict__ x){
  int idx = blockIdx.x*256 + threadIdx.x;
  if (idx >= S_*B_*KX) return;
  int e = idx % KX; int sb = idx / KX; int b = sb % B_; int s = sb / B_;
  float v = 0.0f;
  if (e < 300){
    int t = que[b*S_ + s];
    if (t != 0) v = emb[t*300 + e];
  }
  x[idx] = f2bf(v);
}

// ---------------- one LSTM step via MFMA (v6: all-L2, barrier-free) -----------
// grid (64, 4): x = dir*32 + colslab, y = batch-slab. block 256 (4 waves).
// Block tile: M = 32 batch rows x N = 128 cols (4 gates x 32 units); wave =
// gate. A (x|h rows) and B (weights) read DIRECTLY from global (L2-hot);
// no staging LDS, no K-loop barrier; sG (17KB) only -> 2 blocks/CU.
__launch_bounds__(256, 2)
__global__ void k_step6(const unsigned short* __restrict__ xbf,
                        const unsigned short* __restrict__ wihc,
                        const unsigned short* __restrict__ whhc,
                        const float* __restrict__ bias2,
                        const unsigned short* __restrict__ hin,
                        unsigned short* __restrict__ hout,
                        float* __restrict__ cst, float* __restrict__ Q, int s){
  const int dir = blockIdx.x >> 5;
  const int u0  = (blockIdx.x & 31) * 32;
  const int m0g = blockIdx.y * 32;
  const int tid = threadIdx.x, wave = tid >> 6, lane = tid & 63;
  const int lr = lane & 15, lk = lane >> 4;
  const int xs = dir ? (S_-1-s) : s;

  __shared__ float sG[32][132];

  // A row pointers (invariant): rows m0g+lr and m0g+16+lr
  const unsigned short* ax0 = xbf + ((size_t)xs*B_ + m0g + lr)*KX;
  const unsigned short* ax1 = ax0 + (size_t)16*KX;
  const unsigned short* ah0 = hin + ((size_t)dir*B_ + m0g + lr)*H_;
  const unsigned short* ah1 = ah0 + (size_t)16*H_;

  // B row pointers: weight rows wave*1024 + u0 + lr (and +16)
  const int wr0 = wave*1024 + u0 + lr;
  const unsigned short* bx0 = wihc + (size_t)dir*4096*KX + (size_t)wr0*KX;
  const unsigned short* bx1 = bx0 + (size_t)16*KX;
  const unsigned short* bh0 = whhc + (size_t)dir*4096*H_ + (size_t)wr0*H_;
  const unsigned short* bh1 = bh0 + (size_t)16*H_;

  f32x4 acc00{0,0,0,0}, acc01{0,0,0,0}, acc10{0,0,0,0}, acc11{0,0,0,0};

  // ---- x-part: 12 chunks of 32 ----
  #pragma unroll 4
  for (int ch = 0; ch < 12; ++ch){
    const int ko = ch*32 + lk*8;
    short8v a0 = *(const short8v*)(ax0 + ko);
    short8v a1 = *(const short8v*)(ax1 + ko);
    short8v b0 = *(const short8v*)(bx0 + ko);
    short8v b1 = *(const short8v*)(bx1 + ko);
    acc00 = MFMA16(a0, b0, acc00); acc01 = MFMA16(a0, b1, acc01);
    acc10 = MFMA16(a1, b0, acc10); acc11 = MFMA16(a1, b1, acc11);
  }
  // ---- h-part: 32 chunks of 32 ----
  #pragma unroll 8
  for (int ch = 0; ch < 32; ++ch){
    const int ko = ch*32 + lk*8;
    short8v a0 = *(const short8v*)(ah0 + ko);
    short8v a1 = *(const short8v*)(ah1 + ko);
    short8v b0 = *(const short8v*)(bh0 + ko);
    short8v b1 = *(const short8v*)(bh1 + ko);
    acc00 = MFMA16(a0, b0, acc00); acc01 = MFMA16(a0, b1, acc01);
    acc10 = MFMA16(a1, b0, acc10); acc11 = MFMA16(a1, b1, acc11);
  }

  // ---- recombine: C row = lk*4+j (+16), col = wave*32 + ci*16 + lr ----
  #pragma unroll
  for (int j = 0; j < 4; ++j){
    const int rr = lk*4 + j;
    sG[rr][wave*32 + lr]            = acc00[j];
    sG[rr][wave*32 + 16 + lr]       = acc01[j];
    sG[16 + rr][wave*32 + lr]       = acc10[j];
    sG[16 + rr][wave*32 + 16 + lr]  = acc11[j];
  }
  __syncthreads();

  // ---- gate math: 32 m x 32 units, 4 tasks/thread ----
  const float* bb = bias2 + (size_t)dir*4096;
  float* cc = cst + (size_t)dir*B_*H_;
  unsigned short* ho = hout + (size_t)dir*B_*H_;
  #pragma unroll
  for (int t = 0; t < 4; ++t){
    const int idx = tid + t*256;
    const int m = idx >> 5, u = idx & 31;
    const int ug = u0 + u, mg = m0g + m;
    float gi = sG[m][u]      + bb[ug];
    float gf = sG[m][32+u]   + bb[1024+ug];
    float gg = sG[m][64+u]   + bb[2048+ug];
    float go = sG[m][96+u]   + bb[3072+ug];
    float cold = cc[mg*H_ + ug];
    float cn = sigm(gf)*cold + sigm(gi)*tanhf(gg);
    float hn = sigm(go)*tanhf(cn);
    cc[mg*H_ + ug] = cn;
    ho[(size_t)mg*H_ + ug] = f2bf(hn);
    Q[((size_t)xs*B_ + mg)*2048 + dir*1024 + ug] = hn;
  }
}

// ---------------- qenc L2-normalize (in-place) + enc --------------------------
__global__ void k_qnorm(float* __restrict__ Q, float* __restrict__ enc){
  int sb = blockIdx.x;
  int s = sb >> 7, b = sb & 127;
  float* row = Q + (size_t)sb*2048;
  int tid = threadIdx.x;
  float v[8]; float ss = 0.f;
  #pragma unroll
  for (int i = 0; i < 8; ++i){ v[i] = row[tid*8+i]; ss += v[i]*v[i]; }
  __shared__ float red[256];
  red[tid] = ss; __syncthreads();
  for (int st = 128; st; st >>= 1){
    if (tid < st) red[tid] += red[tid+st];
    __syncthreads();
  }
  float inv = 1.0f / fmaxf(sqrtf(red[0]), 1e-12f);
  #pragma unroll
  for (int i = 0; i < 8; ++i){
    float q = v[i]*inv;
    row[tid*8+i] = q;
    if (s == S_-1) enc[(size_t)b*2048 + tid*8 + i] = q;
  }
}

// ---------------- per-pixel channel sumsq of img ------------------------------
__global__ void k_sqpart(const float* __restrict__ img, float* __restrict__ part){
  int b = blockIdx.x, cq = blockIdx.y;
  int t = threadIdx.x;
  if (t >= P_) return;
  const float* base = img + ((size_t)b*1024 + cq*256)*P_ + t;
  float s = 0.f;
  #pragma unroll 4
  for (int c = 0; c < 256; ++c){ float v = base[c*P_]; s += v*v; }
  part[((size_t)b*4 + cq)*P_ + t] = s;
}

__global__ void k_invnorm(const float* __restrict__ part, float* __restrict__ inv){
  int i = blockIdx.x*256 + threadIdx.x;
  if (i >= B_*P_) return;
  int b = i / P_, p = i % P_;
  float s = part[(b*4+0)*P_+p] + part[(b*4+1)*P_+p]
          + part[(b*4+2)*P_+p] + part[(b*4+3)*P_+p];
  inv[i] = 1.0f / fmaxf(sqrtf(s), 1e-12f);
}

// ---------------- img -> imgT[b][196][1056] bf16 (invnorm+coords+pad) ---------
__global__ void k_mkimgT(const float* __restrict__ img, const float* __restrict__ invn,
                         unsigned short* __restrict__ imgT){
  const int b = blockIdx.x, cg = blockIdx.y;
  const int tid = threadIdx.x;
  unsigned short* dstB = imgT + (size_t)b*196*1056;
  if (cg == 8){           // coord channels 1024,1025 + zero pad to 1055
    for (int i = tid; i < 196*32; i += 256){
      int p = i >> 5, cc = i & 31;
      float v = (cc == 0) ? c0f(p) : (cc == 1) ? c1f(p) : 0.f;
      dstB[(size_t)p*1056 + 1024 + cc] = f2bf(v);
    }
    return;
  }
  __shared__ unsigned short tt[196][136];
  __shared__ float sInv[200];
  for (int i = tid; i < 196; i += 256) sInv[i] = invn[b*196 + i];
  __syncthreads();
  const int c0 = cg*128;
  const float* srcB = img + ((size_t)b*1024 + c0)*196;
  for (int i = tid; i < 128*49; i += 256){
    int c = i / 49, p4 = i - (i/49)*49;
    float4 v = *(const float4*)(srcB + (size_t)c*196 + p4*4);
    int p = p4*4;
    tt[p+0][c] = f2bf(v.x * sInv[p+0]);
    tt[p+1][c] = f2bf(v.y * sInv[p+1]);
    tt[p+2][c] = f2bf(v.z * sInv[p+2]);
    tt[p+3][c] = f2bf(v.w * sInv[p+3]);
  }
  __syncthreads();
  for (int i = tid; i < 196*16; i += 256){
    int p = i >> 4, g = i & 15;
    *(short8v*)(dstB + (size_t)p*1056 + c0 + g*8) = *(short8v*)&tt[p][g*8];
  }
}

// ---------------- 3x3 conv via MFMA (T-layout input, N-split rows) ------------
template<int CPAD>
__device__ __forceinline__ void stage3t(unsigned short (*__restrict__ tile)[40],
                                        const unsigned short* __restrict__ src,
                                        int c0, int r0, int tid){
  for (int i = tid; i < 10*14*4; i += 256){
    int t = i / 56, rem = i - t*56, gx = rem >> 2, seg = rem & 3;
    int gy = r0 - 1 + t;
    if ((unsigned)gy < 14u){
      short8v v = *(const short8v*)(src + (size_t)(gy*14+gx)*CPAD + c0 + seg*8);
      *(short8v*)&tile[t*16 + gx + 1][seg*8] = v;
    }
  }
}

template<int CPAD>
__launch_bounds__(256, 2)
__global__ void k_conv3t(const unsigned short* __restrict__ srcT,
                         const unsigned short* __restrict__ wT,
                         const float* __restrict__ bias,
                         float* __restrict__ out){
  constexpr int T = CPAD / 32;
  const int b = blockIdx.x, n = blockIdx.y, z = blockIdx.z;
  const int r0 = n ? 6 : 0;
  const int chBeg = z ? T/2 : 0, chEnd = z ? T : T/2;
  const int tid = threadIdx.x, wave = tid >> 6, lane = tid & 63;
  const int lr = lane & 15, lk = lane >> 4;
  const int wfM = wave >> 1, wfN = wave & 1;
  const unsigned short* src = srcT + (size_t)b*196*CPAD;

  __shared__ unsigned short tile[2][164][40];

  for (int i = tid; i < 1640; i += 256)
    ((short8v*)&tile[0][0][0])[i] = short8v{0,0,0,0,0,0,0,0};
  __syncthreads();
  stage3t<CPAD>(tile[0], src, chBeg*32, r0, tid);
  __syncthreads();

  f32x4 acc[4][4];
  #pragma unroll
  for (int i = 0; i < 4; ++i)
    #pragma unroll
    for (int j = 0; j < 4; ++j) acc[i][j] = f32x4{0,0,0,0};

  for (int ch = chBeg; ch < chEnd; ++ch){
    const int cur = (ch - chBeg) & 1;
    #pragma unroll
    for (int dy = 0; dy < 3; ++dy){
      #pragma unroll
      for (int dx = 0; dx < 3; ++dx){
        const int dlt = dy*16 + dx;
        short8v a[4];
        #pragma unroll
        for (int rf = 0; rf < 4; ++rf)
          a[rf] = *(const short8v*)(wT + ((size_t)((dy*3+dx)*128) + wfM*64 + rf*16 + lr)*CPAD
                                       + ch*32 + lk*8);
        #pragma unroll
        for (int cf = 0; cf < 4; ++cf){
          short8v bf = *(short8v*)&tile[cur][wfN*64 + cf*16 + lr + dlt][lk*8];
          #pragma unroll
          for (int rf = 0; rf < 4; ++rf)
            acc[rf][cf] = MFMA16(a[rf], bf, acc[rf][cf]);
        }
      }
      if (dy == 0 && ch + 1 < chEnd)
        stage3t<CPAD>(tile[cur^1], src, (ch+1)*32, r0, tid);
    }
    __syncthreads();
  }

  #pragma unroll
  for (int rf = 0; rf < 4; ++rf){
    #pragma unroll
    for (int j = 0; j < 4; ++j){
      const int oc = wfM*64 + rf*16 + lk*4 + j;
      const float bz = z ? 0.f : bias[oc];
      #pragma unroll
      for (int cf = 0; cf < 4; ++cf){
        const int pos = wfN*64 + cf*16 + lr;
        const int py = r0 + (pos >> 4), px = pos & 15;
        const bool rowok = n ? (py >= 8) : true;
        if (rowok && px < 14)
          out[(size_t)z*NE + ((size_t)b*OC_ + oc)*P_ + py*14 + px] = acc[rf][cf][j] + bz;
      }
    }
  }
}

// ---------------- BN stats over 2 partial slabs -------------------------------
__global__ void k_bnstats(const float* __restrict__ t, float* __restrict__ stats){
  int o = blockIdx.x;
  int tid = threadIdx.x;
  float s = 0.f, s2 = 0.f;
  #pragma unroll 4
  for (int i = tid; i < B_*P_; i += 256){
    int b = i / P_, p = i - (i/P_)*P_;
    size_t off = ((size_t)b*OC_ + o)*P_ + p;
    float v = t[off] + t[off + NE];
    s += v; s2 += v*v;
  }
  __shared__ float r1[256], r2[256];
  r1[tid] = s; r2[tid] = s2; __syncthreads();
  for (int st = 128; st; st >>= 1){
    if (tid < st){ r1[tid] += r1[tid+st]; r2[tid] += r2[tid+st]; }
    __syncthreads();
  }
  if (tid == 0){
    float n = (float)(B_*P_);
    float m = r1[0] / n;
    float var = r2[0] / n - m*m;
    stats[o*2]   = m;
    stats[o*2+1] = rsqrtf(var + 1e-5f);
  }
}

// ---------------- BN apply + relu (+ optional residual add) -------------------
template<bool ADD>
__global__ void k_bnapply(const float* __restrict__ t, const float* __restrict__ stats,
                          const float* __restrict__ g, const float* __restrict__ bb,
                          const float* __restrict__ addsrc, float* __restrict__ out){
  int idx = blockIdx.x*256 + threadIdx.x;
  if (idx >= NE) return;
  int o = (idx / P_) % OC_;
  float m = stats[o*2], is = stats[o*2+1];
  float x = t[idx] + t[idx + NE];
  float v = g[o]*(x-m)*is + bb[o];
  v = fmaxf(v, 0.f);
  if (ADD) v += addsrc[idx];
  out[idx] = v;
}

// ---------------- 1x1 conv + relu; writes f32 [b][c][p] AND bf16 [b][p][c] ----
__launch_bounds__(256)
__global__ void k_conv1x1(const float* __restrict__ vin, const float* __restrict__ w,
                          const float* __restrict__ bias, float* __restrict__ out,
                          unsigned short* __restrict__ outT){
  const int b  = blockIdx.x;
  const int o0 = blockIdx.y * 64;
  const int tid = threadIdx.x;
  const int olane = tid & 63, pg = tid >> 6;
  const int o = o0 + olane;

  __shared__ float sV[32][196];
  __shared__ float sW[64][33];

  float acc[49];
  #pragma unroll
  for (int p = 0; p < 49; ++p) acc[p] = 0.f;

  for (int ch = 0; ch < 128; ch += 32){
    __syncthreads();
    for (int i = tid; i < 32*196; i += 256){
      int c = i / 196, p = i - c*196;
      sV[c][p] = vin[((size_t)b*128 + ch + c)*P_ + p];
    }
    for (int i = tid; i < 64*32; i += 256){
      int ol = i >> 5, c = i & 31;
      sW[ol][c] = w[(size_t)(o0+ol)*130 + ch + c];
    }
    __syncthreads();
    for (int c = 0; c < 32; ++c){
      float wv = sW[olane][c];
      #pragma unroll
      for (int p = 0; p < 49; ++p) acc[p] += sV[c][pg*49 + p] * wv;
    }
  }
  float w0 = w[(size_t)o*130 + 128], w1 = w[(size_t)o*130 + 129], bz = bias[o];
  #pragma unroll
  for (int p = 0; p < 49; ++p){
    int pp = pg*49 + p;
    float v = acc[p] + w0*c0f(pp) + w1*c1f(pp) + bz;
    v = fmaxf(v, 0.f);
    out[((size_t)b*128 + o)*P_ + pp] = v;
    outT[((size_t)b*P_ + pp)*128 + o] = f2bf(v);
  }
}

} // namespace

// ---------------------------------------------------------------------------
extern "C" void kernel_launch(void* const* d_in, const int* in_sizes, int n_in,
                              void* d_out, int out_size, void* d_ws, size_t ws_size,
                              hipStream_t stream){
  (void)in_sizes; (void)n_in; (void)out_size; (void)ws_size;
  const int*   que  = (const int*)  d_in[0];
  const float* img  = (const float*)d_in[1];
  const float* emb  = (const float*)d_in[2];
  const float* wihf = (const float*)d_in[3];
  const float* whhf = (const float*)d_in[4];
  const float* bihf = (const float*)d_in[5];
  const float* bhhf = (const float*)d_in[6];
  const float* wihb = (const float*)d_in[7];
  const float* whhb = (const float*)d_in[8];
  const float* bihb = (const float*)d_in[9];
  const float* bhhb = (const float*)d_in[10];
  const float* convw = (const float*)d_in[11];
  const float* convb = (const float*)d_in[12];
  const float* bng  = (const float*)d_in[13];
  const float* bnb  = (const float*)d_in[14];
  const float* r1c1w = (const float*)d_in[15];
  const float* r1c1b = (const float*)d_in[16];
  const float* r1c2w = (const float*)d_in[17];
  const float* r1c2b = (const float*)d_in[18];
  const float* r1bng = (const float*)d_in[19];
  const float* r1bnb = (const float*)d_in[20];
  const float* r2c1w = (const float*)d_in[21];
  const float* r2c1b = (const float*)d_in[22];
  const float* r2c2w = (const float*)d_in[23];
  const float* r2c2b = (const float*)d_in[24];
  const float* r2bng = (const float*)d_in[25];
  const float* r2bnb = (const float*)d_in[26];

  float* out  = (float*)d_out;
  float* enc  = out;                        // 128*2048
  float* Q    = out + 262144;               // 32*128*2048
  float* vout = out + 262144 + 8388608;     // 128*128*196

  // ------ workspace layout (f32 units) ----------------------------------------
  float* ws = (float*)d_ws;
  unsigned short* xbf  = (unsigned short*)ws;            // 32*128*384 bf16
  float* p1 = ws + 786432;
  unsigned short* wihc = (unsigned short*)p1;            // 2*4096*384 bf16
  float* p2 = p1 + 1572864;
  unsigned short* whhc = (unsigned short*)p2;            // 2*4096*1024 bf16
  float* p3 = p2 + 4194304;
  float* bias2 = p3;                                     // 2*4096
  float* p4 = p3 + 8192;
  unsigned short* hstate = (unsigned short*)p4;          // 2par*2dir*128*1024 bf16
  float* p5 = p4 + 262144;
  float* cstate = p5;                                    // 2*128*1024
  float* p6 = p5 + 262144;
  float* part = p6;                                      // 128*4*196
  float* invn = p6 + 100352;                             // 128*196
  float* bufA = invn + 25088;                            // NE
  float* bufB = bufA + NE;                               // NE
  float* convOut = bufB + NE;                            // 2*NE partial slabs
  float* p7 = convOut + 2*(size_t)NE;
  float* stats = p7;                                     // 256
  float* p8 = p7 + 256;
  unsigned short* wTc  = (unsigned short*)p8;            // 9*128*1056 bf16
  float* p9 = p8 + 608256;
  unsigned short* wTr1 = (unsigned short*)p9;            // 9*128*128 bf16
  float* p10 = p9 + 73728;
  unsigned short* wTr2 = (unsigned short*)p10;           // 9*128*128 bf16
  float* p11 = p10 + 73728;
  unsigned short* imgT = (unsigned short*)p11;           // 128*196*1056 bf16
  float* p12 = p11 + 13246464;
  unsigned short* v1T  = (unsigned short*)p12;           // 128*196*128 bf16

  // zero h (both parities) + c state (contiguous 2 MB)
  hipMemsetAsync(hstate, 0, (size_t)(262144 + 262144)*sizeof(float), stream);

  // ------ conversions ---------------------------------------------------------
  k_cvtpad<<<6144, 256, 0, stream>>>(wihf, wihc,                     4096, 300, KX);
  k_cvtpad<<<6144, 256, 0, stream>>>(wihb, wihc + (size_t)4096*KX,   4096, 300, KX);
  k_cvtpad<<<16384,256, 0, stream>>>(whhf, whhc,                     4096, 1024, 1024);
  k_cvtpad<<<16384,256, 0, stream>>>(whhb, whhc + (size_t)4096*1024, 4096, 1024, 1024);
  k_bias2<<<32, 256, 0, stream>>>(bihf, bhhf, bihb, bhhb, bias2);
  k_embed_bf<<<6144, 256, 0, stream>>>(que, emb, xbf);
  k_cvt_wT<<<(9*128*1056 + 255)/256, 256, 0, stream>>>(convw, wTc, 1026, 1056);
  k_cvt_wT<<<(9*128*128 + 255)/256, 256, 0, stream>>>(r1c2w, wTr1, 128, 128);
  k_cvt_wT<<<(9*128*128 + 255)/256, 256, 0, stream>>>(r2c2w, wTr2, 128, 128);

  // ------ bi-LSTM: 32 barrier-free-step launches -------------------------------
  for (int s = 0; s < 32; ++s){
    unsigned short* hin  = hstate + (size_t)(s & 1)*262144;
    unsigned short* hout = hstate + (size_t)((s & 1)^1)*262144;
    k_step6<<<dim3(64,4), 256, 0, stream>>>(xbf, wihc, whhc, bias2,
                                            hin, hout, cstate, Q, s);
  }
  k_qnorm<<<4096, 256, 0, stream>>>(Q, enc);

  // ------ image branch --------------------------------------------------------
  k_sqpart<<<dim3(128,4), 256, 0, stream>>>(img, part);
  k_invnorm<<<(25088+255)/256, 256, 0, stream>>>(part, invn);
  k_mkimgT<<<dim3(128,9), 256, 0, stream>>>(img, invn, imgT);

  k_conv3t<1056><<<dim3(128,2,2), 256, 0, stream>>>(imgT, wTc, convb, convOut);
  k_bnstats<<<128, 256, 0, stream>>>(convOut, stats);
  k_bnapply<false><<<(NE+255)/256, 256, 0, stream>>>(convOut, stats, bng, bnb, bufA, bufA);

  // res block 1: bufA(v) -> bufB/v1T(v1) -> convOut -> bufA(v2+v1)
  k_conv1x1<<<dim3(128,2), 256, 0, stream>>>(bufA, r1c1w, r1c1b, bufB, v1T);
  k_conv3t<128><<<dim3(128,2,2), 256, 0, stream>>>(v1T, wTr1, r1c2b, convOut);
  k_bnstats<<<128, 256, 0, stream>>>(convOut, stats);
  k_bnapply<true><<<(NE+255)/256, 256, 0, stream>>>(convOut, stats, r1bng, r1bnb, bufB, bufA);

  // res block 2: bufA -> bufB/v1T(v1) -> convOut -> vout
  k_conv1x1<<<dim3(128,2), 256, 0, stream>>>(bufA, r2c1w, r2c1b, bufB, v1T);
  k_conv3t<128><<<dim3(128,2,2), 256, 0, stream>>>(v1T, wTr2, r2c2b, convOut);
  k_bnstats<<<128, 256, 0, stream>>>(convOut, stats);
  k_bnapply<true><<<(NE+255)/256, 256, 0, stream>>>(convOut, stats, r2bng, r2bnb, bufB, vout);
}

// Round 10
// 1083.225 us; speedup vs baseline: 1.5384x; 1.2461x over previous
//
#include <hip/hip_runtime.h>
#include <hip/hip_bf16.h>
#include <math.h>

// ---------------------------------------------------------------------------
// R10: fragment-order weight packing. All MFMA weight operands pre-packed as
//      [16row x 32k] tiles in per-lane order -> every weight fragment load is
//      one coalesced 1KB wave-load (base + lane*16B). LSTM back to the staged-A
//      barrier-free structure (k_step7 = k_step5 + packed B). conv3t A-frags
//      from packed tiles. Image branch otherwise identical to R7.
// ---------------------------------------------------------------------------

namespace {

constexpr int S_ = 32, B_ = 128, H_ = 1024, P_ = 196, OC_ = 128;
constexpr int NE = B_ * OC_ * P_;        // elems of a [B][128][196] slab
constexpr int KX = 384;                  // padded x-K (300 -> 384)
constexpr int KC = 44;                   // K chunks: 12 x + 32 h

typedef __attribute__((ext_vector_type(8))) short short8v;
typedef __attribute__((ext_vector_type(4))) float f32x4;
#define MFMA16(a, b, c) __builtin_amdgcn_mfma_f32_16x16x32_bf16((a), (b), (c), 0, 0, 0)

__device__ __forceinline__ float sigm(float x){ return 1.0f/(1.0f + expf(-x)); }
__device__ __forceinline__ float c0f(int p){ return ((float)p/14.0f - 7.0f)/7.0f; }
__device__ __forceinline__ float c1f(int p){ return ((float)(p%14) - 7.0f)/7.0f; }
__device__ __forceinline__ unsigned short f2bf(float x){
  __hip_bfloat16 h = __float2bfloat16(x);
  return *reinterpret_cast<unsigned short*>(&h);
}

// ---------------- LSTM weights -> fragment-order pack -------------------------
// pk[dir][g(256)][kc(44)][lane(64)][8]: lane holds W[row=g*16+(lane&15)]
// [k = kc*32+(lane>>4)*8+j]; kc<12 -> Wih (K=300, zero-pad to 384), else Whh.
__global__ void k_packW(const float* __restrict__ wihf, const float* __restrict__ whhf,
                        const float* __restrict__ wihb, const float* __restrict__ whhb,
                        unsigned short* __restrict__ pk){
  int i = blockIdx.x*256 + threadIdx.x;
  if (i >= 2*256*KC*64) return;
  const int lane = i & 63;
  int t = i >> 6;
  const int kc = t % KC; t /= KC;
  const int g  = t % 256; t /= 256;
  const int dir = t;
  const int row = g*16 + (lane & 15);
  const int k0  = (lane >> 4)*8;
  unsigned short v[8];
  if (kc < 12){
    const float* src = dir ? wihb : wihf;
    #pragma unroll
    for (int j = 0; j < 8; ++j){
      int kcol = kc*32 + k0 + j;
      v[j] = (kcol < 300) ? f2bf(src[(size_t)row*300 + kcol]) : (unsigned short)0;
    }
  } else {
    const float* src = dir ? whhb : whhf;
    #pragma unroll
    for (int j = 0; j < 8; ++j)
      v[j] = f2bf(src[(size_t)row*1024 + (kc-12)*32 + k0 + j]);
  }
  unsigned short* dst = pk + (((size_t)(dir*256 + g)*KC + kc)*64 + lane)*8;
  #pragma unroll
  for (int j = 0; j < 8; ++j) dst[j] = v[j];
}

// ---------------- conv weights -> fragment-order pack -------------------------
// pk[s(9)][ot(8)][kc(T)][lane(64)][8]: lane holds W[oc=ot*16+(lane&15)]
// [c = kc*32+(lane>>4)*8+j] for shift s; zero-pad c >= cin.
__global__ void k_packC(const float* __restrict__ w, unsigned short* __restrict__ pk,
                        int cin, int T){
  int i = blockIdx.x*256 + threadIdx.x;
  if (i >= 9*8*T*64) return;
  const int lane = i & 63;
  int t = i >> 6;
  const int kc = t % T; t /= T;
  const int ot = t % 8; t /= 8;
  const int s = t;
  const int oc = ot*16 + (lane & 15);
  const int c0 = kc*32 + (lane >> 4)*8;
  unsigned short* dst = pk + (((size_t)(s*8 + ot)*T + kc)*64 + lane)*8;
  #pragma unroll
  for (int j = 0; j < 8; ++j){
    int c = c0 + j;
    dst[j] = (c < cin) ? f2bf(w[((size_t)oc*cin + c)*9 + s]) : (unsigned short)0;
  }
}

__global__ void k_bias2(const float* __restrict__ bif, const float* __restrict__ bhf,
                        const float* __restrict__ bib, const float* __restrict__ bhb,
                        float* __restrict__ out){
  int i = blockIdx.x*256 + threadIdx.x;
  if (i >= 8192) return;
  out[i] = (i < 4096) ? (bif[i] + bhf[i]) : (bib[i-4096] + bhb[i-4096]);
}

// ---------------- embedding -> bf16 x[s][b][384] ------------------------------
__global__ void k_embed_bf(const int* __restrict__ que, const float* __restrict__ emb,
                           unsigned short* __restrict__ x){
  int idx = blockIdx.x*256 + threadIdx.x;
  if (idx >= S_*B_*KX) return;
  int e = idx % KX; int sb = idx / KX; int b = sb % B_; int s = sb / B_;
  float v = 0.0f;
  if (e < 300){
    int t = que[b*S_ + s];
    if (t != 0) v = emb[t*300 + e];
  }
  x[idx] = f2bf(v);
}

// ---------------- one LSTM step (v7: staged-A + packed-B, barrier-free) -------
// grid (64, 4): x = dir*32 + colslab, y = batch-slab. block 256 (4 waves).
// Block tile: M = 32 batch rows x N = 128 cols (4 gates x 32 units; wave =
// gate). A (x|h, 32x1408) staged once into LDS; B = packed fragment tiles,
// each load = base + lane*16B (fully coalesced). 44-chunk barrier-free K-loop.
__launch_bounds__(256, 1)
__global__ void k_step7(const unsigned short* __restrict__ xbf,
                        const unsigned short* __restrict__ pkW,
                        const float* __restrict__ bias2,
                        const unsigned short* __restrict__ hin,
                        unsigned short* __restrict__ hout,
                        float* __restrict__ cst, float* __restrict__ Q, int s){
  const int dir = blockIdx.x >> 5;
  const int u0  = (blockIdx.x & 31) * 32;
  const int m0g = blockIdx.y * 32;
  const int tid = threadIdx.x, wave = tid >> 6, lane = tid & 63;
  const int lr = lane & 15, lk = lane >> 4;
  const int xs = dir ? (S_-1-s) : s;

  __shared__ unsigned short tA[32][1416];   // [m][k] (x 0..383 | h 384..1407)
  __shared__ float sG[32][132];

  // ---- stage A once: 22 independent 16B loads/thread ----
  {
    const int r = tid >> 3, sg = tid & 7;
    const unsigned short* xr = xbf + ((size_t)xs*B_ + m0g + r)*KX + sg*48;
    #pragma unroll
    for (int q = 0; q < 6; ++q)
      *(short8v*)&tA[r][sg*48 + q*8] = *(const short8v*)(xr + q*8);
    const unsigned short* hr = hin + ((size_t)dir*B_ + m0g + r)*H_ + sg*128;
    #pragma unroll
    for (int q = 0; q < 16; ++q)
      *(short8v*)&tA[r][384 + sg*128 + q*8] = *(const short8v*)(hr + q*8);
  }
  __syncthreads();

  // packed-B bases: group g0 = wave*64 + u0/16, g1 = g0+1
  const unsigned short* pw0 = pkW + (((size_t)(dir*256 + wave*64 + (u0 >> 4))*KC)*64
                                     + lane)*8;
  const unsigned short* pw1 = pw0 + (size_t)KC*64*8;

  f32x4 acc00{0,0,0,0}, acc01{0,0,0,0}, acc10{0,0,0,0}, acc11{0,0,0,0};

  #pragma unroll 4
  for (int ch = 0; ch < KC; ++ch){
    const int ka = ch*32 + lk*8;
    short8v a0 = *(short8v*)&tA[lr][ka];
    short8v a1 = *(short8v*)&tA[16 + lr][ka];
    short8v b0 = *(const short8v*)(pw0 + (size_t)ch*512);
    short8v b1 = *(const short8v*)(pw1 + (size_t)ch*512);
    acc00 = MFMA16(a0, b0, acc00); acc01 = MFMA16(a0, b1, acc01);
    acc10 = MFMA16(a1, b0, acc10); acc11 = MFMA16(a1, b1, acc11);
  }

  // ---- recombine: C row = lk*4+j (+16), col = wave*32 + ci*16 + lr ----
  #pragma unroll
  for (int j = 0; j < 4; ++j){
    const int rr = lk*4 + j;
    sG[rr][wave*32 + lr]            = acc00[j];
    sG[rr][wave*32 + 16 + lr]       = acc01[j];
    sG[16 + rr][wave*32 + lr]       = acc10[j];
    sG[16 + rr][wave*32 + 16 + lr]  = acc11[j];
  }
  __syncthreads();

  // ---- gate math ----
  const float* bb = bias2 + (size_t)dir*4096;
  float* cc = cst + (size_t)dir*B_*H_;
  unsigned short* ho = hout + (size_t)dir*B_*H_;
  #pragma unroll
  for (int t = 0; t < 4; ++t){
    const int idx = tid + t*256;
    const int m = idx >> 5, u = idx & 31;
    const int ug = u0 + u, mg = m0g + m;
    float gi = sG[m][u]      + bb[ug];
    float gf = sG[m][32+u]   + bb[1024+ug];
    float gg = sG[m][64+u]   + bb[2048+ug];
    float go = sG[m][96+u]   + bb[3072+ug];
    float cold = cc[mg*H_ + ug];
    float cn = sigm(gf)*cold + sigm(gi)*tanhf(gg);
    float hn = sigm(go)*tanhf(cn);
    cc[mg*H_ + ug] = cn;
    ho[(size_t)mg*H_ + ug] = f2bf(hn);
    Q[((size_t)xs*B_ + mg)*2048 + dir*1024 + ug] = hn;
  }
}

// ---------------- qenc L2-normalize (in-place) + enc --------------------------
__global__ void k_qnorm(float* __restrict__ Q, float* __restrict__ enc){
  int sb = blockIdx.x;
  int s = sb >> 7, b = sb & 127;
  float* row = Q + (size_t)sb*2048;
  int tid = threadIdx.x;
  float v[8]; float ss = 0.f;
  #pragma unroll
  for (int i = 0; i < 8; ++i){ v[i] = row[tid*8+i]; ss += v[i]*v[i]; }
  __shared__ float red[256];
  red[tid] = ss; __syncthreads();
  for (int st = 128; st; st >>= 1){
    if (tid < st) red[tid] += red[tid+st];
    __syncthreads();
  }
  float inv = 1.0f / fmaxf(sqrtf(red[0]), 1e-12f);
  #pragma unroll
  for (int i = 0; i < 8; ++i){
    float q = v[i]*inv;
    row[tid*8+i] = q;
    if (s == S_-1) enc[(size_t)b*2048 + tid*8 + i] = q;
  }
}

// ---------------- per-pixel channel sumsq of img ------------------------------
__global__ void k_sqpart(const float* __restrict__ img, float* __restrict__ part){
  int b = blockIdx.x, cq = blockIdx.y;
  int t = threadIdx.x;
  if (t >= P_) return;
  const float* base = img + ((size_t)b*1024 + cq*256)*P_ + t;
  float s = 0.f;
  #pragma unroll 4
  for (int c = 0; c < 256; ++c){ float v = base[c*P_]; s += v*v; }
  part[((size_t)b*4 + cq)*P_ + t] = s;
}

__global__ void k_invnorm(const float* __restrict__ part, float* __restrict__ inv){
  int i = blockIdx.x*256 + threadIdx.x;
  if (i >= B_*P_) return;
  int b = i / P_, p = i % P_;
  float s = part[(b*4+0)*P_+p] + part[(b*4+1)*P_+p]
          + part[(b*4+2)*P_+p] + part[(b*4+3)*P_+p];
  inv[i] = 1.0f / fmaxf(sqrtf(s), 1e-12f);
}

// ---------------- img -> imgT[b][196][1056] bf16 (invnorm+coords+pad) ---------
__global__ void k_mkimgT(const float* __restrict__ img, const float* __restrict__ invn,
                         unsigned short* __restrict__ imgT){
  const int b = blockIdx.x, cg = blockIdx.y;
  const int tid = threadIdx.x;
  unsigned short* dstB = imgT + (size_t)b*196*1056;
  if (cg == 8){           // coord channels 1024,1025 + zero pad to 1055
    for (int i = tid; i < 196*32; i += 256){
      int p = i >> 5, cc = i & 31;
      float v = (cc == 0) ? c0f(p) : (cc == 1) ? c1f(p) : 0.f;
      dstB[(size_t)p*1056 + 1024 + cc] = f2bf(v);
    }
    return;
  }
  __shared__ unsigned short tt[196][136];
  __shared__ float sInv[200];
  for (int i = tid; i < 196; i += 256) sInv[i] = invn[b*196 + i];
  __syncthreads();
  const int c0 = cg*128;
  const float* srcB = img + ((size_t)b*1024 + c0)*196;
  for (int i = tid; i < 128*49; i += 256){
    int c = i / 49, p4 = i - (i/49)*49;
    float4 v = *(const float4*)(srcB + (size_t)c*196 + p4*4);
    int p = p4*4;
    tt[p+0][c] = f2bf(v.x * sInv[p+0]);
    tt[p+1][c] = f2bf(v.y * sInv[p+1]);
    tt[p+2][c] = f2bf(v.z * sInv[p+2]);
    tt[p+3][c] = f2bf(v.w * sInv[p+3]);
  }
  __syncthreads();
  for (int i = tid; i < 196*16; i += 256){
    int p = i >> 4, g = i & 15;
    *(short8v*)(dstB + (size_t)p*1056 + c0 + g*8) = *(short8v*)&tt[p][g*8];
  }
}

// ---------------- 3x3 conv via MFMA (T-layout input, packed weights) ----------
template<int CPAD>
__device__ __forceinline__ void stage3t(unsigned short (*__restrict__ tile)[40],
                                        const unsigned short* __restrict__ src,
                                        int c0, int r0, int tid){
  for (int i = tid; i < 10*14*4; i += 256){
    int t = i / 56, rem = i - t*56, gx = rem >> 2, seg = rem & 3;
    int gy = r0 - 1 + t;
    if ((unsigned)gy < 14u){
      short8v v = *(const short8v*)(src + (size_t)(gy*14+gx)*CPAD + c0 + seg*8);
      *(short8v*)&tile[t*16 + gx + 1][seg*8] = v;
    }
  }
}

template<int CPAD>
__launch_bounds__(256, 2)
__global__ void k_conv3t(const unsigned short* __restrict__ srcT,
                         const unsigned short* __restrict__ wPk,
                         const float* __restrict__ bias,
                         float* __restrict__ out){
  constexpr int T = CPAD / 32;
  const int b = blockIdx.x, n = blockIdx.y, z = blockIdx.z;
  const int r0 = n ? 6 : 0;
  const int chBeg = z ? T/2 : 0, chEnd = z ? T : T/2;
  const int tid = threadIdx.x, wave = tid >> 6, lane = tid & 63;
  const int lr = lane & 15, lk = lane >> 4;
  const int wfM = wave >> 1, wfN = wave & 1;
  const unsigned short* src = srcT + (size_t)b*196*CPAD;

  __shared__ unsigned short tile[2][164][40];

  for (int i = tid; i < 1640; i += 256)
    ((short8v*)&tile[0][0][0])[i] = short8v{0,0,0,0,0,0,0,0};
  __syncthreads();
  stage3t<CPAD>(tile[0], src, chBeg*32, r0, tid);
  __syncthreads();

  f32x4 acc[4][4];
  #pragma unroll
  for (int i = 0; i < 4; ++i)
    #pragma unroll
    for (int j = 0; j < 4; ++j) acc[i][j] = f32x4{0,0,0,0};

  for (int ch = chBeg; ch < chEnd; ++ch){
    const int cur = (ch - chBeg) & 1;
    #pragma unroll
    for (int dy = 0; dy < 3; ++dy){
      #pragma unroll
      for (int dx = 0; dx < 3; ++dx){
        const int dlt = dy*16 + dx;
        short8v a[4];
        #pragma unroll
        for (int rf = 0; rf < 4; ++rf)
          a[rf] = *(const short8v*)(wPk + ((((size_t)(dy*3+dx)*8 + wfM*4 + rf)*T + ch)*64
                                           + lane)*8);
        #pragma unroll
        for (int cf = 0; cf < 4; ++cf){
          short8v bf = *(short8v*)&tile[cur][wfN*64 + cf*16 + lr + dlt][lk*8];
          #pragma unroll
          for (int rf = 0; rf < 4; ++rf)
            acc[rf][cf] = MFMA16(a[rf], bf, acc[rf][cf]);
        }
      }
      if (dy == 0 && ch + 1 < chEnd)
        stage3t<CPAD>(tile[cur^1], src, (ch+1)*32, r0, tid);
    }
    __syncthreads();
  }

  #pragma unroll
  for (int rf = 0; rf < 4; ++rf){
    #pragma unroll
    for (int j = 0; j < 4; ++j){
      const int oc = wfM*64 + rf*16 + lk*4 + j;
      const float bz = z ? 0.f : bias[oc];
      #pragma unroll
      for (int cf = 0; cf < 4; ++cf){
        const int pos = wfN*64 + cf*16 + lr;
        const int py = r0 + (pos >> 4), px = pos & 15;
        const bool rowok = n ? (py >= 8) : true;
        if (rowok && px < 14)
          out[(size_t)z*NE + ((size_t)b*OC_ + oc)*P_ + py*14 + px] = acc[rf][cf][j] + bz;
      }
    }
  }
}

// ---------------- BN stats over 2 partial slabs -------------------------------
__global__ void k_bnstats(const float* __restrict__ t, float* __restrict__ stats){
  int o = blockIdx.x;
  int tid = threadIdx.x;
  float s = 0.f, s2 = 0.f;
  #pragma unroll 4
  for (int i = tid; i < B_*P_; i += 256){
    int b = i / P_, p = i - (i/P_)*P_;
    size_t off = ((size_t)b*OC_ + o)*P_ + p;
    float v = t[off] + t[off + NE];
    s += v; s2 += v*v;
  }
  __shared__ float r1[256], r2[256];
  r1[tid] = s; r2[tid] = s2; __syncthreads();
  for (int st = 128; st; st >>= 1){
    if (tid < st){ r1[tid] += r1[tid+st]; r2[tid] += r2[tid+st]; }
    __syncthreads();
  }
  if (tid == 0){
    float n = (float)(B_*P_);
    float m = r1[0] / n;
    float var = r2[0] / n - m*m;
    stats[o*2]   = m;
    stats[o*2+1] = rsqrtf(var + 1e-5f);
  }
}

// ---------------- BN apply + relu (+ optional residual add) -------------------
template<bool ADD>
__global__ void k_bnapply(const float* __restrict__ t, const float* __restrict__ stats,
                          const float* __restrict__ g, const float* __restrict__ bb,
                          const float* __restrict__ addsrc, float* __restrict__ out){
  int idx = blockIdx.x*256 + threadIdx.x;
  if (idx >= NE) return;
  int o = (idx / P_) % OC_;
  float m = stats[o*2], is = stats[o*2+1];
  float x = t[idx] + t[idx + NE];
  float v = g[o]*(x-m)*is + bb[o];
  v = fmaxf(v, 0.f);
  if (ADD) v += addsrc[idx];
  out[idx] = v;
}

// ---------------- 1x1 conv + relu; writes f32 [b][c][p] AND bf16 [b][p][c] ----
__launch_bounds__(256)
__global__ void k_conv1x1(const float* __restrict__ vin, const float* __restrict__ w,
                          const float* __restrict__ bias, float* __restrict__ out,
                          unsigned short* __restrict__ outT){
  const int b  = blockIdx.x;
  const int o0 = blockIdx.y * 64;
  const int tid = threadIdx.x;
  const int olane = tid & 63, pg = tid >> 6;
  const int o = o0 + olane;

  __shared__ float sV[32][196];
  __shared__ float sW[64][33];

  float acc[49];
  #pragma unroll
  for (int p = 0; p < 49; ++p) acc[p] = 0.f;

  for (int ch = 0; ch < 128; ch += 32){
    __syncthreads();
    for (int i = tid; i < 32*196; i += 256){
      int c = i / 196, p = i - c*196;
      sV[c][p] = vin[((size_t)b*128 + ch + c)*P_ + p];
    }
    for (int i = tid; i < 64*32; i += 256){
      int ol = i >> 5, c = i & 31;
      sW[ol][c] = w[(size_t)(o0+ol)*130 + ch + c];
    }
    __syncthreads();
    for (int c = 0; c < 32; ++c){
      float wv = sW[olane][c];
      #pragma unroll
      for (int p = 0; p < 49; ++p) acc[p] += sV[c][pg*49 + p] * wv;
    }
  }
  float w0 = w[(size_t)o*130 + 128], w1 = w[(size_t)o*130 + 129], bz = bias[o];
  #pragma unroll
  for (int p = 0; p < 49; ++p){
    int pp = pg*49 + p;
    float v = acc[p] + w0*c0f(pp) + w1*c1f(pp) + bz;
    v = fmaxf(v, 0.f);
    out[((size_t)b*128 + o)*P_ + pp] = v;
    outT[((size_t)b*P_ + pp)*128 + o] = f2bf(v);
  }
}

} // namespace

// ---------------------------------------------------------------------------
extern "C" void kernel_launch(void* const* d_in, const int* in_sizes, int n_in,
                              void* d_out, int out_size, void* d_ws, size_t ws_size,
                              hipStream_t stream){
  (void)in_sizes; (void)n_in; (void)out_size; (void)ws_size;
  const int*   que  = (const int*)  d_in[0];
  const float* img  = (const float*)d_in[1];
  const float* emb  = (const float*)d_in[2];
  const float* wihf = (const float*)d_in[3];
  const float* whhf = (const float*)d_in[4];
  const float* bihf = (const float*)d_in[5];
  const float* bhhf = (const float*)d_in[6];
  const float* wihb = (const float*)d_in[7];
  const float* whhb = (const float*)d_in[8];
  const float* bihb = (const float*)d_in[9];
  const float* bhhb = (const float*)d_in[10];
  const float* convw = (const float*)d_in[11];
  const float* convb = (const float*)d_in[12];
  const float* bng  = (const float*)d_in[13];
  const float* bnb  = (const float*)d_in[14];
  const float* r1c1w = (const float*)d_in[15];
  const float* r1c1b = (const float*)d_in[16];
  const float* r1c2w = (const float*)d_in[17];
  const float* r1c2b = (const float*)d_in[18];
  const float* r1bng = (const float*)d_in[19];
  const float* r1bnb = (const float*)d_in[20];
  const float* r2c1w = (const float*)d_in[21];
  const float* r2c1b = (const float*)d_in[22];
  const float* r2c2w = (const float*)d_in[23];
  const float* r2c2b = (const float*)d_in[24];
  const float* r2bng = (const float*)d_in[25];
  const float* r2bnb = (const float*)d_in[26];

  float* out  = (float*)d_out;
  float* enc  = out;                        // 128*2048
  float* Q    = out + 262144;               // 32*128*2048
  float* vout = out + 262144 + 8388608;     // 128*128*196

  // ------ workspace layout (f32 units) ----------------------------------------
  float* ws = (float*)d_ws;
  unsigned short* xbf  = (unsigned short*)ws;            // 32*128*384 bf16
  float* p1 = ws + 786432;
  unsigned short* pkW  = (unsigned short*)p1;            // 2*256*44*512 bf16
  float* p2 = p1 + 5767168;
  float* bias2 = p2;                                     // 2*4096
  float* p3 = p2 + 8192;
  unsigned short* hstate = (unsigned short*)p3;          // 2par*2dir*128*1024 bf16
  float* p4 = p3 + 262144;
  float* cstate = p4;                                    // 2*128*1024
  float* p5 = p4 + 262144;
  float* part = p5;                                      // 128*4*196
  float* invn = p5 + 100352;                             // 128*196
  float* bufA = invn + 25088;                            // NE
  float* bufB = bufA + NE;                               // NE
  float* convOut = bufB + NE;                            // 2*NE partial slabs
  float* p6 = convOut + 2*(size_t)NE;
  float* stats = p6;                                     // 256
  float* p7 = p6 + 256;
  unsigned short* pkC  = (unsigned short*)p7;            // 9*8*33*512 bf16
  float* p8 = p7 + 608256;
  unsigned short* pkR1 = (unsigned short*)p8;            // 9*8*4*512 bf16
  float* p9 = p8 + 73728;
  unsigned short* pkR2 = (unsigned short*)p9;            // 9*8*4*512 bf16
  float* p10 = p9 + 73728;
  unsigned short* imgT = (unsigned short*)p10;           // 128*196*1056 bf16
  float* p11 = p10 + 13246464;
  unsigned short* v1T  = (unsigned short*)p11;           // 128*196*128 bf16

  // zero h (both parities) + c state (contiguous 2 MB)
  hipMemsetAsync(hstate, 0, (size_t)(262144 + 262144)*sizeof(float), stream);

  // ------ packing / conversions ------------------------------------------------
  k_packW<<<(2*256*44*64 + 255)/256, 256, 0, stream>>>(wihf, whhf, wihb, whhb, pkW);
  k_packC<<<(9*8*33*64 + 255)/256, 256, 0, stream>>>(convw, pkC, 1026, 33);
  k_packC<<<(9*8*4*64 + 255)/256, 256, 0, stream>>>(r1c2w, pkR1, 128, 4);
  k_packC<<<(9*8*4*64 + 255)/256, 256, 0, stream>>>(r2c2w, pkR2, 128, 4);
  k_bias2<<<32, 256, 0, stream>>>(bihf, bhhf, bihb, bhhb, bias2);
  k_embed_bf<<<6144, 256, 0, stream>>>(que, emb, xbf);

  // ------ bi-LSTM: 32 step launches -------------------------------------------
  for (int s = 0; s < 32; ++s){
    unsigned short* hin  = hstate + (size_t)(s & 1)*262144;
    unsigned short* hout = hstate + (size_t)((s & 1)^1)*262144;
    k_step7<<<dim3(64,4), 256, 0, stream>>>(xbf, pkW, bias2, hin, hout,
                                            cstate, Q, s);
  }
  k_qnorm<<<4096, 256, 0, stream>>>(Q, enc);

  // ------ image branch --------------------------------------------------------
  k_sqpart<<<dim3(128,4), 256, 0, stream>>>(img, part);
  k_invnorm<<<(25088+255)/256, 256, 0, stream>>>(part, invn);
  k_mkimgT<<<dim3(128,9), 256, 0, stream>>>(img, invn, imgT);

  k_conv3t<1056><<<dim3(128,2,2), 256, 0, stream>>>(imgT, pkC, convb, convOut);
  k_bnstats<<<128, 256, 0, stream>>>(convOut, stats);
  k_bnapply<false><<<(NE+255)/256, 256, 0, stream>>>(convOut, stats, bng, bnb, bufA, bufA);

  // res block 1: bufA(v) -> bufB/v1T(v1) -> convOut -> bufA(v2+v1)
  k_conv1x1<<<dim3(128,2), 256, 0, stream>>>(bufA, r1c1w, r1c1b, bufB, v1T);
  k_conv3t<128><<<dim3(128,2,2), 256, 0, stream>>>(v1T, pkR1, r1c2b, convOut);
  k_bnstats<<<128, 256, 0, stream>>>(convOut, stats);
  k_bnapply<true><<<(NE+255)/256, 256, 0, stream>>>(convOut, stats, r1bng, r1bnb, bufB, bufA);

  // res block 2: bufA -> bufB/v1T(v1) -> convOut -> vout
  k_conv1x1<<<dim3(128,2), 256, 0, stream>>>(bufA, r2c1w, r2c1b, bufB, v1T);
  k_conv3t<128><<<dim3(128,2,2), 256, 0, stream>>>(v1T, pkR2, r2c2b, convOut);
  k_bnstats<<<128, 256, 0, stream>>>(convOut, stats);
  k_bnapply<true><<<(NE+255)/256, 256, 0, stream>>>(convOut, stats, r2bng, r2bnb, bufB, vout);
}

// Round 11
// 1049.568 us; speedup vs baseline: 1.5877x; 1.0321x over previous
//
#include <hip/hip_runtime.h>
#include <hip/hip_bf16.h>
#include <math.h>

// ---------------------------------------------------------------------------
// R11: (a) conv3t v3 — A-frag register double-buffer pipeline (hide L2 lat
//      under MFMA). (b) conv1x1 -> MFMA (k_c1m) with packed weights, coords
//      folded as K channels. (c) k_bntr: BN+relu(+add) fused with bf16-T emit
//      (replaces bnapply; drops bufA slab). LSTM (k_step7) unchanged.
// ---------------------------------------------------------------------------

namespace {

constexpr int S_ = 32, B_ = 128, H_ = 1024, P_ = 196, OC_ = 128;
constexpr int NE = B_ * OC_ * P_;        // elems of a [B][128][196] slab
constexpr int KX = 384;                  // padded x-K (300 -> 384)
constexpr int KC = 44;                   // LSTM K chunks: 12 x + 32 h

typedef __attribute__((ext_vector_type(8))) short short8v;
typedef __attribute__((ext_vector_type(4))) short short4v;
typedef __attribute__((ext_vector_type(4))) float f32x4;
#define MFMA16(a, b, c) __builtin_amdgcn_mfma_f32_16x16x32_bf16((a), (b), (c), 0, 0, 0)

__device__ __forceinline__ float sigm(float x){ return 1.0f/(1.0f + expf(-x)); }
__device__ __forceinline__ float c0f(int p){ return ((float)p/14.0f - 7.0f)/7.0f; }
__device__ __forceinline__ float c1f(int p){ return ((float)(p%14) - 7.0f)/7.0f; }
__device__ __forceinline__ unsigned short f2bf(float x){
  __hip_bfloat16 h = __float2bfloat16(x);
  return *reinterpret_cast<unsigned short*>(&h);
}

// ---------------- LSTM weights -> fragment-order pack -------------------------
__global__ void k_packW(const float* __restrict__ wihf, const float* __restrict__ whhf,
                        const float* __restrict__ wihb, const float* __restrict__ whhb,
                        unsigned short* __restrict__ pk){
  int i = blockIdx.x*256 + threadIdx.x;
  if (i >= 2*256*KC*64) return;
  const int lane = i & 63;
  int t = i >> 6;
  const int kc = t % KC; t /= KC;
  const int g  = t % 256; t /= 256;
  const int dir = t;
  const int row = g*16 + (lane & 15);
  const int k0  = (lane >> 4)*8;
  unsigned short v[8];
  if (kc < 12){
    const float* src = dir ? wihb : wihf;
    #pragma unroll
    for (int j = 0; j < 8; ++j){
      int kcol = kc*32 + k0 + j;
      v[j] = (kcol < 300) ? f2bf(src[(size_t)row*300 + kcol]) : (unsigned short)0;
    }
  } else {
    const float* src = dir ? whhb : whhf;
    #pragma unroll
    for (int j = 0; j < 8; ++j)
      v[j] = f2bf(src[(size_t)row*1024 + (kc-12)*32 + k0 + j]);
  }
  unsigned short* dst = pk + (((size_t)(dir*256 + g)*KC + kc)*64 + lane)*8;
  #pragma unroll
  for (int j = 0; j < 8; ++j) dst[j] = v[j];
}

// ---------------- conv3 weights -> fragment-order pack ------------------------
__global__ void k_packC(const float* __restrict__ w, unsigned short* __restrict__ pk,
                        int cin, int T){
  int i = blockIdx.x*256 + threadIdx.x;
  if (i >= 9*8*T*64) return;
  const int lane = i & 63;
  int t = i >> 6;
  const int kc = t % T; t /= T;
  const int ot = t % 8; t /= 8;
  const int s = t;
  const int oc = ot*16 + (lane & 15);
  const int c0 = kc*32 + (lane >> 4)*8;
  unsigned short* dst = pk + (((size_t)(s*8 + ot)*T + kc)*64 + lane)*8;
  #pragma unroll
  for (int j = 0; j < 8; ++j){
    int c = c0 + j;
    dst[j] = (c < cin) ? f2bf(w[((size_t)oc*cin + c)*9 + s]) : (unsigned short)0;
  }
}

// ---------------- 1x1 weights [128][cin] -> fragment-order pack ---------------
__global__ void k_packG(const float* __restrict__ w, unsigned short* __restrict__ pk,
                        int cin, int T){
  int i = blockIdx.x*256 + threadIdx.x;
  if (i >= 8*T*64) return;
  const int lane = i & 63;
  int t = i >> 6;
  const int kc = t % T; t /= T;
  const int ot = t;
  const int oc = ot*16 + (lane & 15);
  const int c0 = kc*32 + (lane >> 4)*8;
  unsigned short* dst = pk + (((size_t)(ot*T + kc))*64 + lane)*8;
  #pragma unroll
  for (int j = 0; j < 8; ++j){
    int c = c0 + j;
    dst[j] = (c < cin) ? f2bf(w[(size_t)oc*cin + c]) : (unsigned short)0;
  }
}

__global__ void k_bias2(const float* __restrict__ bif, const float* __restrict__ bhf,
                        const float* __restrict__ bib, const float* __restrict__ bhb,
                        float* __restrict__ out){
  int i = blockIdx.x*256 + threadIdx.x;
  if (i >= 8192) return;
  out[i] = (i < 4096) ? (bif[i] + bhf[i]) : (bib[i-4096] + bhb[i-4096]);
}

// ---------------- embedding -> bf16 x[s][b][384] ------------------------------
__global__ void k_embed_bf(const int* __restrict__ que, const float* __restrict__ emb,
                           unsigned short* __restrict__ x){
  int idx = blockIdx.x*256 + threadIdx.x;
  if (idx >= S_*B_*KX) return;
  int e = idx % KX; int sb = idx / KX; int b = sb % B_; int s = sb / B_;
  float v = 0.0f;
  if (e < 300){
    int t = que[b*S_ + s];
    if (t != 0) v = emb[t*300 + e];
  }
  x[idx] = f2bf(v);
}

// ---------------- one LSTM step (staged-A + packed-B, barrier-free) -----------
__launch_bounds__(256, 1)
__global__ void k_step7(const unsigned short* __restrict__ xbf,
                        const unsigned short* __restrict__ pkW,
                        const float* __restrict__ bias2,
                        const unsigned short* __restrict__ hin,
                        unsigned short* __restrict__ hout,
                        float* __restrict__ cst, float* __restrict__ Q, int s){
  const int dir = blockIdx.x >> 5;
  const int u0  = (blockIdx.x & 31) * 32;
  const int m0g = blockIdx.y * 32;
  const int tid = threadIdx.x, wave = tid >> 6, lane = tid & 63;
  const int lr = lane & 15, lk = lane >> 4;
  const int xs = dir ? (S_-1-s) : s;

  __shared__ unsigned short tA[32][1416];
  __shared__ float sG[32][132];

  {
    const int r = tid >> 3, sg = tid & 7;
    const unsigned short* xr = xbf + ((size_t)xs*B_ + m0g + r)*KX + sg*48;
    #pragma unroll
    for (int q = 0; q < 6; ++q)
      *(short8v*)&tA[r][sg*48 + q*8] = *(const short8v*)(xr + q*8);
    const unsigned short* hr = hin + ((size_t)dir*B_ + m0g + r)*H_ + sg*128;
    #pragma unroll
    for (int q = 0; q < 16; ++q)
      *(short8v*)&tA[r][384 + sg*128 + q*8] = *(const short8v*)(hr + q*8);
  }
  __syncthreads();

  const unsigned short* pw0 = pkW + (((size_t)(dir*256 + wave*64 + (u0 >> 4))*KC)*64
                                     + lane)*8;
  const unsigned short* pw1 = pw0 + (size_t)KC*64*8;

  f32x4 acc00{0,0,0,0}, acc01{0,0,0,0}, acc10{0,0,0,0}, acc11{0,0,0,0};

  #pragma unroll 4
  for (int ch = 0; ch < KC; ++ch){
    const int ka = ch*32 + lk*8;
    short8v a0 = *(short8v*)&tA[lr][ka];
    short8v a1 = *(short8v*)&tA[16 + lr][ka];
    short8v b0 = *(const short8v*)(pw0 + (size_t)ch*512);
    short8v b1 = *(const short8v*)(pw1 + (size_t)ch*512);
    acc00 = MFMA16(a0, b0, acc00); acc01 = MFMA16(a0, b1, acc01);
    acc10 = MFMA16(a1, b0, acc10); acc11 = MFMA16(a1, b1, acc11);
  }

  #pragma unroll
  for (int j = 0; j < 4; ++j){
    const int rr = lk*4 + j;
    sG[rr][wave*32 + lr]            = acc00[j];
    sG[rr][wave*32 + 16 + lr]       = acc01[j];
    sG[16 + rr][wave*32 + lr]       = acc10[j];
    sG[16 + rr][wave*32 + 16 + lr]  = acc11[j];
  }
  __syncthreads();

  const float* bb = bias2 + (size_t)dir*4096;
  float* cc = cst + (size_t)dir*B_*H_;
  unsigned short* ho = hout + (size_t)dir*B_*H_;
  #pragma unroll
  for (int t = 0; t < 4; ++t){
    const int idx = tid + t*256;
    const int m = idx >> 5, u = idx & 31;
    const int ug = u0 + u, mg = m0g + m;
    float gi = sG[m][u]      + bb[ug];
    float gf = sG[m][32+u]   + bb[1024+ug];
    float gg = sG[m][64+u]   + bb[2048+ug];
    float go = sG[m][96+u]   + bb[3072+ug];
    float cold = cc[mg*H_ + ug];
    float cn = sigm(gf)*cold + sigm(gi)*tanhf(gg);
    float hn = sigm(go)*tanhf(cn);
    cc[mg*H_ + ug] = cn;
    ho[(size_t)mg*H_ + ug] = f2bf(hn);
    Q[((size_t)xs*B_ + mg)*2048 + dir*1024 + ug] = hn;
  }
}

// ---------------- qenc L2-normalize (in-place) + enc --------------------------
__global__ void k_qnorm(float* __restrict__ Q, float* __restrict__ enc){
  int sb = blockIdx.x;
  int s = sb >> 7, b = sb & 127;
  float* row = Q + (size_t)sb*2048;
  int tid = threadIdx.x;
  float v[8]; float ss = 0.f;
  #pragma unroll
  for (int i = 0; i < 8; ++i){ v[i] = row[tid*8+i]; ss += v[i]*v[i]; }
  __shared__ float red[256];
  red[tid] = ss; __syncthreads();
  for (int st = 128; st; st >>= 1){
    if (tid < st) red[tid] += red[tid+st];
    __syncthreads();
  }
  float inv = 1.0f / fmaxf(sqrtf(red[0]), 1e-12f);
  #pragma unroll
  for (int i = 0; i < 8; ++i){
    float q = v[i]*inv;
    row[tid*8+i] = q;
    if (s == S_-1) enc[(size_t)b*2048 + tid*8 + i] = q;
  }
}

// ---------------- per-pixel channel sumsq of img ------------------------------
__global__ void k_sqpart(const float* __restrict__ img, float* __restrict__ part){
  int b = blockIdx.x, cq = blockIdx.y;
  int t = threadIdx.x;
  if (t >= P_) return;
  const float* base = img + ((size_t)b*1024 + cq*256)*P_ + t;
  float s = 0.f;
  #pragma unroll 4
  for (int c = 0; c < 256; ++c){ float v = base[c*P_]; s += v*v; }
  part[((size_t)b*4 + cq)*P_ + t] = s;
}

__global__ void k_invnorm(const float* __restrict__ part, float* __restrict__ inv){
  int i = blockIdx.x*256 + threadIdx.x;
  if (i >= B_*P_) return;
  int b = i / P_, p = i % P_;
  float s = part[(b*4+0)*P_+p] + part[(b*4+1)*P_+p]
          + part[(b*4+2)*P_+p] + part[(b*4+3)*P_+p];
  inv[i] = 1.0f / fmaxf(sqrtf(s), 1e-12f);
}

// ---------------- img -> imgT[b][196][1056] bf16 (invnorm+coords+pad) ---------
__global__ void k_mkimgT(const float* __restrict__ img, const float* __restrict__ invn,
                         unsigned short* __restrict__ imgT){
  const int b = blockIdx.x, cg = blockIdx.y;
  const int tid = threadIdx.x;
  unsigned short* dstB = imgT + (size_t)b*196*1056;
  if (cg == 8){
    for (int i = tid; i < 196*32; i += 256){
      int p = i >> 5, cc = i & 31;
      float v = (cc == 0) ? c0f(p) : (cc == 1) ? c1f(p) : 0.f;
      dstB[(size_t)p*1056 + 1024 + cc] = f2bf(v);
    }
    return;
  }
  __shared__ unsigned short tt[196][136];
  __shared__ float sInv[200];
  for (int i = tid; i < 196; i += 256) sInv[i] = invn[b*196 + i];
  __syncthreads();
  const int c0 = cg*128;
  const float* srcB = img + ((size_t)b*1024 + c0)*196;
  for (int i = tid; i < 128*49; i += 256){
    int c = i / 49, p4 = i - (i/49)*49;
    float4 v = *(const float4*)(srcB + (size_t)c*196 + p4*4);
    int p = p4*4;
    tt[p+0][c] = f2bf(v.x * sInv[p+0]);
    tt[p+1][c] = f2bf(v.y * sInv[p+1]);
    tt[p+2][c] = f2bf(v.z * sInv[p+2]);
    tt[p+3][c] = f2bf(v.w * sInv[p+3]);
  }
  __syncthreads();
  for (int i = tid; i < 196*16; i += 256){
    int p = i >> 4, g = i & 15;
    *(short8v*)(dstB + (size_t)p*1056 + c0 + g*8) = *(short8v*)&tt[p][g*8];
  }
}

// ---------------- 3x3 conv via MFMA (v3: A-frag register pipeline) ------------
template<int CPAD>
__device__ __forceinline__ void stage3t(unsigned short (*__restrict__ tile)[40],
                                        const unsigned short* __restrict__ src,
                                        int c0, int r0, int tid){
  for (int i = tid; i < 10*14*4; i += 256){
    int t = i / 56, rem = i - t*56, gx = rem >> 2, seg = rem & 3;
    int gy = r0 - 1 + t;
    if ((unsigned)gy < 14u){
      short8v v = *(const short8v*)(src + (size_t)(gy*14+gx)*CPAD + c0 + seg*8);
      *(short8v*)&tile[t*16 + gx + 1][seg*8] = v;
    }
  }
}

template<int CPAD>
__launch_bounds__(256, 2)
__global__ void k_conv3t(const unsigned short* __restrict__ srcT,
                         const unsigned short* __restrict__ wPk,
                         const float* __restrict__ bias,
                         float* __restrict__ out){
  constexpr int T = CPAD / 32;
  const int b = blockIdx.x, n = blockIdx.y, z = blockIdx.z;
  const int r0 = n ? 6 : 0;
  const int chBeg = z ? T/2 : 0, chEnd = z ? T : T/2;
  const int tid = threadIdx.x, wave = tid >> 6, lane = tid & 63;
  const int lr = lane & 15, lk = lane >> 4;
  const int wfM = wave >> 1, wfN = wave & 1;
  const unsigned short* src = srcT + (size_t)b*196*CPAD;

  __shared__ unsigned short tile[2][164][40];

  for (int i = tid; i < 1640; i += 256)
    ((short8v*)&tile[0][0][0])[i] = short8v{0,0,0,0,0,0,0,0};
  __syncthreads();
  stage3t<CPAD>(tile[0], src, chBeg*32, r0, tid);
  __syncthreads();

  f32x4 acc[4][4];
  #pragma unroll
  for (int i = 0; i < 4; ++i)
    #pragma unroll
    for (int j = 0; j < 4; ++j) acc[i][j] = f32x4{0,0,0,0};

  short8v aC[12], aN[12];
  // preload (chBeg, dy=0)
  #pragma unroll
  for (int dx = 0; dx < 3; ++dx)
    #pragma unroll
    for (int rf = 0; rf < 4; ++rf)
      aC[dx*4+rf] = *(const short8v*)(wPk + ((((size_t)dx*8 + wfM*4 + rf)*T + chBeg)*64
                                             + lane)*8);

  for (int ch = chBeg; ch < chEnd; ++ch){
    const int cur = (ch - chBeg) & 1;
    #pragma unroll
    for (int dy = 0; dy < 3; ++dy){
      const int ndy = (dy < 2) ? dy + 1 : 0;
      const int nch = (dy < 2) ? ch : ch + 1;
      const bool hasN = nch < chEnd;
      if (hasN){
        #pragma unroll
        for (int dx = 0; dx < 3; ++dx)
          #pragma unroll
          for (int rf = 0; rf < 4; ++rf)
            aN[dx*4+rf] = *(const short8v*)(wPk + ((((size_t)(ndy*3+dx)*8 + wfM*4 + rf)*T
                                                    + nch)*64 + lane)*8);
      }
      #pragma unroll
      for (int dx = 0; dx < 3; ++dx){
        const int dlt = dy*16 + dx;
        #pragma unroll
        for (int cf = 0; cf < 4; ++cf){
          short8v bf = *(short8v*)&tile[cur][wfN*64 + cf*16 + lr + dlt][lk*8];
          #pragma unroll
          for (int rf = 0; rf < 4; ++rf)
            acc[rf][cf] = MFMA16(aC[dx*4+rf], bf, acc[rf][cf]);
        }
      }
      if (dy == 0 && ch + 1 < chEnd)
        stage3t<CPAD>(tile[cur^1], src, (ch+1)*32, r0, tid);
      if (hasN){
        #pragma unroll
        for (int q = 0; q < 12; ++q) aC[q] = aN[q];
      }
    }
    __syncthreads();
  }

  #pragma unroll
  for (int rf = 0; rf < 4; ++rf){
    #pragma unroll
    for (int j = 0; j < 4; ++j){
      const int oc = wfM*64 + rf*16 + lk*4 + j;
      const float bz = z ? 0.f : bias[oc];
      #pragma unroll
      for (int cf = 0; cf < 4; ++cf){
        const int pos = wfN*64 + cf*16 + lr;
        const int py = r0 + (pos >> 4), px = pos & 15;
        const bool rowok = n ? (py >= 8) : true;
        if (rowok && px < 14)
          out[(size_t)z*NE + ((size_t)b*OC_ + oc)*P_ + py*14 + px] = acc[rf][cf][j] + bz;
      }
    }
  }
}

// ---------------- BN stats over 2 partial slabs -------------------------------
__global__ void k_bnstats(const float* __restrict__ t, float* __restrict__ stats){
  int o = blockIdx.x;
  int tid = threadIdx.x;
  float s = 0.f, s2 = 0.f;
  #pragma unroll 4
  for (int i = tid; i < B_*P_; i += 256){
    int b = i / P_, p = i - (i/P_)*P_;
    size_t off = ((size_t)b*OC_ + o)*P_ + p;
    float v = t[off] + t[off + NE];
    s += v; s2 += v*v;
  }
  __shared__ float r1[256], r2[256];
  r1[tid] = s; r2[tid] = s2; __syncthreads();
  for (int st = 128; st; st >>= 1){
    if (tid < st){ r1[tid] += r1[tid+st]; r2[tid] += r2[tid+st]; }
    __syncthreads();
  }
  if (tid == 0){
    float n = (float)(B_*P_);
    float m = r1[0] / n;
    float var = r2[0] / n - m*m;
    stats[o*2]   = m;
    stats[o*2+1] = rsqrtf(var + 1e-5f);
  }
}

// ---------------- BN apply + relu (+add), emit bf16-T (or final f32) ----------
// grid 128 (b). !FINAL: write vT[b][196][160] bf16 (c<128 data, 128/129 coords,
// rest zero). FINAL: write f32 [b][c][p] to out.
template<bool ADD, bool FINAL>
__global__ void k_bntr(const float* __restrict__ t, const float* __restrict__ stats,
                       const float* __restrict__ g, const float* __restrict__ bb,
                       const float* __restrict__ addsrc,
                       float* __restrict__ outF, unsigned short* __restrict__ outT){
  const int b = blockIdx.x, tid = threadIdx.x;
  for (int i = tid; i < 128*196; i += 256){
    int c = i / 196, p = i - c*196;
    size_t off = ((size_t)b*OC_ + c)*P_ + p;
    float x = t[off] + t[off + NE];
    float v = g[c]*(x - stats[c*2])*stats[c*2+1] + bb[c];
    v = fmaxf(v, 0.f);
    if (ADD) v += addsrc[off];
    if (FINAL) outF[off] = v;
    else       outT[((size_t)b*P_ + p)*160 + c] = f2bf(v);
  }
  if (!FINAL){
    for (int i = tid; i < 196*32; i += 256){
      int p = i >> 5, c2 = i & 31;
      float v = (c2 == 0) ? c0f(p) : (c2 == 1) ? c1f(p) : 0.f;
      outT[((size_t)b*P_ + p)*160 + 128 + c2] = f2bf(v);
    }
  }
}

// ---------------- 1x1 conv via MFMA -------------------------------------------
// grid (128 b, 2 n); block 256 (4 waves, wave = M rows w*32). M=128 oc,
// N half = 112 pos (n0: 0..111, n1: 112..207; >=196 pad), K = 160 (130 pad,
// coords at 128/129). B tile in LDS [112][164] (conflict-free), A packed.
// Epilogue: +bias, relu, write v1 f32 [b][oc][p] + v1T bf16 [b][p][128].
__launch_bounds__(256, 2)
__global__ void k_c1m(const unsigned short* __restrict__ vT,
                      const unsigned short* __restrict__ pk,
                      const float* __restrict__ bias,
                      float* __restrict__ out, unsigned short* __restrict__ outT){
  const int b = blockIdx.x, n = blockIdx.y;
  const int pBeg = n ? 112 : 0;
  const int nCF = n ? 6 : 7;          // fragments of 16 pos
  const int tid = threadIdx.x, wave = tid >> 6, lane = tid & 63;
  const int lr = lane & 15, lk = lane >> 4;

  __shared__ unsigned short tile[112][164];

  for (int i = tid; i < 112*20; i += 256){
    int r = i / 20, seg = i - r*20;
    int p = pBeg + r;
    short8v v = short8v{0,0,0,0,0,0,0,0};
    if (p < 196 && r < nCF*16)
      v = *(const short8v*)(vT + ((size_t)b*P_ + p)*160 + seg*8);
    *(short8v*)&tile[r][seg*8] = v;
  }
  __syncthreads();

  f32x4 acc[2][7];
  #pragma unroll
  for (int i = 0; i < 2; ++i)
    #pragma unroll
    for (int j = 0; j < 7; ++j) acc[i][j] = f32x4{0,0,0,0};

  #pragma unroll
  for (int kc = 0; kc < 5; ++kc){
    short8v a0 = *(const short8v*)(pk + (((size_t)(wave*2 + 0)*5 + kc)*64 + lane)*8);
    short8v a1 = *(const short8v*)(pk + (((size_t)(wave*2 + 1)*5 + kc)*64 + lane)*8);
    #pragma unroll
    for (int cf = 0; cf < 7; ++cf){
      if (cf < nCF){
        short8v bf = *(short8v*)&tile[cf*16 + lr][kc*32 + lk*8];
        acc[0][cf] = MFMA16(a0, bf, acc[0][cf]);
        acc[1][cf] = MFMA16(a1, bf, acc[1][cf]);
      }
    }
  }

  // epilogue: C row = oc (lk*4+j), col = pos (lr)
  #pragma unroll
  for (int rf = 0; rf < 2; ++rf){
    const int ocBase = wave*32 + rf*16 + lk*4;
    #pragma unroll
    for (int cf = 0; cf < 7; ++cf){
      if (cf < nCF){
        const int pos = pBeg + cf*16 + lr;
        if (pos < 196){
          short4v sv;
          #pragma unroll
          for (int j = 0; j < 4; ++j){
            const int oc = ocBase + j;
            float v = fmaxf(acc[rf][cf][j] + bias[oc], 0.f);
            out[((size_t)b*OC_ + oc)*P_ + pos] = v;
            sv[j] = (short)f2bf(v);
          }
          *(short4v*)(outT + ((size_t)b*P_ + pos)*128 + ocBase) = sv;
        }
      }
    }
  }
}

} // namespace

// ---------------------------------------------------------------------------
extern "C" void kernel_launch(void* const* d_in, const int* in_sizes, int n_in,
                              void* d_out, int out_size, void* d_ws, size_t ws_size,
                              hipStream_t stream){
  (void)in_sizes; (void)n_in; (void)out_size; (void)ws_size;
  const int*   que  = (const int*)  d_in[0];
  const float* img  = (const float*)d_in[1];
  const float* emb  = (const float*)d_in[2];
  const float* wihf = (const float*)d_in[3];
  const float* whhf = (const float*)d_in[4];
  const float* bihf = (const float*)d_in[5];
  const float* bhhf = (const float*)d_in[6];
  const float* wihb = (const float*)d_in[7];
  const float* whhb = (const float*)d_in[8];
  const float* bihb = (const float*)d_in[9];
  const float* bhhb = (const float*)d_in[10];
  const float* convw = (const float*)d_in[11];
  const float* convb = (const float*)d_in[12];
  const float* bng  = (const float*)d_in[13];
  const float* bnb  = (const float*)d_in[14];
  const float* r1c1w = (const float*)d_in[15];
  const float* r1c1b = (const float*)d_in[16];
  const float* r1c2w = (const float*)d_in[17];
  const float* r1c2b = (const float*)d_in[18];
  const float* r1bng = (const float*)d_in[19];
  const float* r1bnb = (const float*)d_in[20];
  const float* r2c1w = (const float*)d_in[21];
  const float* r2c1b = (const float*)d_in[22];
  const float* r2c2w = (const float*)d_in[23];
  const float* r2c2b = (const float*)d_in[24];
  const float* r2bng = (const float*)d_in[25];
  const float* r2bnb = (const float*)d_in[26];

  float* out  = (float*)d_out;
  float* enc  = out;                        // 128*2048
  float* Q    = out + 262144;               // 32*128*2048
  float* vout = out + 262144 + 8388608;     // 128*128*196

  // ------ workspace layout (f32 units) ----------------------------------------
  float* ws = (float*)d_ws;
  unsigned short* xbf  = (unsigned short*)ws;            // 32*128*384 bf16
  float* p1 = ws + 786432;
  unsigned short* pkW  = (unsigned short*)p1;            // 2*256*44*512 bf16
  float* p2 = p1 + 5767168;
  float* bias2 = p2;                                     // 2*4096
  float* p3 = p2 + 8192;
  unsigned short* hstate = (unsigned short*)p3;          // 2par*2dir*128*1024 bf16
  float* p4 = p3 + 262144;
  float* cstate = p4;                                    // 2*128*1024
  float* p5 = p4 + 262144;
  float* part = p5;                                      // 128*4*196
  float* invn = p5 + 100352;                             // 128*196
  float* bufB = invn + 25088;                            // NE (v1 f32)
  float* convOut = bufB + NE;                            // 2*NE partial slabs
  float* p6 = convOut + 2*(size_t)NE;
  float* stats = p6;                                     // 256
  float* p7 = p6 + 256;
  unsigned short* pkC  = (unsigned short*)p7;            // 9*8*33*512 bf16
  float* p8 = p7 + 608256;
  unsigned short* pkR1 = (unsigned short*)p8;            // 9*8*4*512 bf16
  float* p9 = p8 + 73728;
  unsigned short* pkR2 = (unsigned short*)p9;            // 9*8*4*512 bf16
  float* p10 = p9 + 73728;
  unsigned short* pk1  = (unsigned short*)p10;           // 8*5*512 bf16
  float* p11 = p10 + 10240;
  unsigned short* pk2  = (unsigned short*)p11;           // 8*5*512 bf16
  float* p12 = p11 + 10240;
  unsigned short* imgT = (unsigned short*)p12;           // 128*196*1056 bf16
  float* p13 = p12 + 13246464;
  unsigned short* vTb  = (unsigned short*)p13;           // 128*196*160 bf16
  float* p14 = p13 + 2007040;
  unsigned short* v1T  = (unsigned short*)p14;           // 128*196*128 bf16

  hipMemsetAsync(hstate, 0, (size_t)(262144 + 262144)*sizeof(float), stream);

  // ------ packing / conversions ------------------------------------------------
  k_packW<<<(2*256*44*64 + 255)/256, 256, 0, stream>>>(wihf, whhf, wihb, whhb, pkW);
  k_packC<<<(9*8*33*64 + 255)/256, 256, 0, stream>>>(convw, pkC, 1026, 33);
  k_packC<<<(9*8*4*64 + 255)/256, 256, 0, stream>>>(r1c2w, pkR1, 128, 4);
  k_packC<<<(9*8*4*64 + 255)/256, 256, 0, stream>>>(r2c2w, pkR2, 128, 4);
  k_packG<<<(8*5*64 + 255)/256, 256, 0, stream>>>(r1c1w, pk1, 130, 5);
  k_packG<<<(8*5*64 + 255)/256, 256, 0, stream>>>(r2c1w, pk2, 130, 5);
  k_bias2<<<32, 256, 0, stream>>>(bihf, bhhf, bihb, bhhb, bias2);
  k_embed_bf<<<6144, 256, 0, stream>>>(que, emb, xbf);

  // ------ bi-LSTM: 32 step launches -------------------------------------------
  for (int s = 0; s < 32; ++s){
    unsigned short* hin  = hstate + (size_t)(s & 1)*262144;
    unsigned short* hout = hstate + (size_t)((s & 1)^1)*262144;
    k_step7<<<dim3(64,4), 256, 0, stream>>>(xbf, pkW, bias2, hin, hout,
                                            cstate, Q, s);
  }
  k_qnorm<<<4096, 256, 0, stream>>>(Q, enc);

  // ------ image branch --------------------------------------------------------
  k_sqpart<<<dim3(128,4), 256, 0, stream>>>(img, part);
  k_invnorm<<<(25088+255)/256, 256, 0, stream>>>(part, invn);
  k_mkimgT<<<dim3(128,9), 256, 0, stream>>>(img, invn, imgT);

  k_conv3t<1056><<<dim3(128,2,2), 256, 0, stream>>>(imgT, pkC, convb, convOut);
  k_bnstats<<<128, 256, 0, stream>>>(convOut, stats);
  k_bntr<false,false><<<128, 256, 0, stream>>>(convOut, stats, bng, bnb,
                                               nullptr, nullptr, vTb);

  // res block 1: vTb -> (bufB f32, v1T) -> convOut -> vTb
  k_c1m<<<dim3(128,2), 256, 0, stream>>>(vTb, pk1, r1c1b, bufB, v1T);
  k_conv3t<128><<<dim3(128,2,2), 256, 0, stream>>>(v1T, pkR1, r1c2b, convOut);
  k_bnstats<<<128, 256, 0, stream>>>(convOut, stats);
  k_bntr<true,false><<<128, 256, 0, stream>>>(convOut, stats, r1bng, r1bnb,
                                              bufB, nullptr, vTb);

  // res block 2: vTb -> (bufB, v1T) -> convOut -> vout
  k_c1m<<<dim3(128,2), 256, 0, stream>>>(vTb, pk2, r2c1b, bufB, v1T);
  k_conv3t<128><<<dim3(128,2,2), 256, 0, stream>>>(v1T, pkR2, r2c2b, convOut);
  k_bnstats<<<128, 256, 0, stream>>>(convOut, stats);
  k_bntr<true,true><<<128, 256, 0, stream>>>(convOut, stats, r2bng, r2bnb,
                                             bufB, vout, nullptr);
}

// Round 12
// 1005.880 us; speedup vs baseline: 1.6567x; 1.0434x over previous
//
#include <hip/hip_runtime.h>
#include <hip/hip_bf16.h>
#include <math.h>

// ---------------------------------------------------------------------------
// R12: LSTM k_step9 — tA holds h ONLY (66KB -> 2 blocks/CU); x A-frags from
//      fragment-packed px (global, coalesced); weights packed in gate-pair
//      order (pkW2) so the gate quadruple is recombined with __shfl_xor(8)
//      in-register (no sG, one barrier). Image branch identical to R11.
// ---------------------------------------------------------------------------

namespace {

constexpr int S_ = 32, B_ = 128, H_ = 1024, P_ = 196, OC_ = 128;
constexpr int NE = B_ * OC_ * P_;        // elems of a [B][128][196] slab
constexpr int KC = 44;                   // LSTM K chunks: 12 x + 32 h

typedef __attribute__((ext_vector_type(8))) short short8v;
typedef __attribute__((ext_vector_type(4))) short short4v;
typedef __attribute__((ext_vector_type(4))) float f32x4;
#define MFMA16(a, b, c) __builtin_amdgcn_mfma_f32_16x16x32_bf16((a), (b), (c), 0, 0, 0)

__device__ __forceinline__ float sigm(float x){ return 1.0f/(1.0f + expf(-x)); }
__device__ __forceinline__ float c0f(int p){ return ((float)p/14.0f - 7.0f)/7.0f; }
__device__ __forceinline__ float c1f(int p){ return ((float)(p%14) - 7.0f)/7.0f; }
__device__ __forceinline__ unsigned short f2bf(float x){
  __hip_bfloat16 h = __float2bfloat16(x);
  return *reinterpret_cast<unsigned short*>(&h);
}

// ---------------- LSTM weights -> gate-pair fragment pack ---------------------
// pkW2[dir][uslab(32)][w(4)][pair(2)][kc(44)][lane(64)][8]:
// lane holds W[row = (pair*2+(lr>>3))*1024 + uslab*32 + w*8 + (lr&7)]
//           [k = kc*32 + (lane>>4)*8 + j]; kc<12 -> Wih (K=300 pad 384) else Whh.
__global__ void k_packW2(const float* __restrict__ wihf, const float* __restrict__ whhf,
                         const float* __restrict__ wihb, const float* __restrict__ whhb,
                         unsigned short* __restrict__ pk){
  int i = blockIdx.x*256 + threadIdx.x;
  if (i >= 2*32*4*2*KC*64) return;
  const int lane = i & 63;
  int t = i >> 6;
  const int kc = t % KC; t /= KC;
  const int pair = t % 2; t /= 2;
  const int w = t % 4; t /= 4;
  const int uslab = t % 32; t /= 32;
  const int dir = t;
  const int lr = lane & 15, lk = lane >> 4;
  const int row = (pair*2 + (lr >> 3))*1024 + uslab*32 + w*8 + (lr & 7);
  unsigned short v[8];
  if (kc < 12){
    const float* src = dir ? wihb : wihf;
    #pragma unroll
    for (int j = 0; j < 8; ++j){
      int k = kc*32 + lk*8 + j;
      v[j] = (k < 300) ? f2bf(src[(size_t)row*300 + k]) : (unsigned short)0;
    }
  } else {
    const float* src = dir ? whhb : whhf;
    #pragma unroll
    for (int j = 0; j < 8; ++j)
      v[j] = f2bf(src[(size_t)row*1024 + (kc-12)*32 + lk*8 + j]);
  }
  unsigned short* dst = pk + (size_t)i*8;
  #pragma unroll
  for (int j = 0; j < 8; ++j) dst[j] = v[j];
}

// ---------------- embedding -> fragment-packed px -----------------------------
// px[t(32)][mgrp(8)][kc(12)][lane][8]: lane holds x[t][b = mgrp*16 + (lane&15)]
// [k = kc*32 + (lane>>4)*8 + j] (k>=300 -> 0, padding token -> 0).
__global__ void k_embed_px(const int* __restrict__ que, const float* __restrict__ emb,
                           unsigned short* __restrict__ px){
  int i = blockIdx.x*256 + threadIdx.x;
  if (i >= 32*8*12*64) return;
  const int lane = i & 63;
  int t2 = i >> 6;
  const int kc = t2 % 12; t2 /= 12;
  const int mgrp = t2 % 8; t2 /= 8;
  const int t = t2;
  const int b = mgrp*16 + (lane & 15);
  const int tok = que[b*S_ + t];
  const int k0 = kc*32 + (lane >> 4)*8;
  unsigned short* dst = px + (size_t)i*8;
  #pragma unroll
  for (int j = 0; j < 8; ++j){
    int k = k0 + j;
    dst[j] = (tok == 0 || k >= 300) ? (unsigned short)0 : f2bf(emb[(size_t)tok*300 + k]);
  }
}

// ---------------- conv3 weights -> fragment-order pack ------------------------
__global__ void k_packC(const float* __restrict__ w, unsigned short* __restrict__ pk,
                        int cin, int T){
  int i = blockIdx.x*256 + threadIdx.x;
  if (i >= 9*8*T*64) return;
  const int lane = i & 63;
  int t = i >> 6;
  const int kc = t % T; t /= T;
  const int ot = t % 8; t /= 8;
  const int s = t;
  const int oc = ot*16 + (lane & 15);
  const int c0 = kc*32 + (lane >> 4)*8;
  unsigned short* dst = pk + (((size_t)(s*8 + ot)*T + kc)*64 + lane)*8;
  #pragma unroll
  for (int j = 0; j < 8; ++j){
    int c = c0 + j;
    dst[j] = (c < cin) ? f2bf(w[((size_t)oc*cin + c)*9 + s]) : (unsigned short)0;
  }
}

// ---------------- 1x1 weights [128][cin] -> fragment-order pack ---------------
__global__ void k_packG(const float* __restrict__ w, unsigned short* __restrict__ pk,
                        int cin, int T){
  int i = blockIdx.x*256 + threadIdx.x;
  if (i >= 8*T*64) return;
  const int lane = i & 63;
  int t = i >> 6;
  const int kc = t % T; t /= T;
  const int ot = t;
  const int oc = ot*16 + (lane & 15);
  const int c0 = kc*32 + (lane >> 4)*8;
  unsigned short* dst = pk + (((size_t)(ot*T + kc))*64 + lane)*8;
  #pragma unroll
  for (int j = 0; j < 8; ++j){
    int c = c0 + j;
    dst[j] = (c < cin) ? f2bf(w[(size_t)oc*cin + c]) : (unsigned short)0;
  }
}

__global__ void k_bias2(const float* __restrict__ bif, const float* __restrict__ bhf,
                        const float* __restrict__ bib, const float* __restrict__ bhb,
                        float* __restrict__ out){
  int i = blockIdx.x*256 + threadIdx.x;
  if (i >= 8192) return;
  out[i] = (i < 4096) ? (bif[i] + bhf[i]) : (bib[i-4096] + bhb[i-4096]);
}

// ---------------- one LSTM step (v9: h-only tA, shuffle epilogue) -------------
// grid (64, 4): x = dir*32 + uslab (32 units), y = mslab (32 batch rows).
// block 256 (4 waves); wave w owns units [uslab*32 + w*8, +8) x 4 gates.
// Wave cols: frag pair0 = gates {i,f}, pair1 = {g,o}; col = gate-pair layout.
// tA = h rows only (66KB) -> 2 blocks/CU. x A-frags from px, B from pkW2
// (both coalesced packed global). Gate quadruple via __shfl_xor(8).
__launch_bounds__(256, 2)
__global__ void k_step9(const unsigned short* __restrict__ px,
                        const unsigned short* __restrict__ pkW2,
                        const float* __restrict__ bias2,
                        const unsigned short* __restrict__ hin,
                        unsigned short* __restrict__ hout,
                        float* __restrict__ cst, float* __restrict__ Q, int s){
  const int dir   = blockIdx.x >> 5;
  const int uslab = blockIdx.x & 31;
  const int mslab = blockIdx.y;
  const int m0g   = mslab*32;
  const int tid = threadIdx.x, w = tid >> 6, lane = tid & 63;
  const int lr = lane & 15, lk = lane >> 4;
  const int xs = dir ? (S_-1-s) : s;

  __shared__ unsigned short tA[32][1032];   // h rows m0g..+32

  // ---- stage h (64KB): thread r=tid>>3, sg=tid&7: 16 x 16B coalesced ----
  {
    const int r = tid >> 3, sg = tid & 7;
    const unsigned short* hr = hin + ((size_t)dir*B_ + m0g + r)*H_ + sg*128;
    #pragma unroll
    for (int q = 0; q < 16; ++q)
      *(short8v*)&tA[r][sg*128 + q*8] = *(const short8v*)(hr + q*8);
  }

  // packed operand bases
  const unsigned short* pb  = pkW2 + ((((size_t)(dir*32 + uslab)*4 + w)*2)*KC*64 + lane)*8;
  const size_t pbPair = (size_t)KC*512;           // pair stride (shorts)
  const unsigned short* pax = px + (((size_t)(xs*8 + mslab*2)*12)*64 + lane)*8;
  const size_t paxRf  = (size_t)12*512;           // mgrp stride (shorts)

  f32x4 a00{0,0,0,0}, a01{0,0,0,0}, a10{0,0,0,0}, a11{0,0,0,0};  // [rf][pair]

  // ---- x-part: 12 chunks, all-global (tA not needed yet) ----
  #pragma unroll 4
  for (int ch = 0; ch < 12; ++ch){
    short8v a0 = *(const short8v*)(pax + (size_t)ch*512);
    short8v a1 = *(const short8v*)(pax + paxRf + (size_t)ch*512);
    short8v b0 = *(const short8v*)(pb + (size_t)ch*512);
    short8v b1 = *(const short8v*)(pb + pbPair + (size_t)ch*512);
    a00 = MFMA16(a0, b0, a00); a01 = MFMA16(a0, b1, a01);
    a10 = MFMA16(a1, b0, a10); a11 = MFMA16(a1, b1, a11);
  }
  __syncthreads();    // tA ready

  // ---- h-part: 32 chunks, A from LDS ----
  #pragma unroll 8
  for (int ch = 0; ch < 32; ++ch){
    const int ka = ch*32 + lk*8;
    short8v a0 = *(short8v*)&tA[lr][ka];
    short8v a1 = *(short8v*)&tA[16 + lr][ka];
    short8v b0 = *(const short8v*)(pb + (size_t)(12 + ch)*512);
    short8v b1 = *(const short8v*)(pb + pbPair + (size_t)(12 + ch)*512);
    a00 = MFMA16(a0, b0, a00); a01 = MFMA16(a0, b1, a01);
    a10 = MFMA16(a1, b0, a10); a11 = MFMA16(a1, b1, a11);
  }

  // ---- epilogue: shuffle-recombine gate quadruple, gate math ----
  const int ug = uslab*32 + w*8 + (lr & 7);
  const float* bb = bias2 + (size_t)dir*4096;
  const float bi = bb[ug], bfv = bb[1024+ug], bg = bb[2048+ug], bo = bb[3072+ug];
  float* cc = cst + (size_t)dir*B_*H_;
  unsigned short* ho = hout + (size_t)dir*B_*H_;
  const int jbase = (lr & 8) ? 2 : 0;

  #pragma unroll
  for (int rf = 0; rf < 2; ++rf){
    f32x4 c0 = rf ? a10 : a00;      // gates i (lr<8) / f (lr>=8)
    f32x4 c1 = rf ? a11 : a01;      // gates g / o
    float p0[4], p1[4];
    #pragma unroll
    for (int j = 0; j < 4; ++j){
      p0[j] = __shfl_xor(c0[j], 8, 64);
      p1[j] = __shfl_xor(c1[j], 8, 64);
    }
    #pragma unroll
    for (int q = 0; q < 2; ++q){
      const int jj = jbase + q;
      float gi, gf, gg, go;
      if (lr & 8){ gi = p0[jj]; gf = c0[jj]; gg = p1[jj]; go = c1[jj]; }
      else       { gi = c0[jj]; gf = p0[jj]; gg = c1[jj]; go = p1[jj]; }
      gi += bi; gf += bfv; gg += bg; go += bo;
      const int m = m0g + rf*16 + lk*4 + jj;
      const size_t coff = (size_t)m*H_ + ug;
      float cold = cc[coff];
      float cn = sigm(gf)*cold + sigm(gi)*tanhf(gg);
      float hn = sigm(go)*tanhf(cn);
      cc[coff] = cn;
      ho[coff] = f2bf(hn);
      Q[((size_t)xs*B_ + m)*2048 + dir*1024 + ug] = hn;
    }
  }
}

// ---------------- qenc L2-normalize (in-place) + enc --------------------------
__global__ void k_qnorm(float* __restrict__ Q, float* __restrict__ enc){
  int sb = blockIdx.x;
  int s = sb >> 7, b = sb & 127;
  float* row = Q + (size_t)sb*2048;
  int tid = threadIdx.x;
  float v[8]; float ss = 0.f;
  #pragma unroll
  for (int i = 0; i < 8; ++i){ v[i] = row[tid*8+i]; ss += v[i]*v[i]; }
  __shared__ float red[256];
  red[tid] = ss; __syncthreads();
  for (int st = 128; st; st >>= 1){
    if (tid < st) red[tid] += red[tid+st];
    __syncthreads();
  }
  float inv = 1.0f / fmaxf(sqrtf(red[0]), 1e-12f);
  #pragma unroll
  for (int i = 0; i < 8; ++i){
    float q = v[i]*inv;
    row[tid*8+i] = q;
    if (s == S_-1) enc[(size_t)b*2048 + tid*8 + i] = q;
  }
}

// ---------------- per-pixel channel sumsq of img ------------------------------
__global__ void k_sqpart(const float* __restrict__ img, float* __restrict__ part){
  int b = blockIdx.x, cq = blockIdx.y;
  int t = threadIdx.x;
  if (t >= P_) return;
  const float* base = img + ((size_t)b*1024 + cq*256)*P_ + t;
  float s = 0.f;
  #pragma unroll 4
  for (int c = 0; c < 256; ++c){ float v = base[c*P_]; s += v*v; }
  part[((size_t)b*4 + cq)*P_ + t] = s;
}

__global__ void k_invnorm(const float* __restrict__ part, float* __restrict__ inv){
  int i = blockIdx.x*256 + threadIdx.x;
  if (i >= B_*P_) return;
  int b = i / P_, p = i % P_;
  float s = part[(b*4+0)*P_+p] + part[(b*4+1)*P_+p]
          + part[(b*4+2)*P_+p] + part[(b*4+3)*P_+p];
  inv[i] = 1.0f / fmaxf(sqrtf(s), 1e-12f);
}

// ---------------- img -> imgT[b][196][1056] bf16 (invnorm+coords+pad) ---------
__global__ void k_mkimgT(const float* __restrict__ img, const float* __restrict__ invn,
                         unsigned short* __restrict__ imgT){
  const int b = blockIdx.x, cg = blockIdx.y;
  const int tid = threadIdx.x;
  unsigned short* dstB = imgT + (size_t)b*196*1056;
  if (cg == 8){
    for (int i = tid; i < 196*32; i += 256){
      int p = i >> 5, cc = i & 31;
      float v = (cc == 0) ? c0f(p) : (cc == 1) ? c1f(p) : 0.f;
      dstB[(size_t)p*1056 + 1024 + cc] = f2bf(v);
    }
    return;
  }
  __shared__ unsigned short tt[196][136];
  __shared__ float sInv[200];
  for (int i = tid; i < 196; i += 256) sInv[i] = invn[b*196 + i];
  __syncthreads();
  const int c0 = cg*128;
  const float* srcB = img + ((size_t)b*1024 + c0)*196;
  for (int i = tid; i < 128*49; i += 256){
    int c = i / 49, p4 = i - (i/49)*49;
    float4 v = *(const float4*)(srcB + (size_t)c*196 + p4*4);
    int p = p4*4;
    tt[p+0][c] = f2bf(v.x * sInv[p+0]);
    tt[p+1][c] = f2bf(v.y * sInv[p+1]);
    tt[p+2][c] = f2bf(v.z * sInv[p+2]);
    tt[p+3][c] = f2bf(v.w * sInv[p+3]);
  }
  __syncthreads();
  for (int i = tid; i < 196*16; i += 256){
    int p = i >> 4, g = i & 15;
    *(short8v*)(dstB + (size_t)p*1056 + c0 + g*8) = *(short8v*)&tt[p][g*8];
  }
}

// ---------------- 3x3 conv via MFMA (A-frag register pipeline) ----------------
template<int CPAD>
__device__ __forceinline__ void stage3t(unsigned short (*__restrict__ tile)[40],
                                        const unsigned short* __restrict__ src,
                                        int c0, int r0, int tid){
  for (int i = tid; i < 10*14*4; i += 256){
    int t = i / 56, rem = i - t*56, gx = rem >> 2, seg = rem & 3;
    int gy = r0 - 1 + t;
    if ((unsigned)gy < 14u){
      short8v v = *(const short8v*)(src + (size_t)(gy*14+gx)*CPAD + c0 + seg*8);
      *(short8v*)&tile[t*16 + gx + 1][seg*8] = v;
    }
  }
}

template<int CPAD>
__launch_bounds__(256, 2)
__global__ void k_conv3t(const unsigned short* __restrict__ srcT,
                         const unsigned short* __restrict__ wPk,
                         const float* __restrict__ bias,
                         float* __restrict__ out){
  constexpr int T = CPAD / 32;
  const int b = blockIdx.x, n = blockIdx.y, z = blockIdx.z;
  const int r0 = n ? 6 : 0;
  const int chBeg = z ? T/2 : 0, chEnd = z ? T : T/2;
  const int tid = threadIdx.x, wave = tid >> 6, lane = tid & 63;
  const int lr = lane & 15, lk = lane >> 4;
  const int wfM = wave >> 1, wfN = wave & 1;
  const unsigned short* src = srcT + (size_t)b*196*CPAD;

  __shared__ unsigned short tile[2][164][40];

  for (int i = tid; i < 1640; i += 256)
    ((short8v*)&tile[0][0][0])[i] = short8v{0,0,0,0,0,0,0,0};
  __syncthreads();
  stage3t<CPAD>(tile[0], src, chBeg*32, r0, tid);
  __syncthreads();

  f32x4 acc[4][4];
  #pragma unroll
  for (int i = 0; i < 4; ++i)
    #pragma unroll
    for (int j = 0; j < 4; ++j) acc[i][j] = f32x4{0,0,0,0};

  short8v aC[12], aN[12];
  #pragma unroll
  for (int dx = 0; dx < 3; ++dx)
    #pragma unroll
    for (int rf = 0; rf < 4; ++rf)
      aC[dx*4+rf] = *(const short8v*)(wPk + ((((size_t)dx*8 + wfM*4 + rf)*T + chBeg)*64
                                             + lane)*8);

  for (int ch = chBeg; ch < chEnd; ++ch){
    const int cur = (ch - chBeg) & 1;
    #pragma unroll
    for (int dy = 0; dy < 3; ++dy){
      const int ndy = (dy < 2) ? dy + 1 : 0;
      const int nch = (dy < 2) ? ch : ch + 1;
      const bool hasN = nch < chEnd;
      if (hasN){
        #pragma unroll
        for (int dx = 0; dx < 3; ++dx)
          #pragma unroll
          for (int rf = 0; rf < 4; ++rf)
            aN[dx*4+rf] = *(const short8v*)(wPk + ((((size_t)(ndy*3+dx)*8 + wfM*4 + rf)*T
                                                    + nch)*64 + lane)*8);
      }
      #pragma unroll
      for (int dx = 0; dx < 3; ++dx){
        const int dlt = dy*16 + dx;
        #pragma unroll
        for (int cf = 0; cf < 4; ++cf){
          short8v bf = *(short8v*)&tile[cur][wfN*64 + cf*16 + lr + dlt][lk*8];
          #pragma unroll
          for (int rf = 0; rf < 4; ++rf)
            acc[rf][cf] = MFMA16(aC[dx*4+rf], bf, acc[rf][cf]);
        }
      }
      if (dy == 0 && ch + 1 < chEnd)
        stage3t<CPAD>(tile[cur^1], src, (ch+1)*32, r0, tid);
      if (hasN){
        #pragma unroll
        for (int q = 0; q < 12; ++q) aC[q] = aN[q];
      }
    }
    __syncthreads();
  }

  #pragma unroll
  for (int rf = 0; rf < 4; ++rf){
    #pragma unroll
    for (int j = 0; j < 4; ++j){
      const int oc = wfM*64 + rf*16 + lk*4 + j;
      const float bz = z ? 0.f : bias[oc];
      #pragma unroll
      for (int cf = 0; cf < 4; ++cf){
        const int pos = wfN*64 + cf*16 + lr;
        const int py = r0 + (pos >> 4), px = pos & 15;
        const bool rowok = n ? (py >= 8) : true;
        if (rowok && px < 14)
          out[(size_t)z*NE + ((size_t)b*OC_ + oc)*P_ + py*14 + px] = acc[rf][cf][j] + bz;
      }
    }
  }
}

// ---------------- BN stats over 2 partial slabs -------------------------------
__global__ void k_bnstats(const float* __restrict__ t, float* __restrict__ stats){
  int o = blockIdx.x;
  int tid = threadIdx.x;
  float s = 0.f, s2 = 0.f;
  #pragma unroll 4
  for (int i = tid; i < B_*P_; i += 256){
    int b = i / P_, p = i - (i/P_)*P_;
    size_t off = ((size_t)b*OC_ + o)*P_ + p;
    float v = t[off] + t[off + NE];
    s += v; s2 += v*v;
  }
  __shared__ float r1[256], r2[256];
  r1[tid] = s; r2[tid] = s2; __syncthreads();
  for (int st = 128; st; st >>= 1){
    if (tid < st){ r1[tid] += r1[tid+st]; r2[tid] += r2[tid+st]; }
    __syncthreads();
  }
  if (tid == 0){
    float n = (float)(B_*P_);
    float m = r1[0] / n;
    float var = r2[0] / n - m*m;
    stats[o*2]   = m;
    stats[o*2+1] = rsqrtf(var + 1e-5f);
  }
}

// ---------------- BN apply + relu (+add), emit bf16-T (or final f32) ----------
template<bool ADD, bool FINAL>
__global__ void k_bntr(const float* __restrict__ t, const float* __restrict__ stats,
                       const float* __restrict__ g, const float* __restrict__ bb,
                       const float* __restrict__ addsrc,
                       float* __restrict__ outF, unsigned short* __restrict__ outT){
  const int b = blockIdx.x, tid = threadIdx.x;
  for (int i = tid; i < 128*196; i += 256){
    int c = i / 196, p = i - c*196;
    size_t off = ((size_t)b*OC_ + c)*P_ + p;
    float x = t[off] + t[off + NE];
    float v = g[c]*(x - stats[c*2])*stats[c*2+1] + bb[c];
    v = fmaxf(v, 0.f);
    if (ADD) v += addsrc[off];
    if (FINAL) outF[off] = v;
    else       outT[((size_t)b*P_ + p)*160 + c] = f2bf(v);
  }
  if (!FINAL){
    for (int i = tid; i < 196*32; i += 256){
      int p = i >> 5, c2 = i & 31;
      float v = (c2 == 0) ? c0f(p) : (c2 == 1) ? c1f(p) : 0.f;
      outT[((size_t)b*P_ + p)*160 + 128 + c2] = f2bf(v);
    }
  }
}

// ---------------- 1x1 conv via MFMA -------------------------------------------
__launch_bounds__(256, 2)
__global__ void k_c1m(const unsigned short* __restrict__ vT,
                      const unsigned short* __restrict__ pk,
                      const float* __restrict__ bias,
                      float* __restrict__ out, unsigned short* __restrict__ outT){
  const int b = blockIdx.x, n = blockIdx.y;
  const int pBeg = n ? 112 : 0;
  const int nCF = n ? 6 : 7;
  const int tid = threadIdx.x, wave = tid >> 6, lane = tid & 63;
  const int lr = lane & 15, lk = lane >> 4;

  __shared__ unsigned short tile[112][164];

  for (int i = tid; i < 112*20; i += 256){
    int r = i / 20, seg = i - r*20;
    int p = pBeg + r;
    short8v v = short8v{0,0,0,0,0,0,0,0};
    if (p < 196 && r < nCF*16)
      v = *(const short8v*)(vT + ((size_t)b*P_ + p)*160 + seg*8);
    *(short8v*)&tile[r][seg*8] = v;
  }
  __syncthreads();

  f32x4 acc[2][7];
  #pragma unroll
  for (int i = 0; i < 2; ++i)
    #pragma unroll
    for (int j = 0; j < 7; ++j) acc[i][j] = f32x4{0,0,0,0};

  #pragma unroll
  for (int kc = 0; kc < 5; ++kc){
    short8v a0 = *(const short8v*)(pk + (((size_t)(wave*2 + 0)*5 + kc)*64 + lane)*8);
    short8v a1 = *(const short8v*)(pk + (((size_t)(wave*2 + 1)*5 + kc)*64 + lane)*8);
    #pragma unroll
    for (int cf = 0; cf < 7; ++cf){
      if (cf < nCF){
        short8v bf = *(short8v*)&tile[cf*16 + lr][kc*32 + lk*8];
        acc[0][cf] = MFMA16(a0, bf, acc[0][cf]);
        acc[1][cf] = MFMA16(a1, bf, acc[1][cf]);
      }
    }
  }

  #pragma unroll
  for (int rf = 0; rf < 2; ++rf){
    const int ocBase = wave*32 + rf*16 + lk*4;
    #pragma unroll
    for (int cf = 0; cf < 7; ++cf){
      if (cf < nCF){
        const int pos = pBeg + cf*16 + lr;
        if (pos < 196){
          short4v sv;
          #pragma unroll
          for (int j = 0; j < 4; ++j){
            const int oc = ocBase + j;
            float v = fmaxf(acc[rf][cf][j] + bias[oc], 0.f);
            out[((size_t)b*OC_ + oc)*P_ + pos] = v;
            sv[j] = (short)f2bf(v);
          }
          *(short4v*)(outT + ((size_t)b*P_ + pos)*128 + ocBase) = sv;
        }
      }
    }
  }
}

} // namespace

// ---------------------------------------------------------------------------
extern "C" void kernel_launch(void* const* d_in, const int* in_sizes, int n_in,
                              void* d_out, int out_size, void* d_ws, size_t ws_size,
                              hipStream_t stream){
  (void)in_sizes; (void)n_in; (void)out_size; (void)ws_size;
  const int*   que  = (const int*)  d_in[0];
  const float* img  = (const float*)d_in[1];
  const float* emb  = (const float*)d_in[2];
  const float* wihf = (const float*)d_in[3];
  const float* whhf = (const float*)d_in[4];
  const float* bihf = (const float*)d_in[5];
  const float* bhhf = (const float*)d_in[6];
  const float* wihb = (const float*)d_in[7];
  const float* whhb = (const float*)d_in[8];
  const float* bihb = (const float*)d_in[9];
  const float* bhhb = (const float*)d_in[10];
  const float* convw = (const float*)d_in[11];
  const float* convb = (const float*)d_in[12];
  const float* bng  = (const float*)d_in[13];
  const float* bnb  = (const float*)d_in[14];
  const float* r1c1w = (const float*)d_in[15];
  const float* r1c1b = (const float*)d_in[16];
  const float* r1c2w = (const float*)d_in[17];
  const float* r1c2b = (const float*)d_in[18];
  const float* r1bng = (const float*)d_in[19];
  const float* r1bnb = (const float*)d_in[20];
  const float* r2c1w = (const float*)d_in[21];
  const float* r2c1b = (const float*)d_in[22];
  const float* r2c2w = (const float*)d_in[23];
  const float* r2c2b = (const float*)d_in[24];
  const float* r2bng = (const float*)d_in[25];
  const float* r2bnb = (const float*)d_in[26];

  float* out  = (float*)d_out;
  float* enc  = out;                        // 128*2048
  float* Q    = out + 262144;               // 32*128*2048
  float* vout = out + 262144 + 8388608;     // 128*128*196

  // ------ workspace layout (f32 units) ----------------------------------------
  float* ws = (float*)d_ws;
  unsigned short* px   = (unsigned short*)ws;            // 32*8*12*512 bf16
  float* p1 = ws + 786432;
  unsigned short* pkW2 = (unsigned short*)p1;            // 2*32*4*2*44*512 bf16
  float* p2 = p1 + 5767168;
  float* bias2 = p2;                                     // 2*4096
  float* p3 = p2 + 8192;
  unsigned short* hstate = (unsigned short*)p3;          // 2par*2dir*128*1024 bf16
  float* p4 = p3 + 262144;
  float* cstate = p4;                                    // 2*128*1024
  float* p5 = p4 + 262144;
  float* part = p5;                                      // 128*4*196
  float* invn = p5 + 100352;                             // 128*196
  float* bufB = invn + 25088;                            // NE (v1 f32)
  float* convOut = bufB + NE;                            // 2*NE partial slabs
  float* p6 = convOut + 2*(size_t)NE;
  float* stats = p6;                                     // 256
  float* p7 = p6 + 256;
  unsigned short* pkC  = (unsigned short*)p7;            // 9*8*33*512 bf16
  float* p8 = p7 + 608256;
  unsigned short* pkR1 = (unsigned short*)p8;            // 9*8*4*512 bf16
  float* p9 = p8 + 73728;
  unsigned short* pkR2 = (unsigned short*)p9;            // 9*8*4*512 bf16
  float* p10 = p9 + 73728;
  unsigned short* pk1  = (unsigned short*)p10;           // 8*5*512 bf16
  float* p11 = p10 + 10240;
  unsigned short* pk2  = (unsigned short*)p11;           // 8*5*512 bf16
  float* p12 = p11 + 10240;
  unsigned short* imgT = (unsigned short*)p12;           // 128*196*1056 bf16
  float* p13 = p12 + 13246464;
  unsigned short* vTb  = (unsigned short*)p13;           // 128*196*160 bf16
  float* p14 = p13 + 2007040;
  unsigned short* v1T  = (unsigned short*)p14;           // 128*196*128 bf16

  hipMemsetAsync(hstate, 0, (size_t)(262144 + 262144)*sizeof(float), stream);

  // ------ packing / conversions ------------------------------------------------
  k_packW2<<<(2*32*4*2*KC*64 + 255)/256, 256, 0, stream>>>(wihf, whhf, wihb, whhb, pkW2);
  k_embed_px<<<(32*8*12*64 + 255)/256, 256, 0, stream>>>(que, emb, px);
  k_packC<<<(9*8*33*64 + 255)/256, 256, 0, stream>>>(convw, pkC, 1026, 33);
  k_packC<<<(9*8*4*64 + 255)/256, 256, 0, stream>>>(r1c2w, pkR1, 128, 4);
  k_packC<<<(9*8*4*64 + 255)/256, 256, 0, stream>>>(r2c2w, pkR2, 128, 4);
  k_packG<<<(8*5*64 + 255)/256, 256, 0, stream>>>(r1c1w, pk1, 130, 5);
  k_packG<<<(8*5*64 + 255)/256, 256, 0, stream>>>(r2c1w, pk2, 130, 5);
  k_bias2<<<32, 256, 0, stream>>>(bihf, bhhf, bihb, bhhb, bias2);

  // ------ bi-LSTM: 32 step launches -------------------------------------------
  for (int s = 0; s < 32; ++s){
    unsigned short* hin  = hstate + (size_t)(s & 1)*262144;
    unsigned short* hout = hstate + (size_t)((s & 1)^1)*262144;
    k_step9<<<dim3(64,4), 256, 0, stream>>>(px, pkW2, bias2, hin, hout,
                                            cstate, Q, s);
  }
  k_qnorm<<<4096, 256, 0, stream>>>(Q, enc);

  // ------ image branch --------------------------------------------------------
  k_sqpart<<<dim3(128,4), 256, 0, stream>>>(img, part);
  k_invnorm<<<(25088+255)/256, 256, 0, stream>>>(part, invn);
  k_mkimgT<<<dim3(128,9), 256, 0, stream>>>(img, invn, imgT);

  k_conv3t<1056><<<dim3(128,2,2), 256, 0, stream>>>(imgT, pkC, convb, convOut);
  k_bnstats<<<128, 256, 0, stream>>>(convOut, stats);
  k_bntr<false,false><<<128, 256, 0, stream>>>(convOut, stats, bng, bnb,
                                               nullptr, nullptr, vTb);

  // res block 1: vTb -> (bufB f32, v1T) -> convOut -> vTb
  k_c1m<<<dim3(128,2), 256, 0, stream>>>(vTb, pk1, r1c1b, bufB, v1T);
  k_conv3t<128><<<dim3(128,2,2), 256, 0, stream>>>(v1T, pkR1, r1c2b, convOut);
  k_bnstats<<<128, 256, 0, stream>>>(convOut, stats);
  k_bntr<true,false><<<128, 256, 0, stream>>>(convOut, stats, r1bng, r1bnb,
                                              bufB, nullptr, vTb);

  // res block 2: vTb -> (bufB, v1T) -> convOut -> vout
  k_c1m<<<dim3(128,2), 256, 0, stream>>>(vTb, pk2, r2c1b, bufB, v1T);
  k_conv3t<128><<<dim3(128,2,2), 256, 0, stream>>>(v1T, pkR2, r2c2b, convOut);
  k_bnstats<<<128, 256, 0, stream>>>(convOut, stats);
  k_bntr<true,true><<<128, 256, 0, stream>>>(convOut, stats, r2bng, r2bnb,
                                             bufB, vout, nullptr);
}

// Round 13
// 907.269 us; speedup vs baseline: 1.8367x; 1.1087x over previous
//
#include <hip/hip_runtime.h>
#include <hip/hip_bf16.h>
#include <math.h>

// ---------------------------------------------------------------------------
// R13: hoist the LSTM x-part GEMM out of the sequential loop. k_xg computes
//      x@Wih for ALL 32 steps in one wide launch, storing accumulators in
//      fragment order (bf16). k_step10 = h-only 32-chunk loop with acc init
//      from xg. xg aliases the image-phase buffers (mkimgT moved after qnorm).
//      Image branch identical to R12.
// ---------------------------------------------------------------------------

namespace {

constexpr int S_ = 32, B_ = 128, H_ = 1024, P_ = 196, OC_ = 128;
constexpr int NE = B_ * OC_ * P_;        // elems of a [B][128][196] slab
constexpr int KC = 44;                   // LSTM K chunks: 12 x + 32 h

typedef __attribute__((ext_vector_type(8))) short short8v;
typedef __attribute__((ext_vector_type(4))) short short4v;
typedef __attribute__((ext_vector_type(4))) float f32x4;
#define MFMA16(a, b, c) __builtin_amdgcn_mfma_f32_16x16x32_bf16((a), (b), (c), 0, 0, 0)

__device__ __forceinline__ float sigm(float x){ return 1.0f/(1.0f + expf(-x)); }
__device__ __forceinline__ float c0f(int p){ return ((float)p/14.0f - 7.0f)/7.0f; }
__device__ __forceinline__ float c1f(int p){ return ((float)(p%14) - 7.0f)/7.0f; }
__device__ __forceinline__ unsigned short f2bf(float x){
  __hip_bfloat16 h = __float2bfloat16(x);
  return *reinterpret_cast<unsigned short*>(&h);
}
__device__ __forceinline__ float bf2f(unsigned short u){
  unsigned v = ((unsigned)u) << 16;
  union { unsigned u; float f; } c; c.u = v; return c.f;
}

// ---------------- LSTM weights -> gate-pair fragment pack ---------------------
// pkW2[dir][uslab(32)][w(4)][pair(2)][kc(44)][lane(64)][8]:
// lane holds W[row = (pair*2+(lr>>3))*1024 + uslab*32 + w*8 + (lr&7)]
//           [k = kc*32 + (lane>>4)*8 + j]; kc<12 -> Wih (K=300 pad 384) else Whh.
__global__ void k_packW2(const float* __restrict__ wihf, const float* __restrict__ whhf,
                         const float* __restrict__ wihb, const float* __restrict__ whhb,
                         unsigned short* __restrict__ pk){
  int i = blockIdx.x*256 + threadIdx.x;
  if (i >= 2*32*4*2*KC*64) return;
  const int lane = i & 63;
  int t = i >> 6;
  const int kc = t % KC; t /= KC;
  const int pair = t % 2; t /= 2;
  const int w = t % 4; t /= 4;
  const int uslab = t % 32; t /= 32;
  const int dir = t;
  const int lr = lane & 15, lk = lane >> 4;
  const int row = (pair*2 + (lr >> 3))*1024 + uslab*32 + w*8 + (lr & 7);
  unsigned short v[8];
  if (kc < 12){
    const float* src = dir ? wihb : wihf;
    #pragma unroll
    for (int j = 0; j < 8; ++j){
      int k = kc*32 + lk*8 + j;
      v[j] = (k < 300) ? f2bf(src[(size_t)row*300 + k]) : (unsigned short)0;
    }
  } else {
    const float* src = dir ? whhb : whhf;
    #pragma unroll
    for (int j = 0; j < 8; ++j)
      v[j] = f2bf(src[(size_t)row*1024 + (kc-12)*32 + lk*8 + j]);
  }
  unsigned short* dst = pk + (size_t)i*8;
  #pragma unroll
  for (int j = 0; j < 8; ++j) dst[j] = v[j];
}

// ---------------- embedding -> fragment-packed px -----------------------------
// px[t(32)][mgrp(8)][kc(12)][lane][8]: lane holds x[t][b = mgrp*16 + (lane&15)]
// [k = kc*32 + (lane>>4)*8 + j] (k>=300 -> 0, padding token -> 0).
__global__ void k_embed_px(const int* __restrict__ que, const float* __restrict__ emb,
                           unsigned short* __restrict__ px){
  int i = blockIdx.x*256 + threadIdx.x;
  if (i >= 32*8*12*64) return;
  const int lane = i & 63;
  int t2 = i >> 6;
  const int kc = t2 % 12; t2 /= 12;
  const int mgrp = t2 % 8; t2 /= 8;
  const int t = t2;
  const int b = mgrp*16 + (lane & 15);
  const int tok = que[b*S_ + t];
  const int k0 = kc*32 + (lane >> 4)*8;
  unsigned short* dst = px + (size_t)i*8;
  #pragma unroll
  for (int j = 0; j < 8; ++j){
    int k = k0 + j;
    dst[j] = (tok == 0 || k >= 300) ? (unsigned short)0 : f2bf(emb[(size_t)tok*300 + k]);
  }
}

// ---------------- x-part GEMM for all steps -> xg (fragment-order bf16) -------
// grid (64 = dir*32+uslab, 4 = mslab, 32 = xs); block 256 (4 waves, wave = w).
// Record rid = (((xs*2+dir)*4+mslab)*32+uslab)*4 + w : [pair2][rf2][lane][4] bf16.
__launch_bounds__(256, 4)
__global__ void k_xg(const unsigned short* __restrict__ px,
                     const unsigned short* __restrict__ pkW2,
                     unsigned short* __restrict__ xg){
  const int dir = blockIdx.x >> 5, uslab = blockIdx.x & 31;
  const int mslab = blockIdx.y;
  const int xs = blockIdx.z;
  const int tid = threadIdx.x, w = tid >> 6, lane = tid & 63;

  const unsigned short* pb = pkW2 + ((((size_t)(dir*32 + uslab)*4 + w)*2)*KC*64 + lane)*8;
  const size_t pbPair = (size_t)KC*512;
  const unsigned short* pax = px + (((size_t)(xs*8 + mslab*2)*12)*64 + lane)*8;
  const size_t paxRf = (size_t)12*512;

  f32x4 a00{0,0,0,0}, a01{0,0,0,0}, a10{0,0,0,0}, a11{0,0,0,0};
  #pragma unroll 4
  for (int ch = 0; ch < 12; ++ch){
    short8v a0 = *(const short8v*)(pax + (size_t)ch*512);
    short8v a1 = *(const short8v*)(pax + paxRf + (size_t)ch*512);
    short8v b0 = *(const short8v*)(pb + (size_t)ch*512);
    short8v b1 = *(const short8v*)(pb + pbPair + (size_t)ch*512);
    a00 = MFMA16(a0, b0, a00); a01 = MFMA16(a0, b1, a01);
    a10 = MFMA16(a1, b0, a10); a11 = MFMA16(a1, b1, a11);
  }

  const size_t rid = (((size_t)((xs*2 + dir)*4 + mslab)*32 + uslab)*4 + w);
  unsigned short* rec = xg + rid*1024;
  f32x4 accs[4] = {a00, a01, a10, a11};   // [rf*2+pair] -> (p*2+r) index below
  #pragma unroll
  for (int r = 0; r < 2; ++r)
    #pragma unroll
    for (int p = 0; p < 2; ++p){
      f32x4 v = accs[r*2 + p];
      short4v sv;
      #pragma unroll
      for (int j = 0; j < 4; ++j) sv[j] = (short)f2bf(v[j]);
      *(short4v*)(rec + ((p*2 + r)*64 + lane)*4) = sv;
    }
}

// ---------------- conv3 weights -> fragment-order pack ------------------------
__global__ void k_packC(const float* __restrict__ w, unsigned short* __restrict__ pk,
                        int cin, int T){
  int i = blockIdx.x*256 + threadIdx.x;
  if (i >= 9*8*T*64) return;
  const int lane = i & 63;
  int t = i >> 6;
  const int kc = t % T; t /= T;
  const int ot = t % 8; t /= 8;
  const int s = t;
  const int oc = ot*16 + (lane & 15);
  const int c0 = kc*32 + (lane >> 4)*8;
  unsigned short* dst = pk + (((size_t)(s*8 + ot)*T + kc)*64 + lane)*8;
  #pragma unroll
  for (int j = 0; j < 8; ++j){
    int c = c0 + j;
    dst[j] = (c < cin) ? f2bf(w[((size_t)oc*cin + c)*9 + s]) : (unsigned short)0;
  }
}

// ---------------- 1x1 weights [128][cin] -> fragment-order pack ---------------
__global__ void k_packG(const float* __restrict__ w, unsigned short* __restrict__ pk,
                        int cin, int T){
  int i = blockIdx.x*256 + threadIdx.x;
  if (i >= 8*T*64) return;
  const int lane = i & 63;
  int t = i >> 6;
  const int kc = t % T; t /= T;
  const int ot = t;
  const int oc = ot*16 + (lane & 15);
  const int c0 = kc*32 + (lane >> 4)*8;
  unsigned short* dst = pk + (((size_t)(ot*T + kc))*64 + lane)*8;
  #pragma unroll
  for (int j = 0; j < 8; ++j){
    int c = c0 + j;
    dst[j] = (c < cin) ? f2bf(w[(size_t)oc*cin + c]) : (unsigned short)0;
  }
}

__global__ void k_bias2(const float* __restrict__ bif, const float* __restrict__ bhf,
                        const float* __restrict__ bib, const float* __restrict__ bhb,
                        float* __restrict__ out){
  int i = blockIdx.x*256 + threadIdx.x;
  if (i >= 8192) return;
  out[i] = (i < 4096) ? (bif[i] + bhf[i]) : (bib[i-4096] + bhb[i-4096]);
}

// ---------------- one LSTM step (v10: h-only loop, acc init from xg) ----------
// grid (64, 4): x = dir*32 + uslab, y = mslab. block 256 (4 waves, wave = w).
// tA = h rows only (66KB) -> 2 blocks/CU. Gate quadruple via __shfl_xor(8).
__launch_bounds__(256, 2)
__global__ void k_step10(const unsigned short* __restrict__ xg,
                         const unsigned short* __restrict__ pkW2,
                         const float* __restrict__ bias2,
                         const unsigned short* __restrict__ hin,
                         unsigned short* __restrict__ hout,
                         float* __restrict__ cst, float* __restrict__ Q, int s){
  const int dir   = blockIdx.x >> 5;
  const int uslab = blockIdx.x & 31;
  const int mslab = blockIdx.y;
  const int m0g   = mslab*32;
  const int tid = threadIdx.x, w = tid >> 6, lane = tid & 63;
  const int lr = lane & 15, lk = lane >> 4;
  const int xs = dir ? (S_-1-s) : s;

  __shared__ unsigned short tA[32][1032];   // h rows m0g..+32

  // ---- stage h: thread r=tid>>3, sg=tid&7: 16 x 16B coalesced ----
  {
    const int r = tid >> 3, sg = tid & 7;
    const unsigned short* hr = hin + ((size_t)dir*B_ + m0g + r)*H_ + sg*128;
    #pragma unroll
    for (int q = 0; q < 16; ++q)
      *(short8v*)&tA[r][sg*128 + q*8] = *(const short8v*)(hr + q*8);
  }

  // ---- acc init from xg record ----
  const size_t rid = (((size_t)((xs*2 + dir)*4 + mslab)*32 + uslab)*4 + w);
  const unsigned short* rec = xg + rid*1024;
  f32x4 a00, a01, a10, a11;
  {
    short4v s00 = *(const short4v*)(rec + ((0*2 + 0)*64 + lane)*4);  // p0 r0
    short4v s01 = *(const short4v*)(rec + ((1*2 + 0)*64 + lane)*4);  // p1 r0
    short4v s10 = *(const short4v*)(rec + ((0*2 + 1)*64 + lane)*4);  // p0 r1
    short4v s11 = *(const short4v*)(rec + ((1*2 + 1)*64 + lane)*4);  // p1 r1
    #pragma unroll
    for (int j = 0; j < 4; ++j){
      a00[j] = bf2f((unsigned short)s00[j]);
      a01[j] = bf2f((unsigned short)s01[j]);
      a10[j] = bf2f((unsigned short)s10[j]);
      a11[j] = bf2f((unsigned short)s11[j]);
    }
  }

  const unsigned short* pb = pkW2 + ((((size_t)(dir*32 + uslab)*4 + w)*2)*KC*64 + lane)*8;
  const size_t pbPair = (size_t)KC*512;

  __syncthreads();    // tA ready

  // ---- h-part: 32 chunks, A from LDS, B packed global ----
  #pragma unroll 8
  for (int ch = 0; ch < 32; ++ch){
    const int ka = ch*32 + lk*8;
    short8v a0 = *(short8v*)&tA[lr][ka];
    short8v a1 = *(short8v*)&tA[16 + lr][ka];
    short8v b0 = *(const short8v*)(pb + (size_t)(12 + ch)*512);
    short8v b1 = *(const short8v*)(pb + pbPair + (size_t)(12 + ch)*512);
    a00 = MFMA16(a0, b0, a00); a01 = MFMA16(a0, b1, a01);
    a10 = MFMA16(a1, b0, a10); a11 = MFMA16(a1, b1, a11);
  }

  // ---- epilogue: shuffle-recombine gate quadruple, gate math ----
  const int ug = uslab*32 + w*8 + (lr & 7);
  const float* bb = bias2 + (size_t)dir*4096;
  const float bi = bb[ug], bfv = bb[1024+ug], bg = bb[2048+ug], bo = bb[3072+ug];
  float* cc = cst + (size_t)dir*B_*H_;
  unsigned short* ho = hout + (size_t)dir*B_*H_;
  const int jbase = (lr & 8) ? 2 : 0;

  #pragma unroll
  for (int rf = 0; rf < 2; ++rf){
    f32x4 c0 = rf ? a10 : a00;
    f32x4 c1 = rf ? a11 : a01;
    float p0[4], p1[4];
    #pragma unroll
    for (int j = 0; j < 4; ++j){
      p0[j] = __shfl_xor(c0[j], 8, 64);
      p1[j] = __shfl_xor(c1[j], 8, 64);
    }
    #pragma unroll
    for (int q = 0; q < 2; ++q){
      const int jj = jbase + q;
      float gi, gf, gg, go;
      if (lr & 8){ gi = p0[jj]; gf = c0[jj]; gg = p1[jj]; go = c1[jj]; }
      else       { gi = c0[jj]; gf = p0[jj]; gg = c1[jj]; go = p1[jj]; }
      gi += bi; gf += bfv; gg += bg; go += bo;
      const int m = m0g + rf*16 + lk*4 + jj;
      const size_t coff = (size_t)m*H_ + ug;
      float cold = cc[coff];
      float cn = sigm(gf)*cold + sigm(gi)*tanhf(gg);
      float hn = sigm(go)*tanhf(cn);
      cc[coff] = cn;
      ho[coff] = f2bf(hn);
      Q[((size_t)xs*B_ + m)*2048 + dir*1024 + ug] = hn;
    }
  }
}

// ---------------- qenc L2-normalize (in-place) + enc --------------------------
__global__ void k_qnorm(float* __restrict__ Q, float* __restrict__ enc){
  int sb = blockIdx.x;
  int s = sb >> 7, b = sb & 127;
  float* row = Q + (size_t)sb*2048;
  int tid = threadIdx.x;
  float v[8]; float ss = 0.f;
  #pragma unroll
  for (int i = 0; i < 8; ++i){ v[i] = row[tid*8+i]; ss += v[i]*v[i]; }
  __shared__ float red[256];
  red[tid] = ss; __syncthreads();
  for (int st = 128; st; st >>= 1){
    if (tid < st) red[tid] += red[tid+st];
    __syncthreads();
  }
  float inv = 1.0f / fmaxf(sqrtf(red[0]), 1e-12f);
  #pragma unroll
  for (int i = 0; i < 8; ++i){
    float q = v[i]*inv;
    row[tid*8+i] = q;
    if (s == S_-1) enc[(size_t)b*2048 + tid*8 + i] = q;
  }
}

// ---------------- per-pixel channel sumsq of img ------------------------------
__global__ void k_sqpart(const float* __restrict__ img, float* __restrict__ part){
  int b = blockIdx.x, cq = blockIdx.y;
  int t = threadIdx.x;
  if (t >= P_) return;
  const float* base = img + ((size_t)b*1024 + cq*256)*P_ + t;
  float s = 0.f;
  #pragma unroll 4
  for (int c = 0; c < 256; ++c){ float v = base[c*P_]; s += v*v; }
  part[((size_t)b*4 + cq)*P_ + t] = s;
}

__global__ void k_invnorm(const float* __restrict__ part, float* __restrict__ inv){
  int i = blockIdx.x*256 + threadIdx.x;
  if (i >= B_*P_) return;
  int b = i / P_, p = i % P_;
  float s = part[(b*4+0)*P_+p] + part[(b*4+1)*P_+p]
          + part[(b*4+2)*P_+p] + part[(b*4+3)*P_+p];
  inv[i] = 1.0f / fmaxf(sqrtf(s), 1e-12f);
}

// ---------------- img -> imgT[b][196][1056] bf16 (invnorm+coords+pad) ---------
__global__ void k_mkimgT(const float* __restrict__ img, const float* __restrict__ invn,
                         unsigned short* __restrict__ imgT){
  const int b = blockIdx.x, cg = blockIdx.y;
  const int tid = threadIdx.x;
  unsigned short* dstB = imgT + (size_t)b*196*1056;
  if (cg == 8){
    for (int i = tid; i < 196*32; i += 256){
      int p = i >> 5, cc = i & 31;
      float v = (cc == 0) ? c0f(p) : (cc == 1) ? c1f(p) : 0.f;
      dstB[(size_t)p*1056 + 1024 + cc] = f2bf(v);
    }
    return;
  }
  __shared__ unsigned short tt[196][136];
  __shared__ float sInv[200];
  for (int i = tid; i < 196; i += 256) sInv[i] = invn[b*196 + i];
  __syncthreads();
  const int c0 = cg*128;
  const float* srcB = img + ((size_t)b*1024 + c0)*196;
  for (int i = tid; i < 128*49; i += 256){
    int c = i / 49, p4 = i - (i/49)*49;
    float4 v = *(const float4*)(srcB + (size_t)c*196 + p4*4);
    int p = p4*4;
    tt[p+0][c] = f2bf(v.x * sInv[p+0]);
    tt[p+1][c] = f2bf(v.y * sInv[p+1]);
    tt[p+2][c] = f2bf(v.z * sInv[p+2]);
    tt[p+3][c] = f2bf(v.w * sInv[p+3]);
  }
  __syncthreads();
  for (int i = tid; i < 196*16; i += 256){
    int p = i >> 4, g = i & 15;
    *(short8v*)(dstB + (size_t)p*1056 + c0 + g*8) = *(short8v*)&tt[p][g*8];
  }
}

// ---------------- 3x3 conv via MFMA (A-frag register pipeline) ----------------
template<int CPAD>
__device__ __forceinline__ void stage3t(unsigned short (*__restrict__ tile)[40],
                                        const unsigned short* __restrict__ src,
                                        int c0, int r0, int tid){
  for (int i = tid; i < 10*14*4; i += 256){
    int t = i / 56, rem = i - t*56, gx = rem >> 2, seg = rem & 3;
    int gy = r0 - 1 + t;
    if ((unsigned)gy < 14u){
      short8v v = *(const short8v*)(src + (size_t)(gy*14+gx)*CPAD + c0 + seg*8);
      *(short8v*)&tile[t*16 + gx + 1][seg*8] = v;
    }
  }
}

template<int CPAD>
__launch_bounds__(256, 2)
__global__ void k_conv3t(const unsigned short* __restrict__ srcT,
                         const unsigned short* __restrict__ wPk,
                         const float* __restrict__ bias,
                         float* __restrict__ out){
  constexpr int T = CPAD / 32;
  const int b = blockIdx.x, n = blockIdx.y, z = blockIdx.z;
  const int r0 = n ? 6 : 0;
  const int chBeg = z ? T/2 : 0, chEnd = z ? T : T/2;
  const int tid = threadIdx.x, wave = tid >> 6, lane = tid & 63;
  const int lr = lane & 15, lk = lane >> 4;
  const int wfM = wave >> 1, wfN = wave & 1;
  const unsigned short* src = srcT + (size_t)b*196*CPAD;

  __shared__ unsigned short tile[2][164][40];

  for (int i = tid; i < 1640; i += 256)
    ((short8v*)&tile[0][0][0])[i] = short8v{0,0,0,0,0,0,0,0};
  __syncthreads();
  stage3t<CPAD>(tile[0], src, chBeg*32, r0, tid);
  __syncthreads();

  f32x4 acc[4][4];
  #pragma unroll
  for (int i = 0; i < 4; ++i)
    #pragma unroll
    for (int j = 0; j < 4; ++j) acc[i][j] = f32x4{0,0,0,0};

  short8v aC[12], aN[12];
  #pragma unroll
  for (int dx = 0; dx < 3; ++dx)
    #pragma unroll
    for (int rf = 0; rf < 4; ++rf)
      aC[dx*4+rf] = *(const short8v*)(wPk + ((((size_t)dx*8 + wfM*4 + rf)*T + chBeg)*64
                                             + lane)*8);

  for (int ch = chBeg; ch < chEnd; ++ch){
    const int cur = (ch - chBeg) & 1;
    #pragma unroll
    for (int dy = 0; dy < 3; ++dy){
      const int ndy = (dy < 2) ? dy + 1 : 0;
      const int nch = (dy < 2) ? ch : ch + 1;
      const bool hasN = nch < chEnd;
      if (hasN){
        #pragma unroll
        for (int dx = 0; dx < 3; ++dx)
          #pragma unroll
          for (int rf = 0; rf < 4; ++rf)
            aN[dx*4+rf] = *(const short8v*)(wPk + ((((size_t)(ndy*3+dx)*8 + wfM*4 + rf)*T
                                                    + nch)*64 + lane)*8);
      }
      #pragma unroll
      for (int dx = 0; dx < 3; ++dx){
        const int dlt = dy*16 + dx;
        #pragma unroll
        for (int cf = 0; cf < 4; ++cf){
          short8v bf = *(short8v*)&tile[cur][wfN*64 + cf*16 + lr + dlt][lk*8];
          #pragma unroll
          for (int rf = 0; rf < 4; ++rf)
            acc[rf][cf] = MFMA16(aC[dx*4+rf], bf, acc[rf][cf]);
        }
      }
      if (dy == 0 && ch + 1 < chEnd)
        stage3t<CPAD>(tile[cur^1], src, (ch+1)*32, r0, tid);
      if (hasN){
        #pragma unroll
        for (int q = 0; q < 12; ++q) aC[q] = aN[q];
      }
    }
    __syncthreads();
  }

  #pragma unroll
  for (int rf = 0; rf < 4; ++rf){
    #pragma unroll
    for (int j = 0; j < 4; ++j){
      const int oc = wfM*64 + rf*16 + lk*4 + j;
      const float bz = z ? 0.f : bias[oc];
      #pragma unroll
      for (int cf = 0; cf < 4; ++cf){
        const int pos = wfN*64 + cf*16 + lr;
        const int py = r0 + (pos >> 4), px = pos & 15;
        const bool rowok = n ? (py >= 8) : true;
        if (rowok && px < 14)
          out[(size_t)z*NE + ((size_t)b*OC_ + oc)*P_ + py*14 + px] = acc[rf][cf][j] + bz;
      }
    }
  }
}

// ---------------- BN stats over 2 partial slabs -------------------------------
__global__ void k_bnstats(const float* __restrict__ t, float* __restrict__ stats){
  int o = blockIdx.x;
  int tid = threadIdx.x;
  float s = 0.f, s2 = 0.f;
  #pragma unroll 4
  for (int i = tid; i < B_*P_; i += 256){
    int b = i / P_, p = i - (i/P_)*P_;
    size_t off = ((size_t)b*OC_ + o)*P_ + p;
    float v = t[off] + t[off + NE];
    s += v; s2 += v*v;
  }
  __shared__ float r1[256], r2[256];
  r1[tid] = s; r2[tid] = s2; __syncthreads();
  for (int st = 128; st; st >>= 1){
    if (tid < st){ r1[tid] += r1[tid+st]; r2[tid] += r2[tid+st]; }
    __syncthreads();
  }
  if (tid == 0){
    float n = (float)(B_*P_);
    float m = r1[0] / n;
    float var = r2[0] / n - m*m;
    stats[o*2]   = m;
    stats[o*2+1] = rsqrtf(var + 1e-5f);
  }
}

// ---------------- BN apply + relu (+add), emit bf16-T (or final f32) ----------
template<bool ADD, bool FINAL>
__global__ void k_bntr(const float* __restrict__ t, const float* __restrict__ stats,
                       const float* __restrict__ g, const float* __restrict__ bb,
                       const float* __restrict__ addsrc,
                       float* __restrict__ outF, unsigned short* __restrict__ outT){
  const int b = blockIdx.x, tid = threadIdx.x;
  for (int i = tid; i < 128*196; i += 256){
    int c = i / 196, p = i - c*196;
    size_t off = ((size_t)b*OC_ + c)*P_ + p;
    float x = t[off] + t[off + NE];
    float v = g[c]*(x - stats[c*2])*stats[c*2+1] + bb[c];
    v = fmaxf(v, 0.f);
    if (ADD) v += addsrc[off];
    if (FINAL) outF[off] = v;
    else       outT[((size_t)b*P_ + p)*160 + c] = f2bf(v);
  }
  if (!FINAL){
    for (int i = tid; i < 196*32; i += 256){
      int p = i >> 5, c2 = i & 31;
      float v = (c2 == 0) ? c0f(p) : (c2 == 1) ? c1f(p) : 0.f;
      outT[((size_t)b*P_ + p)*160 + 128 + c2] = f2bf(v);
    }
  }
}

// ---------------- 1x1 conv via MFMA -------------------------------------------
__launch_bounds__(256, 2)
__global__ void k_c1m(const unsigned short* __restrict__ vT,
                      const unsigned short* __restrict__ pk,
                      const float* __restrict__ bias,
                      float* __restrict__ out, unsigned short* __restrict__ outT){
  const int b = blockIdx.x, n = blockIdx.y;
  const int pBeg = n ? 112 : 0;
  const int nCF = n ? 6 : 7;
  const int tid = threadIdx.x, wave = tid >> 6, lane = tid & 63;
  const int lr = lane & 15, lk = lane >> 4;

  __shared__ unsigned short tile[112][164];

  for (int i = tid; i < 112*20; i += 256){
    int r = i / 20, seg = i - r*20;
    int p = pBeg + r;
    short8v v = short8v{0,0,0,0,0,0,0,0};
    if (p < 196 && r < nCF*16)
      v = *(const short8v*)(vT + ((size_t)b*P_ + p)*160 + seg*8);
    *(short8v*)&tile[r][seg*8] = v;
  }
  __syncthreads();

  f32x4 acc[2][7];
  #pragma unroll
  for (int i = 0; i < 2; ++i)
    #pragma unroll
    for (int j = 0; j < 7; ++j) acc[i][j] = f32x4{0,0,0,0};

  #pragma unroll
  for (int kc = 0; kc < 5; ++kc){
    short8v a0 = *(const short8v*)(pk + (((size_t)(wave*2 + 0)*5 + kc)*64 + lane)*8);
    short8v a1 = *(const short8v*)(pk + (((size_t)(wave*2 + 1)*5 + kc)*64 + lane)*8);
    #pragma unroll
    for (int cf = 0; cf < 7; ++cf){
      if (cf < nCF){
        short8v bf = *(short8v*)&tile[cf*16 + lr][kc*32 + lk*8];
        acc[0][cf] = MFMA16(a0, bf, acc[0][cf]);
        acc[1][cf] = MFMA16(a1, bf, acc[1][cf]);
      }
    }
  }

  #pragma unroll
  for (int rf = 0; rf < 2; ++rf){
    const int ocBase = wave*32 + rf*16 + lk*4;
    #pragma unroll
    for (int cf = 0; cf < 7; ++cf){
      if (cf < nCF){
        const int pos = pBeg + cf*16 + lr;
        if (pos < 196){
          short4v sv;
          #pragma unroll
          for (int j = 0; j < 4; ++j){
            const int oc = ocBase + j;
            float v = fmaxf(acc[rf][cf][j] + bias[oc], 0.f);
            out[((size_t)b*OC_ + oc)*P_ + pos] = v;
            sv[j] = (short)f2bf(v);
          }
          *(short4v*)(outT + ((size_t)b*P_ + pos)*128 + ocBase) = sv;
        }
      }
    }
  }
}

} // namespace

// ---------------------------------------------------------------------------
extern "C" void kernel_launch(void* const* d_in, const int* in_sizes, int n_in,
                              void* d_out, int out_size, void* d_ws, size_t ws_size,
                              hipStream_t stream){
  (void)in_sizes; (void)n_in; (void)out_size; (void)ws_size;
  const int*   que  = (const int*)  d_in[0];
  const float* img  = (const float*)d_in[1];
  const float* emb  = (const float*)d_in[2];
  const float* wihf = (const float*)d_in[3];
  const float* whhf = (const float*)d_in[4];
  const float* bihf = (const float*)d_in[5];
  const float* bhhf = (const float*)d_in[6];
  const float* wihb = (const float*)d_in[7];
  const float* whhb = (const float*)d_in[8];
  const float* bihb = (const float*)d_in[9];
  const float* bhhb = (const float*)d_in[10];
  const float* convw = (const float*)d_in[11];
  const float* convb = (const float*)d_in[12];
  const float* bng  = (const float*)d_in[13];
  const float* bnb  = (const float*)d_in[14];
  const float* r1c1w = (const float*)d_in[15];
  const float* r1c1b = (const float*)d_in[16];
  const float* r1c2w = (const float*)d_in[17];
  const float* r1c2b = (const float*)d_in[18];
  const float* r1bng = (const float*)d_in[19];
  const float* r1bnb = (const float*)d_in[20];
  const float* r2c1w = (const float*)d_in[21];
  const float* r2c1b = (const float*)d_in[22];
  const float* r2c2w = (const float*)d_in[23];
  const float* r2c2b = (const float*)d_in[24];
  const float* r2bng = (const float*)d_in[25];
  const float* r2bnb = (const float*)d_in[26];

  float* out  = (float*)d_out;
  float* enc  = out;                        // 128*2048
  float* Q    = out + 262144;               // 32*128*2048
  float* vout = out + 262144 + 8388608;     // 128*128*196

  // ------ workspace layout (f32 units) ----------------------------------------
  float* ws = (float*)d_ws;
  unsigned short* px   = (unsigned short*)ws;                  // 32*8*12*512 bf16
  unsigned short* pkW2 = (unsigned short*)(ws + 786432);       // 2*32*4*2*44*512 bf16
  float* bias2 = ws + 6553600;                                 // 2*4096
  unsigned short* hstate = (unsigned short*)(ws + 6561792);    // 2par*2dir*128*1024 bf16
  float* cstate = ws + 6823936;                                // 2*128*1024
  float* part   = ws + 7086080;                                // 128*4*196
  float* invn   = ws + 7186432;                                // 128*196
  float* stats  = ws + 7211520;                                // 256
  unsigned short* pkC  = (unsigned short*)(ws + 7211776);      // 9*8*33*512 bf16
  unsigned short* pkR1 = (unsigned short*)(ws + 7820032);      // 9*8*4*512 bf16
  unsigned short* pkR2 = (unsigned short*)(ws + 7893760);      // 9*8*4*512 bf16
  unsigned short* pk1  = (unsigned short*)(ws + 7967488);      // 8*5*512 bf16
  unsigned short* pk2  = (unsigned short*)(ws + 7977728);      // 8*5*512 bf16
  float* U = ws + 7987968;                                     // union region
  // LSTM phase: xg = 32768 records x 1024 bf16 = 16.7M floats
  unsigned short* xg = (unsigned short*)U;
  // image phase (written only after LSTM finishes):
  float* bufB = U;                                             // NE (v1 f32)
  float* convOut = U + NE;                                     // 2*NE partial slabs
  unsigned short* imgT = (unsigned short*)(U + NE + 2*(size_t)NE);   // 128*196*1056
  unsigned short* vTb  = (unsigned short*)(U + 9633792 + 13246464);  // 128*196*160
  unsigned short* v1T  = (unsigned short*)(U + 9633792 + 13246464 + 2007040);

  hipMemsetAsync(hstate, 0, (size_t)(262144 + 262144)*sizeof(float), stream);

  // ------ packing / conversions ------------------------------------------------
  k_packW2<<<(2*32*4*2*KC*64 + 255)/256, 256, 0, stream>>>(wihf, whhf, wihb, whhb, pkW2);
  k_embed_px<<<(32*8*12*64 + 255)/256, 256, 0, stream>>>(que, emb, px);
  k_packC<<<(9*8*33*64 + 255)/256, 256, 0, stream>>>(convw, pkC, 1026, 33);
  k_packC<<<(9*8*4*64 + 255)/256, 256, 0, stream>>>(r1c2w, pkR1, 128, 4);
  k_packC<<<(9*8*4*64 + 255)/256, 256, 0, stream>>>(r2c2w, pkR2, 128, 4);
  k_packG<<<(8*5*64 + 255)/256, 256, 0, stream>>>(r1c1w, pk1, 130, 5);
  k_packG<<<(8*5*64 + 255)/256, 256, 0, stream>>>(r2c1w, pk2, 130, 5);
  k_bias2<<<32, 256, 0, stream>>>(bihf, bhhf, bihb, bhhb, bias2);

  // ------ x-part GEMM for all steps (one wide launch) --------------------------
  k_xg<<<dim3(64,4,32), 256, 0, stream>>>(px, pkW2, xg);

  // ------ bi-LSTM: 32 h-only step launches -------------------------------------
  for (int s = 0; s < 32; ++s){
    unsigned short* hin  = hstate + (size_t)(s & 1)*262144;
    unsigned short* hout = hstate + (size_t)((s & 1)^1)*262144;
    k_step10<<<dim3(64,4), 256, 0, stream>>>(xg, pkW2, bias2, hin, hout,
                                             cstate, Q, s);
  }
  k_qnorm<<<4096, 256, 0, stream>>>(Q, enc);

  // ------ image branch (after LSTM: imgT/bufB/convOut alias xg) ---------------
  k_sqpart<<<dim3(128,4), 256, 0, stream>>>(img, part);
  k_invnorm<<<(25088+255)/256, 256, 0, stream>>>(part, invn);
  k_mkimgT<<<dim3(128,9), 256, 0, stream>>>(img, invn, imgT);

  k_conv3t<1056><<<dim3(128,2,2), 256, 0, stream>>>(imgT, pkC, convb, convOut);
  k_bnstats<<<128, 256, 0, stream>>>(convOut, stats);
  k_bntr<false,false><<<128, 256, 0, stream>>>(convOut, stats, bng, bnb,
                                               nullptr, nullptr, vTb);

  // res block 1: vTb -> (bufB f32, v1T) -> convOut -> vTb
  k_c1m<<<dim3(128,2), 256, 0, stream>>>(vTb, pk1, r1c1b, bufB, v1T);
  k_conv3t<128><<<dim3(128,2,2), 256, 0, stream>>>(v1T, pkR1, r1c2b, convOut);
  k_bnstats<<<128, 256, 0, stream>>>(convOut, stats);
  k_bntr<true,false><<<128, 256, 0, stream>>>(convOut, stats, r1bng, r1bnb,
                                              bufB, nullptr, vTb);

  // res block 2: vTb -> (bufB, v1T) -> convOut -> vout
  k_c1m<<<dim3(128,2), 256, 0, stream>>>(vTb, pk2, r2c1b, bufB, v1T);
  k_conv3t<128><<<dim3(128,2,2), 256, 0, stream>>>(v1T, pkR2, r2c2b, convOut);
  k_bnstats<<<128, 256, 0, stream>>>(convOut, stats);
  k_bntr<true,true><<<128, 256, 0, stream>>>(convOut, stats, r2bng, r2bnb,
                                             bufB, vout, nullptr);
}

// Round 14
// 833.833 us; speedup vs baseline: 1.9985x; 1.0881x over previous
//
#include <hip/hip_runtime.h>
#include <hip/hip_bf16.h>
#include <math.h>

// ---------------------------------------------------------------------------
// R14: widen the elementwise/stats tail. bnstats -> 2-phase (1024 blocks +
//      finalize); bntr -> grid (128b x 8 oc-seg); vTb coords written once
//      (k_coordT). All MFMA kernels identical to R13.
// ---------------------------------------------------------------------------

namespace {

constexpr int S_ = 32, B_ = 128, H_ = 1024, P_ = 196, OC_ = 128;
constexpr int NE = B_ * OC_ * P_;        // elems of a [B][128][196] slab
constexpr int KC = 44;                   // LSTM K chunks: 12 x + 32 h

typedef __attribute__((ext_vector_type(8))) short short8v;
typedef __attribute__((ext_vector_type(4))) short short4v;
typedef __attribute__((ext_vector_type(4))) float f32x4;
#define MFMA16(a, b, c) __builtin_amdgcn_mfma_f32_16x16x32_bf16((a), (b), (c), 0, 0, 0)

__device__ __forceinline__ float sigm(float x){ return 1.0f/(1.0f + expf(-x)); }
__device__ __forceinline__ float c0f(int p){ return ((float)p/14.0f - 7.0f)/7.0f; }
__device__ __forceinline__ float c1f(int p){ return ((float)(p%14) - 7.0f)/7.0f; }
__device__ __forceinline__ unsigned short f2bf(float x){
  __hip_bfloat16 h = __float2bfloat16(x);
  return *reinterpret_cast<unsigned short*>(&h);
}
__device__ __forceinline__ float bf2f(unsigned short u){
  unsigned v = ((unsigned)u) << 16;
  union { unsigned u; float f; } c; c.u = v; return c.f;
}

// ---------------- LSTM weights -> gate-pair fragment pack ---------------------
__global__ void k_packW2(const float* __restrict__ wihf, const float* __restrict__ whhf,
                         const float* __restrict__ wihb, const float* __restrict__ whhb,
                         unsigned short* __restrict__ pk){
  int i = blockIdx.x*256 + threadIdx.x;
  if (i >= 2*32*4*2*KC*64) return;
  const int lane = i & 63;
  int t = i >> 6;
  const int kc = t % KC; t /= KC;
  const int pair = t % 2; t /= 2;
  const int w = t % 4; t /= 4;
  const int uslab = t % 32; t /= 32;
  const int dir = t;
  const int lr = lane & 15, lk = lane >> 4;
  const int row = (pair*2 + (lr >> 3))*1024 + uslab*32 + w*8 + (lr & 7);
  unsigned short v[8];
  if (kc < 12){
    const float* src = dir ? wihb : wihf;
    #pragma unroll
    for (int j = 0; j < 8; ++j){
      int k = kc*32 + lk*8 + j;
      v[j] = (k < 300) ? f2bf(src[(size_t)row*300 + k]) : (unsigned short)0;
    }
  } else {
    const float* src = dir ? whhb : whhf;
    #pragma unroll
    for (int j = 0; j < 8; ++j)
      v[j] = f2bf(src[(size_t)row*1024 + (kc-12)*32 + lk*8 + j]);
  }
  unsigned short* dst = pk + (size_t)i*8;
  #pragma unroll
  for (int j = 0; j < 8; ++j) dst[j] = v[j];
}

// ---------------- embedding -> fragment-packed px -----------------------------
__global__ void k_embed_px(const int* __restrict__ que, const float* __restrict__ emb,
                           unsigned short* __restrict__ px){
  int i = blockIdx.x*256 + threadIdx.x;
  if (i >= 32*8*12*64) return;
  const int lane = i & 63;
  int t2 = i >> 6;
  const int kc = t2 % 12; t2 /= 12;
  const int mgrp = t2 % 8; t2 /= 8;
  const int t = t2;
  const int b = mgrp*16 + (lane & 15);
  const int tok = que[b*S_ + t];
  const int k0 = kc*32 + (lane >> 4)*8;
  unsigned short* dst = px + (size_t)i*8;
  #pragma unroll
  for (int j = 0; j < 8; ++j){
    int k = k0 + j;
    dst[j] = (tok == 0 || k >= 300) ? (unsigned short)0 : f2bf(emb[(size_t)tok*300 + k]);
  }
}

// ---------------- x-part GEMM for all steps -> xg (fragment-order bf16) -------
__launch_bounds__(256, 4)
__global__ void k_xg(const unsigned short* __restrict__ px,
                     const unsigned short* __restrict__ pkW2,
                     unsigned short* __restrict__ xg){
  const int dir = blockIdx.x >> 5, uslab = blockIdx.x & 31;
  const int mslab = blockIdx.y;
  const int xs = blockIdx.z;
  const int tid = threadIdx.x, w = tid >> 6, lane = tid & 63;

  const unsigned short* pb = pkW2 + ((((size_t)(dir*32 + uslab)*4 + w)*2)*KC*64 + lane)*8;
  const size_t pbPair = (size_t)KC*512;
  const unsigned short* pax = px + (((size_t)(xs*8 + mslab*2)*12)*64 + lane)*8;
  const size_t paxRf = (size_t)12*512;

  f32x4 a00{0,0,0,0}, a01{0,0,0,0}, a10{0,0,0,0}, a11{0,0,0,0};
  #pragma unroll 4
  for (int ch = 0; ch < 12; ++ch){
    short8v a0 = *(const short8v*)(pax + (size_t)ch*512);
    short8v a1 = *(const short8v*)(pax + paxRf + (size_t)ch*512);
    short8v b0 = *(const short8v*)(pb + (size_t)ch*512);
    short8v b1 = *(const short8v*)(pb + pbPair + (size_t)ch*512);
    a00 = MFMA16(a0, b0, a00); a01 = MFMA16(a0, b1, a01);
    a10 = MFMA16(a1, b0, a10); a11 = MFMA16(a1, b1, a11);
  }

  const size_t rid = (((size_t)((xs*2 + dir)*4 + mslab)*32 + uslab)*4 + w);
  unsigned short* rec = xg + rid*1024;
  f32x4 accs[4] = {a00, a01, a10, a11};
  #pragma unroll
  for (int r = 0; r < 2; ++r)
    #pragma unroll
    for (int p = 0; p < 2; ++p){
      f32x4 v = accs[r*2 + p];
      short4v sv;
      #pragma unroll
      for (int j = 0; j < 4; ++j) sv[j] = (short)f2bf(v[j]);
      *(short4v*)(rec + ((p*2 + r)*64 + lane)*4) = sv;
    }
}

// ---------------- conv3 weights -> fragment-order pack ------------------------
__global__ void k_packC(const float* __restrict__ w, unsigned short* __restrict__ pk,
                        int cin, int T){
  int i = blockIdx.x*256 + threadIdx.x;
  if (i >= 9*8*T*64) return;
  const int lane = i & 63;
  int t = i >> 6;
  const int kc = t % T; t /= T;
  const int ot = t % 8; t /= 8;
  const int s = t;
  const int oc = ot*16 + (lane & 15);
  const int c0 = kc*32 + (lane >> 4)*8;
  unsigned short* dst = pk + (((size_t)(s*8 + ot)*T + kc)*64 + lane)*8;
  #pragma unroll
  for (int j = 0; j < 8; ++j){
    int c = c0 + j;
    dst[j] = (c < cin) ? f2bf(w[((size_t)oc*cin + c)*9 + s]) : (unsigned short)0;
  }
}

// ---------------- 1x1 weights [128][cin] -> fragment-order pack ---------------
__global__ void k_packG(const float* __restrict__ w, unsigned short* __restrict__ pk,
                        int cin, int T){
  int i = blockIdx.x*256 + threadIdx.x;
  if (i >= 8*T*64) return;
  const int lane = i & 63;
  int t = i >> 6;
  const int kc = t % T; t /= T;
  const int ot = t;
  const int oc = ot*16 + (lane & 15);
  const int c0 = kc*32 + (lane >> 4)*8;
  unsigned short* dst = pk + (((size_t)(ot*T + kc))*64 + lane)*8;
  #pragma unroll
  for (int j = 0; j < 8; ++j){
    int c = c0 + j;
    dst[j] = (c < cin) ? f2bf(w[(size_t)oc*cin + c]) : (unsigned short)0;
  }
}

__global__ void k_bias2(const float* __restrict__ bif, const float* __restrict__ bhf,
                        const float* __restrict__ bib, const float* __restrict__ bhb,
                        float* __restrict__ out){
  int i = blockIdx.x*256 + threadIdx.x;
  if (i >= 8192) return;
  out[i] = (i < 4096) ? (bif[i] + bhf[i]) : (bib[i-4096] + bhb[i-4096]);
}

// ---------------- vTb coord channels (written once) ---------------------------
__global__ void k_coordT(unsigned short* __restrict__ outT){
  int i = blockIdx.x*256 + threadIdx.x;
  if (i >= 128*196*32) return;
  int c2 = i & 31; int t = i >> 5; int p = t % 196; int b = t / 196;
  float v = (c2 == 0) ? c0f(p) : (c2 == 1) ? c1f(p) : 0.f;
  outT[((size_t)b*196 + p)*160 + 128 + c2] = f2bf(v);
}

// ---------------- one LSTM step (v10: h-only loop, acc init from xg) ----------
__launch_bounds__(256, 2)
__global__ void k_step10(const unsigned short* __restrict__ xg,
                         const unsigned short* __restrict__ pkW2,
                         const float* __restrict__ bias2,
                         const unsigned short* __restrict__ hin,
                         unsigned short* __restrict__ hout,
                         float* __restrict__ cst, float* __restrict__ Q, int s){
  const int dir   = blockIdx.x >> 5;
  const int uslab = blockIdx.x & 31;
  const int mslab = blockIdx.y;
  const int m0g   = mslab*32;
  const int tid = threadIdx.x, w = tid >> 6, lane = tid & 63;
  const int lr = lane & 15, lk = lane >> 4;
  const int xs = dir ? (S_-1-s) : s;

  __shared__ unsigned short tA[32][1032];

  {
    const int r = tid >> 3, sg = tid & 7;
    const unsigned short* hr = hin + ((size_t)dir*B_ + m0g + r)*H_ + sg*128;
    #pragma unroll
    for (int q = 0; q < 16; ++q)
      *(short8v*)&tA[r][sg*128 + q*8] = *(const short8v*)(hr + q*8);
  }

  const size_t rid = (((size_t)((xs*2 + dir)*4 + mslab)*32 + uslab)*4 + w);
  const unsigned short* rec = xg + rid*1024;
  f32x4 a00, a01, a10, a11;
  {
    short4v s00 = *(const short4v*)(rec + ((0*2 + 0)*64 + lane)*4);
    short4v s01 = *(const short4v*)(rec + ((1*2 + 0)*64 + lane)*4);
    short4v s10 = *(const short4v*)(rec + ((0*2 + 1)*64 + lane)*4);
    short4v s11 = *(const short4v*)(rec + ((1*2 + 1)*64 + lane)*4);
    #pragma unroll
    for (int j = 0; j < 4; ++j){
      a00[j] = bf2f((unsigned short)s00[j]);
      a01[j] = bf2f((unsigned short)s01[j]);
      a10[j] = bf2f((unsigned short)s10[j]);
      a11[j] = bf2f((unsigned short)s11[j]);
    }
  }

  const unsigned short* pb = pkW2 + ((((size_t)(dir*32 + uslab)*4 + w)*2)*KC*64 + lane)*8;
  const size_t pbPair = (size_t)KC*512;

  __syncthreads();

  #pragma unroll 8
  for (int ch = 0; ch < 32; ++ch){
    const int ka = ch*32 + lk*8;
    short8v a0 = *(short8v*)&tA[lr][ka];
    short8v a1 = *(short8v*)&tA[16 + lr][ka];
    short8v b0 = *(const short8v*)(pb + (size_t)(12 + ch)*512);
    short8v b1 = *(const short8v*)(pb + pbPair + (size_t)(12 + ch)*512);
    a00 = MFMA16(a0, b0, a00); a01 = MFMA16(a0, b1, a01);
    a10 = MFMA16(a1, b0, a10); a11 = MFMA16(a1, b1, a11);
  }

  const int ug = uslab*32 + w*8 + (lr & 7);
  const float* bb = bias2 + (size_t)dir*4096;
  const float bi = bb[ug], bfv = bb[1024+ug], bg = bb[2048+ug], bo = bb[3072+ug];
  float* cc = cst + (size_t)dir*B_*H_;
  unsigned short* ho = hout + (size_t)dir*B_*H_;
  const int jbase = (lr & 8) ? 2 : 0;

  #pragma unroll
  for (int rf = 0; rf < 2; ++rf){
    f32x4 c0 = rf ? a10 : a00;
    f32x4 c1 = rf ? a11 : a01;
    float p0[4], p1[4];
    #pragma unroll
    for (int j = 0; j < 4; ++j){
      p0[j] = __shfl_xor(c0[j], 8, 64);
      p1[j] = __shfl_xor(c1[j], 8, 64);
    }
    #pragma unroll
    for (int q = 0; q < 2; ++q){
      const int jj = jbase + q;
      float gi, gf, gg, go;
      if (lr & 8){ gi = p0[jj]; gf = c0[jj]; gg = p1[jj]; go = c1[jj]; }
      else       { gi = c0[jj]; gf = p0[jj]; gg = c1[jj]; go = p1[jj]; }
      gi += bi; gf += bfv; gg += bg; go += bo;
      const int m = m0g + rf*16 + lk*4 + jj;
      const size_t coff = (size_t)m*H_ + ug;
      float cold = cc[coff];
      float cn = sigm(gf)*cold + sigm(gi)*tanhf(gg);
      float hn = sigm(go)*tanhf(cn);
      cc[coff] = cn;
      ho[coff] = f2bf(hn);
      Q[((size_t)xs*B_ + m)*2048 + dir*1024 + ug] = hn;
    }
  }
}

// ---------------- qenc L2-normalize (in-place) + enc --------------------------
__global__ void k_qnorm(float* __restrict__ Q, float* __restrict__ enc){
  int sb = blockIdx.x;
  int s = sb >> 7, b = sb & 127;
  float* row = Q + (size_t)sb*2048;
  int tid = threadIdx.x;
  float v[8]; float ss = 0.f;
  #pragma unroll
  for (int i = 0; i < 8; ++i){ v[i] = row[tid*8+i]; ss += v[i]*v[i]; }
  __shared__ float red[256];
  red[tid] = ss; __syncthreads();
  for (int st = 128; st; st >>= 1){
    if (tid < st) red[tid] += red[tid+st];
    __syncthreads();
  }
  float inv = 1.0f / fmaxf(sqrtf(red[0]), 1e-12f);
  #pragma unroll
  for (int i = 0; i < 8; ++i){
    float q = v[i]*inv;
    row[tid*8+i] = q;
    if (s == S_-1) enc[(size_t)b*2048 + tid*8 + i] = q;
  }
}

// ---------------- per-pixel channel sumsq of img ------------------------------
__global__ void k_sqpart(const float* __restrict__ img, float* __restrict__ part){
  int b = blockIdx.x, cq = blockIdx.y;
  int t = threadIdx.x;
  if (t >= P_) return;
  const float* base = img + ((size_t)b*1024 + cq*256)*P_ + t;
  float s = 0.f;
  #pragma unroll 4
  for (int c = 0; c < 256; ++c){ float v = base[c*P_]; s += v*v; }
  part[((size_t)b*4 + cq)*P_ + t] = s;
}

__global__ void k_invnorm(const float* __restrict__ part, float* __restrict__ inv){
  int i = blockIdx.x*256 + threadIdx.x;
  if (i >= B_*P_) return;
  int b = i / P_, p = i % P_;
  float s = part[(b*4+0)*P_+p] + part[(b*4+1)*P_+p]
          + part[(b*4+2)*P_+p] + part[(b*4+3)*P_+p];
  inv[i] = 1.0f / fmaxf(sqrtf(s), 1e-12f);
}

// ---------------- img -> imgT[b][196][1056] bf16 (invnorm+coords+pad) ---------
__global__ void k_mkimgT(const float* __restrict__ img, const float* __restrict__ invn,
                         unsigned short* __restrict__ imgT){
  const int b = blockIdx.x, cg = blockIdx.y;
  const int tid = threadIdx.x;
  unsigned short* dstB = imgT + (size_t)b*196*1056;
  if (cg == 8){
    for (int i = tid; i < 196*32; i += 256){
      int p = i >> 5, cc = i & 31;
      float v = (cc == 0) ? c0f(p) : (cc == 1) ? c1f(p) : 0.f;
      dstB[(size_t)p*1056 + 1024 + cc] = f2bf(v);
    }
    return;
  }
  __shared__ unsigned short tt[196][136];
  __shared__ float sInv[200];
  for (int i = tid; i < 196; i += 256) sInv[i] = invn[b*196 + i];
  __syncthreads();
  const int c0 = cg*128;
  const float* srcB = img + ((size_t)b*1024 + c0)*196;
  for (int i = tid; i < 128*49; i += 256){
    int c = i / 49, p4 = i - (i/49)*49;
    float4 v = *(const float4*)(srcB + (size_t)c*196 + p4*4);
    int p = p4*4;
    tt[p+0][c] = f2bf(v.x * sInv[p+0]);
    tt[p+1][c] = f2bf(v.y * sInv[p+1]);
    tt[p+2][c] = f2bf(v.z * sInv[p+2]);
    tt[p+3][c] = f2bf(v.w * sInv[p+3]);
  }
  __syncthreads();
  for (int i = tid; i < 196*16; i += 256){
    int p = i >> 4, g = i & 15;
    *(short8v*)(dstB + (size_t)p*1056 + c0 + g*8) = *(short8v*)&tt[p][g*8];
  }
}

// ---------------- 3x3 conv via MFMA (A-frag register pipeline) ----------------
template<int CPAD>
__device__ __forceinline__ void stage3t(unsigned short (*__restrict__ tile)[40],
                                        const unsigned short* __restrict__ src,
                                        int c0, int r0, int tid){
  for (int i = tid; i < 10*14*4; i += 256){
    int t = i / 56, rem = i - t*56, gx = rem >> 2, seg = rem & 3;
    int gy = r0 - 1 + t;
    if ((unsigned)gy < 14u){
      short8v v = *(const short8v*)(src + (size_t)(gy*14+gx)*CPAD + c0 + seg*8);
      *(short8v*)&tile[t*16 + gx + 1][seg*8] = v;
    }
  }
}

template<int CPAD>
__launch_bounds__(256, 2)
__global__ void k_conv3t(const unsigned short* __restrict__ srcT,
                         const unsigned short* __restrict__ wPk,
                         const float* __restrict__ bias,
                         float* __restrict__ out){
  constexpr int T = CPAD / 32;
  const int b = blockIdx.x, n = blockIdx.y, z = blockIdx.z;
  const int r0 = n ? 6 : 0;
  const int chBeg = z ? T/2 : 0, chEnd = z ? T : T/2;
  const int tid = threadIdx.x, wave = tid >> 6, lane = tid & 63;
  const int lr = lane & 15, lk = lane >> 4;
  const int wfM = wave >> 1, wfN = wave & 1;
  const unsigned short* src = srcT + (size_t)b*196*CPAD;

  __shared__ unsigned short tile[2][164][40];

  for (int i = tid; i < 1640; i += 256)
    ((short8v*)&tile[0][0][0])[i] = short8v{0,0,0,0,0,0,0,0};
  __syncthreads();
  stage3t<CPAD>(tile[0], src, chBeg*32, r0, tid);
  __syncthreads();

  f32x4 acc[4][4];
  #pragma unroll
  for (int i = 0; i < 4; ++i)
    #pragma unroll
    for (int j = 0; j < 4; ++j) acc[i][j] = f32x4{0,0,0,0};

  short8v aC[12], aN[12];
  #pragma unroll
  for (int dx = 0; dx < 3; ++dx)
    #pragma unroll
    for (int rf = 0; rf < 4; ++rf)
      aC[dx*4+rf] = *(const short8v*)(wPk + ((((size_t)dx*8 + wfM*4 + rf)*T + chBeg)*64
                                             + lane)*8);

  for (int ch = chBeg; ch < chEnd; ++ch){
    const int cur = (ch - chBeg) & 1;
    #pragma unroll
    for (int dy = 0; dy < 3; ++dy){
      const int ndy = (dy < 2) ? dy + 1 : 0;
      const int nch = (dy < 2) ? ch : ch + 1;
      const bool hasN = nch < chEnd;
      if (hasN){
        #pragma unroll
        for (int dx = 0; dx < 3; ++dx)
          #pragma unroll
          for (int rf = 0; rf < 4; ++rf)
            aN[dx*4+rf] = *(const short8v*)(wPk + ((((size_t)(ndy*3+dx)*8 + wfM*4 + rf)*T
                                                    + nch)*64 + lane)*8);
      }
      #pragma unroll
      for (int dx = 0; dx < 3; ++dx){
        const int dlt = dy*16 + dx;
        #pragma unroll
        for (int cf = 0; cf < 4; ++cf){
          short8v bf = *(short8v*)&tile[cur][wfN*64 + cf*16 + lr + dlt][lk*8];
          #pragma unroll
          for (int rf = 0; rf < 4; ++rf)
            acc[rf][cf] = MFMA16(aC[dx*4+rf], bf, acc[rf][cf]);
        }
      }
      if (dy == 0 && ch + 1 < chEnd)
        stage3t<CPAD>(tile[cur^1], src, (ch+1)*32, r0, tid);
      if (hasN){
        #pragma unroll
        for (int q = 0; q < 12; ++q) aC[q] = aN[q];
      }
    }
    __syncthreads();
  }

  #pragma unroll
  for (int rf = 0; rf < 4; ++rf){
    #pragma unroll
    for (int j = 0; j < 4; ++j){
      const int oc = wfM*64 + rf*16 + lk*4 + j;
      const float bz = z ? 0.f : bias[oc];
      #pragma unroll
      for (int cf = 0; cf < 4; ++cf){
        const int pos = wfN*64 + cf*16 + lr;
        const int py = r0 + (pos >> 4), px = pos & 15;
        const bool rowok = n ? (py >= 8) : true;
        if (rowok && px < 14)
          out[(size_t)z*NE + ((size_t)b*OC_ + oc)*P_ + py*14 + px] = acc[rf][cf][j] + bz;
      }
    }
  }
}

// ---------------- BN stats: phase 1 (partials, 1024 blocks) -------------------
__global__ void k_bnstats2(const float* __restrict__ t, float* __restrict__ bpart){
  const int o = blockIdx.x, part = blockIdx.y;
  const int tid = threadIdx.x;
  float s = 0.f, s2 = 0.f;
  for (int i = tid; i < 16*196; i += 256){
    int b = part*16 + i/196, p = i - (i/196)*196;
    size_t off = ((size_t)b*OC_ + o)*P_ + p;
    float v = t[off] + t[off + NE];
    s += v; s2 += v*v;
  }
  __shared__ float r1[256], r2[256];
  r1[tid] = s; r2[tid] = s2; __syncthreads();
  for (int st = 128; st; st >>= 1){
    if (tid < st){ r1[tid] += r1[tid+st]; r2[tid] += r2[tid+st]; }
    __syncthreads();
  }
  if (tid == 0){
    bpart[(o*8 + part)*2]     = r1[0];
    bpart[(o*8 + part)*2 + 1] = r2[0];
  }
}

// ---------------- BN stats: phase 2 (finalize) --------------------------------
__global__ void k_bnfin(const float* __restrict__ bpart, float* __restrict__ stats){
  int o = threadIdx.x;
  if (o >= 128) return;
  float s = 0.f, s2 = 0.f;
  #pragma unroll
  for (int q = 0; q < 8; ++q){
    s  += bpart[(o*8 + q)*2];
    s2 += bpart[(o*8 + q)*2 + 1];
  }
  float n = (float)(B_*P_);
  float m = s / n;
  float var = s2 / n - m*m;
  stats[o*2]   = m;
  stats[o*2+1] = rsqrtf(var + 1e-5f);
}

// ---------------- BN apply + relu (+add), emit bf16-T (or final f32) ----------
// grid (128 b, 8 seg): seg covers oc [seg*16, +16).
template<bool ADD, bool FINAL>
__global__ void k_bntr(const float* __restrict__ t, const float* __restrict__ stats,
                       const float* __restrict__ g, const float* __restrict__ bb,
                       const float* __restrict__ addsrc,
                       float* __restrict__ outF, unsigned short* __restrict__ outT){
  const int b = blockIdx.x, seg = blockIdx.y, tid = threadIdx.x;
  for (int i = tid; i < 16*196; i += 256){
    int c = seg*16 + i/196, p = i - (i/196)*196;
    size_t off = ((size_t)b*OC_ + c)*P_ + p;
    float x = t[off] + t[off + NE];
    float v = g[c]*(x - stats[c*2])*stats[c*2+1] + bb[c];
    v = fmaxf(v, 0.f);
    if (ADD) v += addsrc[off];
    if (FINAL) outF[off] = v;
    else       outT[((size_t)b*P_ + p)*160 + c] = f2bf(v);
  }
}

// ---------------- 1x1 conv via MFMA -------------------------------------------
__launch_bounds__(256, 2)
__global__ void k_c1m(const unsigned short* __restrict__ vT,
                      const unsigned short* __restrict__ pk,
                      const float* __restrict__ bias,
                      float* __restrict__ out, unsigned short* __restrict__ outT){
  const int b = blockIdx.x, n = blockIdx.y;
  const int pBeg = n ? 112 : 0;
  const int nCF = n ? 6 : 7;
  const int tid = threadIdx.x, wave = tid >> 6, lane = tid & 63;
  const int lr = lane & 15, lk = lane >> 4;

  __shared__ unsigned short tile[112][164];

  for (int i = tid; i < 112*20; i += 256){
    int r = i / 20, seg = i - r*20;
    int p = pBeg + r;
    short8v v = short8v{0,0,0,0,0,0,0,0};
    if (p < 196 && r < nCF*16)
      v = *(const short8v*)(vT + ((size_t)b*P_ + p)*160 + seg*8);
    *(short8v*)&tile[r][seg*8] = v;
  }
  __syncthreads();

  f32x4 acc[2][7];
  #pragma unroll
  for (int i = 0; i < 2; ++i)
    #pragma unroll
    for (int j = 0; j < 7; ++j) acc[i][j] = f32x4{0,0,0,0};

  #pragma unroll
  for (int kc = 0; kc < 5; ++kc){
    short8v a0 = *(const short8v*)(pk + (((size_t)(wave*2 + 0)*5 + kc)*64 + lane)*8);
    short8v a1 = *(const short8v*)(pk + (((size_t)(wave*2 + 1)*5 + kc)*64 + lane)*8);
    #pragma unroll
    for (int cf = 0; cf < 7; ++cf){
      if (cf < nCF){
        short8v bf = *(short8v*)&tile[cf*16 + lr][kc*32 + lk*8];
        acc[0][cf] = MFMA16(a0, bf, acc[0][cf]);
        acc[1][cf] = MFMA16(a1, bf, acc[1][cf]);
      }
    }
  }

  #pragma unroll
  for (int rf = 0; rf < 2; ++rf){
    const int ocBase = wave*32 + rf*16 + lk*4;
    #pragma unroll
    for (int cf = 0; cf < 7; ++cf){
      if (cf < nCF){
        const int pos = pBeg + cf*16 + lr;
        if (pos < 196){
          short4v sv;
          #pragma unroll
          for (int j = 0; j < 4; ++j){
            const int oc = ocBase + j;
            float v = fmaxf(acc[rf][cf][j] + bias[oc], 0.f);
            out[((size_t)b*OC_ + oc)*P_ + pos] = v;
            sv[j] = (short)f2bf(v);
          }
          *(short4v*)(outT + ((size_t)b*P_ + pos)*128 + ocBase) = sv;
        }
      }
    }
  }
}

} // namespace

// ---------------------------------------------------------------------------
extern "C" void kernel_launch(void* const* d_in, const int* in_sizes, int n_in,
                              void* d_out, int out_size, void* d_ws, size_t ws_size,
                              hipStream_t stream){
  (void)in_sizes; (void)n_in; (void)out_size; (void)ws_size;
  const int*   que  = (const int*)  d_in[0];
  const float* img  = (const float*)d_in[1];
  const float* emb  = (const float*)d_in[2];
  const float* wihf = (const float*)d_in[3];
  const float* whhf = (const float*)d_in[4];
  const float* bihf = (const float*)d_in[5];
  const float* bhhf = (const float*)d_in[6];
  const float* wihb = (const float*)d_in[7];
  const float* whhb = (const float*)d_in[8];
  const float* bihb = (const float*)d_in[9];
  const float* bhhb = (const float*)d_in[10];
  const float* convw = (const float*)d_in[11];
  const float* convb = (const float*)d_in[12];
  const float* bng  = (const float*)d_in[13];
  const float* bnb  = (const float*)d_in[14];
  const float* r1c1w = (const float*)d_in[15];
  const float* r1c1b = (const float*)d_in[16];
  const float* r1c2w = (const float*)d_in[17];
  const float* r1c2b = (const float*)d_in[18];
  const float* r1bng = (const float*)d_in[19];
  const float* r1bnb = (const float*)d_in[20];
  const float* r2c1w = (const float*)d_in[21];
  const float* r2c1b = (const float*)d_in[22];
  const float* r2c2w = (const float*)d_in[23];
  const float* r2c2b = (const float*)d_in[24];
  const float* r2bng = (const float*)d_in[25];
  const float* r2bnb = (const float*)d_in[26];

  float* out  = (float*)d_out;
  float* enc  = out;                        // 128*2048
  float* Q    = out + 262144;               // 32*128*2048
  float* vout = out + 262144 + 8388608;     // 128*128*196

  // ------ workspace layout (f32 units) ----------------------------------------
  float* ws = (float*)d_ws;
  unsigned short* px   = (unsigned short*)ws;                  // 32*8*12*512 bf16
  unsigned short* pkW2 = (unsigned short*)(ws + 786432);       // 2*32*4*2*44*512 bf16
  float* bias2 = ws + 6553600;                                 // 2*4096
  unsigned short* hstate = (unsigned short*)(ws + 6561792);    // 2par*2dir*128*1024 bf16
  float* cstate = ws + 6823936;                                // 2*128*1024
  float* part   = ws + 7086080;                                // 128*4*196
  float* invn   = ws + 7186432;                                // 128*196
  float* stats  = ws + 7211520;                                // 256
  float* bpart  = ws + 7211776;                                // 128*8*2
  unsigned short* pkC  = (unsigned short*)(ws + 7213824);      // 9*8*33*512 bf16
  unsigned short* pkR1 = (unsigned short*)(ws + 7822080);      // 9*8*4*512 bf16
  unsigned short* pkR2 = (unsigned short*)(ws + 7895808);      // 9*8*4*512 bf16
  unsigned short* pk1  = (unsigned short*)(ws + 7969536);      // 8*5*512 bf16
  unsigned short* pk2  = (unsigned short*)(ws + 7979776);      // 8*5*512 bf16
  float* U = ws + 7990016;                                     // union region
  // LSTM phase: xg = 32768 records x 1024 bf16 = 16.8M floats
  unsigned short* xg = (unsigned short*)U;
  // image phase (bufB/convOut/imgT written only after LSTM finishes):
  float* bufB = U;                                             // NE (v1 f32)
  float* convOut = U + NE;                                     // 2*NE partial slabs
  unsigned short* imgT = (unsigned short*)(U + 3*(size_t)NE);  // 128*196*1056
  unsigned short* vTb  = (unsigned short*)(U + 9633792 + 13246464);  // no xg overlap
  unsigned short* v1T  = (unsigned short*)(U + 9633792 + 13246464 + 2007040);

  hipMemsetAsync(hstate, 0, (size_t)(262144 + 262144)*sizeof(float), stream);

  // ------ packing / conversions ------------------------------------------------
  k_packW2<<<(2*32*4*2*KC*64 + 255)/256, 256, 0, stream>>>(wihf, whhf, wihb, whhb, pkW2);
  k_embed_px<<<(32*8*12*64 + 255)/256, 256, 0, stream>>>(que, emb, px);
  k_packC<<<(9*8*33*64 + 255)/256, 256, 0, stream>>>(convw, pkC, 1026, 33);
  k_packC<<<(9*8*4*64 + 255)/256, 256, 0, stream>>>(r1c2w, pkR1, 128, 4);
  k_packC<<<(9*8*4*64 + 255)/256, 256, 0, stream>>>(r2c2w, pkR2, 128, 4);
  k_packG<<<(8*5*64 + 255)/256, 256, 0, stream>>>(r1c1w, pk1, 130, 5);
  k_packG<<<(8*5*64 + 255)/256, 256, 0, stream>>>(r2c1w, pk2, 130, 5);
  k_bias2<<<32, 256, 0, stream>>>(bihf, bhhf, bihb, bhhb, bias2);
  k_coordT<<<(128*196*32 + 255)/256, 256, 0, stream>>>(vTb);   // vTb doesn't alias xg

  // ------ x-part GEMM for all steps (one wide launch) --------------------------
  k_xg<<<dim3(64,4,32), 256, 0, stream>>>(px, pkW2, xg);

  // ------ bi-LSTM: 32 h-only step launches -------------------------------------
  for (int s = 0; s < 32; ++s){
    unsigned short* hin  = hstate + (size_t)(s & 1)*262144;
    unsigned short* hout = hstate + (size_t)((s & 1)^1)*262144;
    k_step10<<<dim3(64,4), 256, 0, stream>>>(xg, pkW2, bias2, hin, hout,
                                             cstate, Q, s);
  }
  k_qnorm<<<4096, 256, 0, stream>>>(Q, enc);

  // ------ image branch (after LSTM: imgT/bufB/convOut alias xg) ---------------
  k_sqpart<<<dim3(128,4), 256, 0, stream>>>(img, part);
  k_invnorm<<<(25088+255)/256, 256, 0, stream>>>(part, invn);
  k_mkimgT<<<dim3(128,9), 256, 0, stream>>>(img, invn, imgT);

  k_conv3t<1056><<<dim3(128,2,2), 256, 0, stream>>>(imgT, pkC, convb, convOut);
  k_bnstats2<<<dim3(128,8), 256, 0, stream>>>(convOut, bpart);
  k_bnfin<<<1, 128, 0, stream>>>(bpart, stats);
  k_bntr<false,false><<<dim3(128,8), 256, 0, stream>>>(convOut, stats, bng, bnb,
                                                       nullptr, nullptr, vTb);

  // res block 1: vTb -> (bufB f32, v1T) -> convOut -> vTb
  k_c1m<<<dim3(128,2), 256, 0, stream>>>(vTb, pk1, r1c1b, bufB, v1T);
  k_conv3t<128><<<dim3(128,2,2), 256, 0, stream>>>(v1T, pkR1, r1c2b, convOut);
  k_bnstats2<<<dim3(128,8), 256, 0, stream>>>(convOut, bpart);
  k_bnfin<<<1, 128, 0, stream>>>(bpart, stats);
  k_bntr<true,false><<<dim3(128,8), 256, 0, stream>>>(convOut, stats, r1bng, r1bnb,
                                                      bufB, nullptr, vTb);

  // res block 2: vTb -> (bufB, v1T) -> convOut -> vout
  k_c1m<<<dim3(128,2), 256, 0, stream>>>(vTb, pk2, r2c1b, bufB, v1T);
  k_conv3t<128><<<dim3(128,2,2), 256, 0, stream>>>(v1T, pkR2, r2c2b, convOut);
  k_bnstats2<<<dim3(128,8), 256, 0, stream>>>(convOut, bpart);
  k_bnfin<<<1, 128, 0, stream>>>(bpart, stats);
  k_bntr<true,true><<<dim3(128,8), 256, 0, stream>>>(convOut, stats, r2bng, r2bnb,
                                                     bufB, vout, nullptr);
}